// Round 2
// baseline (1284.126 us; speedup 1.0000x reference)
//
#include <hip/hip_runtime.h>

#define NMF_EPS 1e-6f

typedef unsigned short ushort_t;
typedef __attribute__((ext_vector_type(8))) short bf16x8;
typedef __attribute__((ext_vector_type(4))) float f32x4;

__device__ __forceinline__ ushort_t f2bf(float f) {
    unsigned int u = __float_as_uint(f);
    return (ushort_t)((u + 0x7FFFu + ((u >> 16) & 1u)) >> 16);
}
__device__ __forceinline__ float bf2f(ushort_t h) {
    return __uint_as_float(((unsigned int)h) << 16);
}

__device__ __forceinline__ void gl_lds16(const ushort_t* g, ushort_t* l) {
    __builtin_amdgcn_global_load_lds(
        (const __attribute__((address_space(1))) unsigned int*)g,
        (__attribute__((address_space(3))) unsigned int*)l,
        16, 0, 0);
}

// =====================================================================
// Big MFMA GEMM (lower / upper). C[m,n] = op(sum_k A[m,k]*B[n,k])
// Double-buffered LDS, single barrier per K-step (stage t+1 before
// compute t; __syncthreads' implicit vmcnt(0) drain is the fence).
// EPI 2: relu(acc+bias[m]) -> bf16 hi/lo TRANSPOSED [n][M] (LDS transpose)
// EPI 3: relu(ham*acc + sc*res[m,n]) -> fp32 [M,N]
// =====================================================================
template<int SPLIT, int EPI>
__global__ __launch_bounds__(256) void mfma_gemm(
    const ushort_t* __restrict__ Ah, const ushort_t* __restrict__ Al,
    const ushort_t* __restrict__ Bh, const ushort_t* __restrict__ Bl,
    float* __restrict__ C, ushort_t* __restrict__ Chi, ushort_t* __restrict__ Clo,
    int M, int N, int K,
    long sB, long sC,
    const float* __restrict__ bias,
    const float* __restrict__ res, long sRes,
    const float* __restrict__ hamp, const float* __restrict__ scp)
{
    constexpr int SB = SPLIT ? 32768 : 16384;   // bytes per dbuf slot
    __shared__ char smem[2 * SB];

    const int tid  = threadIdx.x;
    const int wave = tid >> 6, lane = tid & 63;
    const int quad = lane >> 4, lr = lane & 15;
    const int batch = blockIdx.z;
    const int m0 = blockIdx.y * 128, n0 = blockIdx.x * 128;

    const ushort_t* Bhb = Bh + (long)batch * sB;
    const ushort_t* Blb = SPLIT ? (Bl + (long)batch * sB) : nullptr;

    f32x4 acc[4][4];
    #pragma unroll
    for (int i = 0; i < 4; ++i)
        #pragma unroll
        for (int j = 0; j < 4; ++j)
            acc[i][j] = (f32x4){0.f, 0.f, 0.f, 0.f};

    const int q   = wave * 2;
    const int ra0 = (q + 0) * 16 + (lane >> 2);
    const int ra1 = (q + 1) * 16 + (lane >> 2);
    const int ko  = (lane & 3) * 8;
    const int wm = (wave & 1) * 64, wn = (wave >> 1) * 64;

    auto STAGE = [&](int buf, int k0) {
        char* base = smem + buf * SB;
        ushort_t* dAh = (ushort_t*)base;
        ushort_t* dBh = (ushort_t*)(base + 8192);
        gl_lds16(&Ah [(long)(m0 + ra0) * K + k0 + ko], &dAh[(q + 0) * 512]);
        gl_lds16(&Ah [(long)(m0 + ra1) * K + k0 + ko], &dAh[(q + 1) * 512]);
        gl_lds16(&Bhb[(long)(n0 + ra0) * K + k0 + ko], &dBh[(q + 0) * 512]);
        gl_lds16(&Bhb[(long)(n0 + ra1) * K + k0 + ko], &dBh[(q + 1) * 512]);
        if constexpr (SPLIT) {
            ushort_t* dAl = (ushort_t*)(base + 16384);
            ushort_t* dBl = (ushort_t*)(base + 24576);
            gl_lds16(&Al [(long)(m0 + ra0) * K + k0 + ko], &dAl[(q + 0) * 512]);
            gl_lds16(&Al [(long)(m0 + ra1) * K + k0 + ko], &dAl[(q + 1) * 512]);
            gl_lds16(&Blb[(long)(n0 + ra0) * K + k0 + ko], &dBl[(q + 0) * 512]);
            gl_lds16(&Blb[(long)(n0 + ra1) * K + k0 + ko], &dBl[(q + 1) * 512]);
        }
    };

    STAGE(0, 0);
    __syncthreads();
    int cur = 0;

    for (int k0 = 0; k0 < K; k0 += 32) {
        if (k0 + 32 < K) STAGE(cur ^ 1, k0 + 32);

        char* base = smem + cur * SB;
        ushort_t* sAh = (ushort_t*)base;
        ushort_t* sBh = (ushort_t*)(base + 8192);

        bf16x8 af[4], bfr[4], afl[4], bfl[4];
        #pragma unroll
        for (int i = 0; i < 4; ++i)
            af[i] = *(const bf16x8*)&sAh[(wm + i * 16 + lr) * 32 + quad * 8];
        #pragma unroll
        for (int j = 0; j < 4; ++j)
            bfr[j] = *(const bf16x8*)&sBh[(wn + j * 16 + lr) * 32 + quad * 8];
        if constexpr (SPLIT) {
            ushort_t* sAl = (ushort_t*)(base + 16384);
            ushort_t* sBl = (ushort_t*)(base + 24576);
            #pragma unroll
            for (int i = 0; i < 4; ++i)
                afl[i] = *(const bf16x8*)&sAl[(wm + i * 16 + lr) * 32 + quad * 8];
            #pragma unroll
            for (int j = 0; j < 4; ++j)
                bfl[j] = *(const bf16x8*)&sBl[(wn + j * 16 + lr) * 32 + quad * 8];
        }

        #pragma unroll
        for (int i = 0; i < 4; ++i)
            #pragma unroll
            for (int j = 0; j < 4; ++j) {
                acc[i][j] = __builtin_amdgcn_mfma_f32_16x16x32_bf16(af[i], bfr[j], acc[i][j], 0, 0, 0);
                if constexpr (SPLIT) {
                    acc[i][j] = __builtin_amdgcn_mfma_f32_16x16x32_bf16(af[i], bfl[j], acc[i][j], 0, 0, 0);
                    acc[i][j] = __builtin_amdgcn_mfma_f32_16x16x32_bf16(afl[i], bfr[j], acc[i][j], 0, 0, 0);
                }
            }
        __syncthreads();
        cur ^= 1;
    }

    if (EPI == 2) {
        ushort_t* Hh = Chi + (long)batch * sC;
        ushort_t* Hl = Clo + (long)batch * sC;
        unsigned int* slab = (unsigned int*)smem;  // [128 n][64 m] u32
        #pragma unroll
        for (int p = 0; p < 2; ++p) {
            __syncthreads();
            if ((wave & 1) == p) {
                #pragma unroll
                for (int i = 0; i < 4; ++i) {
                    const int mb = m0 + p * 64 + i * 16 + quad * 4;
                    #pragma unroll
                    for (int j = 0; j < 4; ++j) {
                        const int nl = wn + j * 16 + lr;
                        #pragma unroll
                        for (int r = 0; r < 4; ++r) {
                            float v = fmaxf(acc[i][j][r] + bias[mb + r], 0.f);
                            ushort_t h = f2bf(v);
                            ushort_t l = f2bf(v - bf2f(h));
                            slab[nl * 64 + (i * 16 + quad * 4 + r)] =
                                (unsigned)h | ((unsigned)l << 16);
                        }
                    }
                }
            }
            __syncthreads();
            for (int idx = tid; idx < 8192; idx += 256) {
                const int nl = idx >> 6, ml = idx & 63;
                unsigned u = slab[idx];
                const long off = (long)(n0 + nl) * M + m0 + p * 64 + ml;
                Hh[off] = (ushort_t)(u & 0xffffu);
                Hl[off] = (ushort_t)(u >> 16);
            }
        }
    } else {
        const float hm = *hamp, sc = *scp;
        float* Cb = C + (long)batch * sC;
        #pragma unroll
        for (int i = 0; i < 4; ++i) {
            #pragma unroll
            for (int j = 0; j < 4; ++j) {
                const int mbase = m0 + wm + i * 16 + quad * 4;
                const int n     = n0 + wn + j * 16 + lr;
                #pragma unroll
                for (int r = 0; r < 4; ++r) {
                    float rv = res[(long)batch * sRes + (long)(mbase + r) * N + n];
                    Cb[(long)(mbase + r) * N + n] = fmaxf(fmaf(hm, acc[i][j][r], sc * rv), 0.f);
                }
            }
        }
    }
}

// =====================================================================
// Fused coef step. grid (N/64, B), 256 thr.
// X staged to LDS (double-buffered, single barrier/tile); bt B-fragments
// read DIRECTLY from global (L2-hot, shared by all 64 N-blocks).
// MODE 0 (INIT): coef = softmax_r(X^T bases)
// MODE 1 (MU):   coef = coef*xtb/(coef@btb+eps); writes ct hi/lo + ctc partials
// MODE 2 (MU, final): as MODE 1 but skips the dead ct/ctc tail
// =====================================================================
template<int MODE>
__global__ __launch_bounds__(256) void coef_step(
    const ushort_t* __restrict__ Xh, const ushort_t* __restrict__ Xl,   // [B][N][512]
    const ushort_t* __restrict__ bth, const ushort_t* __restrict__ btl, // [B][64][512]
    const float* __restrict__ btb_part,   // [8][B][4096]
    float* __restrict__ coef,             // [B][N][64]
    ushort_t* __restrict__ cth, ushort_t* __restrict__ ctl, // [B][64][N]
    float* __restrict__ ctc_part,         // [64][B][4096]
    int Bcnt)
{
    constexpr bool MU = (MODE >= 1);
    __shared__ char smem[32768 + 18432];
    ushort_t* stg = (ushort_t*)smem;             // 2 bufs x 8192 ushorts: [buf][p*2+kc][2048]
    ushort_t* gLh = (ushort_t*)(smem + 32768);   // [64][72] btb hi (later ct hi)
    ushort_t* gLl = gLh + 64 * 72;               // btb lo (later ct lo)

    const int tid = threadIdx.x, wave = tid >> 6, lane = tid & 63;
    const int quad = lane >> 4, lr = lane & 15;
    const int b = blockIdx.y, n0 = blockIdx.x * 64;

    const ushort_t* Xhb  = Xh  + (long)b * 2097152 + (long)n0 * 512;
    const ushort_t* Xlb  = Xl  + (long)b * 2097152 + (long)n0 * 512;
    const ushort_t* bthb = bth + (long)b * 32768;
    const ushort_t* btlb = btl + (long)b * 32768;
    float* coefB = coef + (long)b * 262144 + (long)n0 * 64;

    if (MU) {
        // reduce btb partials -> LDS (hi/lo)
        for (int i = tid; i < 4096; i += 256) {
            const int r = i >> 6, s = i & 63;
            float v = 0.f;
            #pragma unroll
            for (int c = 0; c < 8; ++c)
                v += btb_part[((long)c * Bcnt + b) * 4096 + i];
            ushort_t h = f2bf(v);
            gLh[r * 72 + s] = h;
            gLl[r * 72 + s] = f2bf(v - bf2f(h));
        }
    }

    // ---- xtb via MFMA, BK=64, dbuf single-barrier ----
    const int srow = wave * 16 + (lane >> 2);
    const int koff = (lane & 3) * 8;
    f32x4 accx[4];
    #pragma unroll
    for (int j = 0; j < 4; ++j) accx[j] = (f32x4){0.f, 0.f, 0.f, 0.f};

    auto STAGEX = [&](int buf, int kt) {
        #pragma unroll
        for (int kc = 0; kc < 2; ++kc) {
            const int kg = kt + kc * 32 + koff;
            gl_lds16(&Xhb[(long)srow * 512 + kg], &stg[buf * 8192 + (0 * 2 + kc) * 2048 + wave * 512]);
            gl_lds16(&Xlb[(long)srow * 512 + kg], &stg[buf * 8192 + (1 * 2 + kc) * 2048 + wave * 512]);
        }
    };

    STAGEX(0, 0);
    __syncthreads();
    int cur = 0;

    for (int kt = 0; kt < 512; kt += 64) {
        if (kt + 64 < 512) STAGEX(cur ^ 1, kt + 64);
        #pragma unroll
        for (int kc = 0; kc < 2; ++kc) {
            bf16x8 ah = *(const bf16x8*)&stg[cur * 8192 + (0 * 2 + kc) * 2048 + (wave * 16 + lr) * 32 + quad * 8];
            bf16x8 al = *(const bf16x8*)&stg[cur * 8192 + (1 * 2 + kc) * 2048 + (wave * 16 + lr) * 32 + quad * 8];
            const int kg = kt + kc * 32 + quad * 8;
            #pragma unroll
            for (int j = 0; j < 4; ++j) {
                const long boff = (long)(j * 16 + lr) * 512 + kg;
                bf16x8 bh = *(const bf16x8*)&bthb[boff];
                bf16x8 bl = *(const bf16x8*)&btlb[boff];
                accx[j] = __builtin_amdgcn_mfma_f32_16x16x32_bf16(ah, bh, accx[j], 0, 0, 0);
                accx[j] = __builtin_amdgcn_mfma_f32_16x16x32_bf16(ah, bl, accx[j], 0, 0, 0);
                accx[j] = __builtin_amdgcn_mfma_f32_16x16x32_bf16(al, bh, accx[j], 0, 0, 0);
            }
        }
        __syncthreads();
        cur ^= 1;
    }

    float cnew[4][4]; // [j][reg]
    if (MU) {
        // denom = coef @ btb (split MFMA; coef A-frags direct from global fp32)
        f32x4 accd[4];
        #pragma unroll
        for (int j = 0; j < 4; ++j) accd[j] = (f32x4){0.f, 0.f, 0.f, 0.f};
        #pragma unroll
        for (int kk = 0; kk < 2; ++kk) {
            const float* cp = &coefB[(wave * 16 + lr) * 64 + kk * 32 + quad * 8];
            float4 cA = *(const float4*)cp;
            float4 cB = *(const float4*)(cp + 4);
            float cv[8] = {cA.x, cA.y, cA.z, cA.w, cB.x, cB.y, cB.z, cB.w};
            bf16x8 ah, al;
            #pragma unroll
            for (int e = 0; e < 8; ++e) {
                ushort_t h = f2bf(cv[e]);
                ((short*)&ah)[e] = (short)h;
                ((short*)&al)[e] = (short)f2bf(cv[e] - bf2f(h));
            }
            #pragma unroll
            for (int j = 0; j < 4; ++j) {
                bf16x8 bh = *(const bf16x8*)&gLh[(j * 16 + lr) * 72 + kk * 32 + quad * 8];
                bf16x8 bl = *(const bf16x8*)&gLl[(j * 16 + lr) * 72 + kk * 32 + quad * 8];
                accd[j] = __builtin_amdgcn_mfma_f32_16x16x32_bf16(ah, bh, accd[j], 0, 0, 0);
                accd[j] = __builtin_amdgcn_mfma_f32_16x16x32_bf16(ah, bl, accd[j], 0, 0, 0);
                accd[j] = __builtin_amdgcn_mfma_f32_16x16x32_bf16(al, bh, accd[j], 0, 0, 0);
            }
        }
        #pragma unroll
        for (int j = 0; j < 4; ++j)
            #pragma unroll
            for (int r = 0; r < 4; ++r) {
                float cold = coefB[(wave * 16 + quad * 4 + r) * 64 + j * 16 + lr];
                cnew[j][r] = cold * accx[j][r] / (accd[j][r] + NMF_EPS);
            }
    } else {
        #pragma unroll
        for (int r = 0; r < 4; ++r) {
            float m = fmaxf(fmaxf(accx[0][r], accx[1][r]), fmaxf(accx[2][r], accx[3][r]));
            #pragma unroll
            for (int off = 1; off < 16; off <<= 1) m = fmaxf(m, __shfl_xor(m, off, 64));
            float e[4], s = 0.f;
            #pragma unroll
            for (int j = 0; j < 4; ++j) { e[j] = __expf(accx[j][r] - m); s += e[j]; }
            #pragma unroll
            for (int off = 1; off < 16; off <<= 1) s += __shfl_xor(s, off, 64);
            float inv = 1.f / s;
            #pragma unroll
            for (int j = 0; j < 4; ++j) cnew[j][r] = e[j] * inv;
        }
    }

    #pragma unroll
    for (int j = 0; j < 4; ++j)
        #pragma unroll
        for (int r = 0; r < 4; ++r)
            coefB[(wave * 16 + quad * 4 + r) * 64 + j * 16 + lr] = cnew[j][r];

    if (MODE != 1) return;

    __syncthreads();  // btb dead; overlay ct on gL
    #pragma unroll
    for (int j = 0; j < 4; ++j)
        #pragma unroll
        for (int r = 0; r < 4; ++r) {
            const int nl = wave * 16 + quad * 4 + r;
            const int rr = j * 16 + lr;
            float v = cnew[j][r];
            ushort_t h = f2bf(v);
            gLh[rr * 72 + nl] = h;
            gLl[rr * 72 + nl] = f2bf(v - bf2f(h));
        }
    __syncthreads();
    for (int i = tid; i < 4096; i += 256) {
        const int r = i >> 6, nn = i & 63;
        cth[(long)b * 262144 + (long)r * 4096 + n0 + nn] = gLh[r * 72 + nn];
        ctl[(long)b * 262144 + (long)r * 4096 + n0 + nn] = gLl[r * 72 + nn];
    }
    // ctc Gram partials via MFMA
    f32x4 accc[4];
    #pragma unroll
    for (int j = 0; j < 4; ++j) accc[j] = (f32x4){0.f, 0.f, 0.f, 0.f};
    #pragma unroll
    for (int kk = 0; kk < 64; kk += 32) {
        bf16x8 ah = *(const bf16x8*)&gLh[(wave * 16 + lr) * 72 + kk + quad * 8];
        bf16x8 al = *(const bf16x8*)&gLl[(wave * 16 + lr) * 72 + kk + quad * 8];
        #pragma unroll
        for (int j = 0; j < 4; ++j) {
            bf16x8 bh = *(const bf16x8*)&gLh[(j * 16 + lr) * 72 + kk + quad * 8];
            bf16x8 bl = *(const bf16x8*)&gLl[(j * 16 + lr) * 72 + kk + quad * 8];
            accc[j] = __builtin_amdgcn_mfma_f32_16x16x32_bf16(ah, bh, accc[j], 0, 0, 0);
            accc[j] = __builtin_amdgcn_mfma_f32_16x16x32_bf16(ah, bl, accc[j], 0, 0, 0);
            accc[j] = __builtin_amdgcn_mfma_f32_16x16x32_bf16(al, bh, accc[j], 0, 0, 0);
        }
    }
    float* cp = ctc_part + ((long)blockIdx.x * Bcnt + b) * 4096;
    #pragma unroll
    for (int j = 0; j < 4; ++j)
        #pragma unroll
        for (int r = 0; r < 4; ++r)
            cp[(wave * 16 + quad * 4 + r) * 64 + j * 16 + lr] = accc[j][r];
}

// xc split-K partials, BK=64: part[kc][b][c][r] = sum_{k chunk} X[c,k]*ct[r,k]
// grid (8, C/64, B). X staged (dbuf, single barrier); ct frags direct global.
__global__ __launch_bounds__(256) void xc_partial(
    const ushort_t* __restrict__ Ah, const ushort_t* __restrict__ Al, // X_dn [B][512][4096]
    const ushort_t* __restrict__ Bh, const ushort_t* __restrict__ Bl, // ct  [B][64][4096]
    float* __restrict__ part, int Bcnt)
{
    __shared__ ushort_t stg[2 * 8192];
    const int tid = threadIdx.x, wave = tid >> 6, lane = tid & 63;
    const int quad = lane >> 4, lr = lane & 15;
    const int batch = blockIdx.z;
    const int m0 = blockIdx.y * 64;
    const int k0 = blockIdx.x * 512;

    const ushort_t* Ab  = Ah + (long)batch * 2097152;
    const ushort_t* Alb = Al + (long)batch * 2097152;
    const ushort_t* Bb  = Bh + (long)batch * 262144;
    const ushort_t* Blb = Bl + (long)batch * 262144;

    const int srow = wave * 16 + (lane >> 2);
    const int koff = (lane & 3) * 8;

    f32x4 acc[4];
    #pragma unroll
    for (int j = 0; j < 4; ++j) acc[j] = (f32x4){0.f, 0.f, 0.f, 0.f};

    auto STAGEX = [&](int buf, int kt) {
        #pragma unroll
        for (int kc = 0; kc < 2; ++kc) {
            const int kg = k0 + kt + kc * 32 + koff;
            gl_lds16(&Ab [(long)(m0 + srow) * 4096 + kg], &stg[buf * 8192 + (0 * 2 + kc) * 2048 + wave * 512]);
            gl_lds16(&Alb[(long)(m0 + srow) * 4096 + kg], &stg[buf * 8192 + (1 * 2 + kc) * 2048 + wave * 512]);
        }
    };

    STAGEX(0, 0);
    __syncthreads();
    int cur = 0;

    for (int kt = 0; kt < 512; kt += 64) {
        if (kt + 64 < 512) STAGEX(cur ^ 1, kt + 64);
        #pragma unroll
        for (int kc = 0; kc < 2; ++kc) {
            bf16x8 ah = *(const bf16x8*)&stg[cur * 8192 + (0 * 2 + kc) * 2048 + (wave * 16 + lr) * 32 + quad * 8];
            bf16x8 al = *(const bf16x8*)&stg[cur * 8192 + (1 * 2 + kc) * 2048 + (wave * 16 + lr) * 32 + quad * 8];
            const int kg = k0 + kt + kc * 32 + quad * 8;
            #pragma unroll
            for (int j = 0; j < 4; ++j) {
                const long boff = (long)(j * 16 + lr) * 4096 + kg;
                bf16x8 bh = *(const bf16x8*)&Bb [boff];
                bf16x8 bl = *(const bf16x8*)&Blb[boff];
                acc[j] = __builtin_amdgcn_mfma_f32_16x16x32_bf16(ah, bh, acc[j], 0, 0, 0);
                acc[j] = __builtin_amdgcn_mfma_f32_16x16x32_bf16(ah, bl, acc[j], 0, 0, 0);
                acc[j] = __builtin_amdgcn_mfma_f32_16x16x32_bf16(al, bh, acc[j], 0, 0, 0);
            }
        }
        __syncthreads();
        cur ^= 1;
    }

    float* Cb = part + ((long)blockIdx.x * Bcnt + batch) * 32768;
    #pragma unroll
    for (int j = 0; j < 4; ++j) {
        const int col = j * 16 + lr;
        #pragma unroll
        for (int r = 0; r < 4; ++r)
            Cb[(long)(m0 + wave * 16 + quad * 4 + r) * 64 + col] = acc[j][r];
    }
}

// =====================================================================
// Fused bases step. grid (C/64, B).
// MODE 0 (prep): bases -> bt hi/lo + btb Gram partials
// MODE 1 (full): reduce xc + ctc partials inline, mu-update bases, bt + btb
// =====================================================================
template<int MODE>
__global__ __launch_bounds__(256) void bases_step(
    const float* __restrict__ xc_part,   // [8][B][512][64]
    const float* __restrict__ ctc_part,  // [64][B][4096]
    float* __restrict__ bases,           // [B][512][64]
    ushort_t* __restrict__ bth, ushort_t* __restrict__ btl, // [B][64][512]
    float* __restrict__ btb_part,        // [8][B][4096]
    int Bcnt)
{
    __shared__ char smem[16640 * 2 + 18432];
    float* bnL  = (float*)smem;                  // [64][65]
    float* ctcL = (float*)(smem + 16640);        // [64][65]
    ushort_t* btLh = (ushort_t*)(smem + 33280);  // [64][72]
    ushort_t* btLl = btLh + 64 * 72;
    float* basesL = (float*)(smem + 33280);      // overlays btL (phase 1 only)

    const int b = blockIdx.y, c0 = blockIdx.x * 64;
    const int tid = threadIdx.x;
    float* basesB = bases + (long)b * 32768 + (long)c0 * 64;

    if (MODE == 1) {
        for (int i = tid; i < 4096; i += 256) {
            const int c = i >> 6, r = i & 63;
            basesL[c * 65 + r] = basesB[i];
            float cv = 0.f;
            #pragma unroll 8
            for (int ch = 0; ch < 64; ++ch)
                cv += ctc_part[((long)ch * Bcnt + b) * 4096 + i];
            ctcL[c * 65 + r] = cv;
            float v = 0.f;
            #pragma unroll
            for (int s0 = 0; s0 < 8; ++s0)
                v += xc_part[((long)s0 * Bcnt + b) * 32768 + (long)(c0 + c) * 64 + r];
            bnL[c * 65 + r] = v;
        }
        __syncthreads();
        for (int i = tid; i < 4096; i += 256) {
            const int c = i >> 6, r = i & 63;
            float denom = 0.f;
            #pragma unroll 8
            for (int s = 0; s < 64; ++s)
                denom = fmaf(basesL[c * 65 + s], ctcL[s * 65 + r], denom);
            float bnew = basesL[c * 65 + r] * bnL[c * 65 + r] / (denom + NMF_EPS);
            bnL[c * 65 + r] = bnew;
            basesB[i] = bnew;
        }
        __syncthreads();
    } else {
        for (int i = tid; i < 4096; i += 256)
            bnL[(i >> 6) * 65 + (i & 63)] = basesB[i];
        __syncthreads();
    }

    for (int i = tid; i < 4096; i += 256) {
        const int r = i >> 6, cc = i & 63;
        float v = bnL[cc * 65 + r];
        ushort_t h = f2bf(v);
        ushort_t l = f2bf(v - bf2f(h));
        btLh[r * 72 + cc] = h;
        btLl[r * 72 + cc] = l;
        bth[(long)b * 32768 + (long)r * 512 + c0 + cc] = h;
        btl[(long)b * 32768 + (long)r * 512 + c0 + cc] = l;
    }
    __syncthreads();

    const int wave = tid >> 6, lane = tid & 63;
    const int quad = lane >> 4, lr = lane & 15;
    f32x4 acg[4];
    #pragma unroll
    for (int j = 0; j < 4; ++j) acg[j] = (f32x4){0.f, 0.f, 0.f, 0.f};
    #pragma unroll
    for (int kk = 0; kk < 64; kk += 32) {
        bf16x8 ah = *(const bf16x8*)&btLh[(wave * 16 + lr) * 72 + kk + quad * 8];
        bf16x8 al = *(const bf16x8*)&btLl[(wave * 16 + lr) * 72 + kk + quad * 8];
        #pragma unroll
        for (int j = 0; j < 4; ++j) {
            bf16x8 bh = *(const bf16x8*)&btLh[(j * 16 + lr) * 72 + kk + quad * 8];
            bf16x8 bl = *(const bf16x8*)&btLl[(j * 16 + lr) * 72 + kk + quad * 8];
            acg[j] = __builtin_amdgcn_mfma_f32_16x16x32_bf16(ah, bh, acg[j], 0, 0, 0);
            acg[j] = __builtin_amdgcn_mfma_f32_16x16x32_bf16(ah, bl, acg[j], 0, 0, 0);
            acg[j] = __builtin_amdgcn_mfma_f32_16x16x32_bf16(al, bh, acg[j], 0, 0, 0);
        }
    }
    float* gp = btb_part + ((long)blockIdx.x * Bcnt + b) * 4096;
    #pragma unroll
    for (int j = 0; j < 4; ++j)
        #pragma unroll
        for (int r = 0; r < 4; ++r)
            gp[(wave * 16 + quad * 4 + r) * 64 + j * 16 + lr] = acg[j][r];
}

// =====================================================================
// fp32 tiled GEMM (cheese ops only): EPI 0 plain; 4 relu(+bias)->bf16 [n][m]
// =====================================================================
constexpr int BM = 64, BN = 64, BK = 16;

template<int ALAY, int BLAY, int EPI>
__global__ __launch_bounds__(256) void gemm_kernel(
    const float* __restrict__ A, const float* __restrict__ B, float* __restrict__ C,
    int Kchunk, int kchunks,
    int lda, int ldb, int ldc,
    long sA, long sB, long sC,
    const float* __restrict__ bias)
{
    __shared__ float As[BK][BM + 4];
    __shared__ float Bs[BK][BN + 4];

    const int batch = blockIdx.z;
    const float* Ab = A + (long)batch * sA;
    const float* Bb = B + (long)batch * sB;

    const int m0  = blockIdx.y * BM;
    const int n0  = blockIdx.x * BN;
    const int tid = threadIdx.x;
    const int ty  = tid >> 4, tx = tid & 15;

    float acc[4][4] = {};

    for (int kt = 0; kt < Kchunk; kt += BK) {
        if (ALAY == 0) {
            const int m = tid >> 2, k4 = (tid & 3) << 2;
            float4 v = *(const float4*)&Ab[(long)(m0 + m) * lda + (kt + k4)];
            As[k4 + 0][m] = v.x; As[k4 + 1][m] = v.y;
            As[k4 + 2][m] = v.z; As[k4 + 3][m] = v.w;
        } else {
            const int k = tid >> 4, m4 = (tid & 15) << 2;
            float4 v = *(const float4*)&Ab[(long)(kt + k) * lda + (m0 + m4)];
            *(float4*)&As[k][m4] = v;
        }
        if (BLAY == 0) {
            const int k = tid >> 4, n4 = (tid & 15) << 2;
            float4 v = *(const float4*)&Bb[(long)(kt + k) * ldb + (n0 + n4)];
            *(float4*)&Bs[k][n4] = v;
        } else {
            const int n = tid >> 2, k4 = (tid & 3) << 2;
            float4 v = *(const float4*)&Bb[(long)(n0 + n) * ldb + (kt + k4)];
            Bs[k4 + 0][n] = v.x; Bs[k4 + 1][n] = v.y;
            Bs[k4 + 2][n] = v.z; Bs[k4 + 3][n] = v.w;
        }
        __syncthreads();
        #pragma unroll
        for (int k = 0; k < BK; ++k) {
            float4 a4 = *(const float4*)&As[k][ty << 2];
            float4 b4 = *(const float4*)&Bs[k][tx << 2];
            float av[4] = {a4.x, a4.y, a4.z, a4.w};
            float bv[4] = {b4.x, b4.y, b4.z, b4.w};
            #pragma unroll
            for (int i = 0; i < 4; ++i)
                #pragma unroll
                for (int j = 0; j < 4; ++j)
                    acc[i][j] = fmaf(av[i], bv[j], acc[i][j]);
        }
        __syncthreads();
    }

    const int mb = m0 + (ty << 2), nb = n0 + (tx << 2);
    if (EPI == 4) {
        ushort_t* Cu = (ushort_t*)C + (long)batch * sC;
        #pragma unroll
        for (int j = 0; j < 4; ++j) {
            ushort_t pk[4];
            #pragma unroll
            for (int i = 0; i < 4; ++i)
                pk[i] = f2bf(fmaxf(acc[i][j] + bias[mb + i], 0.f));
            *(ushort4*)&Cu[(long)(nb + j) * ldc + mb] =
                make_ushort4(pk[0], pk[1], pk[2], pk[3]);
        }
    } else {
        float* Cb = C + (long)batch * sC;
        #pragma unroll
        for (int i = 0; i < 4; ++i) {
            float4 o = make_float4(acc[i][0], acc[i][1], acc[i][2], acc[i][3]);
            *(float4*)&Cb[(long)(mb + i) * ldc + nb] = o;
        }
    }
}

// ---------- casts / transposes ----------
__global__ __launch_bounds__(256) void cast_x_t(const float* __restrict__ x,
                                                ushort_t* __restrict__ hi,
                                                ushort_t* __restrict__ lo)
{
    __shared__ float t[64][65];
    const int b = blockIdx.z, c0 = blockIdx.y * 64, n0 = blockIdx.x * 64;
    const int tid = threadIdx.x, tx = tid & 63, ty = tid >> 6;
    const float* xb = x + (long)b * 512 * 4096;
    #pragma unroll 4
    for (int s = ty; s < 64; s += 4)
        t[s][tx] = xb[(long)(c0 + s) * 4096 + n0 + tx];
    __syncthreads();
    #pragma unroll 4
    for (int s = ty; s < 64; s += 4) {
        float v = t[tx][s];
        long idx = (long)b * 2097152 + (long)(n0 + s) * 512 + c0 + tx;
        ushort_t h = f2bf(v);
        hi[idx] = h;
        lo[idx] = f2bf(v - bf2f(h));
    }
}

__global__ __launch_bounds__(256) void nd2dn(const ushort_t* __restrict__ hi,
                                             const ushort_t* __restrict__ lo,
                                             ushort_t* __restrict__ dhi,
                                             ushort_t* __restrict__ dlo)
{
    __shared__ unsigned int t[64][65];
    const int b = blockIdx.z, n0 = blockIdx.x * 64, c0 = blockIdx.y * 64;
    const int tx = threadIdx.x & 63, ty = threadIdx.x >> 6;
    const long base = (long)b * 2097152;
    #pragma unroll 4
    for (int s = ty; s < 64; s += 4) {
        long idx = base + (long)(n0 + s) * 512 + c0 + tx;
        t[s][tx] = (unsigned)hi[idx] | ((unsigned)lo[idx] << 16);
    }
    __syncthreads();
    #pragma unroll 4
    for (int s = ty; s < 64; s += 4) {
        unsigned v = t[tx][s];
        long idx = base + (long)(c0 + s) * 4096 + n0 + tx;
        dhi[idx] = (ushort_t)(v & 0xffffu);
        dlo[idx] = (ushort_t)(v >> 16);
    }
}

__global__ void cast_w_split(const float* __restrict__ w, ushort_t* __restrict__ hi,
                             ushort_t* __restrict__ lo, int n)
{
    int i = blockIdx.x * 256 + threadIdx.x;
    if (i < n) {
        float v = w[i];
        ushort_t h = f2bf(v);
        hi[i] = h;
        lo[i] = f2bf(v - bf2f(h));
    }
}

__global__ void cast_w_plain(const float* __restrict__ w, ushort_t* __restrict__ o, int n)
{
    int i = blockIdx.x * 256 + threadIdx.x;
    if (i < n) o[i] = f2bf(w[i]);
}

__global__ __launch_bounds__(1024) void l2norm_kernel(const float* __restrict__ b0,
                                                      float* __restrict__ bases)
{
    __shared__ float part[16][64];
    const int b = blockIdx.x;
    const int tid = threadIdx.x;
    const int r = tid & 63, slice = tid >> 6;
    const float* src = b0 + (long)b * 512 * 64;
    float* dst = bases + (long)b * 512 * 64;
    float s = 0.f;
    #pragma unroll 4
    for (int d = slice; d < 512; d += 16) {
        float v = src[d * 64 + r];
        s = fmaf(v, v, s);
    }
    part[slice][r] = s;
    __syncthreads();
    if (slice == 0) {
        float t = 0.f;
        #pragma unroll
        for (int i = 0; i < 16; ++i) t += part[i][r];
        part[0][r] = 1.0f / fmaxf(sqrtf(t), 1e-12f);
    }
    __syncthreads();
    const float inv = part[0][r];
    #pragma unroll 4
    for (int d = slice; d < 512; d += 16)
        dst[d * 64 + r] = src[d * 64 + r] * inv;
}

extern "C" void kernel_launch(void* const* d_in, const int* in_sizes, int n_in,
                              void* d_out, int out_size, void* d_ws, size_t ws_size,
                              hipStream_t stream)
{
    const float* x_in     = (const float*)d_in[0];
    const float* bases0   = (const float*)d_in[1];
    const float* w_lower  = (const float*)d_in[2];
    const float* b_lower  = (const float*)d_in[3];
    const float* w_cheese = (const float*)d_in[4];
    const float* b_cheese = (const float*)d_in[5];
    const float* w_upper  = (const float*)d_in[6];
    const float* csc      = (const float*)d_in[7];
    const float* cham     = (const float*)d_in[8];
    float* out = (float*)d_out;

    const int B = 8, C = 512, N = 4096, R = 64;
    const long sCN = (long)C * N;
    const long sNC = (long)N * C;
    const long sNR = (long)N * R, sCR = (long)C * R;

    // ---- workspace layout (bytes) ----
    char* w = (char*)d_ws;
    ushort_t* X_nd_hi  = (ushort_t*)w;  w += 33554432;  // [B,N,C]
    ushort_t* xt_hi    = (ushort_t*)w;  w += 33554432;  // x^T; later X_dn_hi
    ushort_t* xt_lo    = (ushort_t*)w;  w += 33554432;  // x^T; later X_dn_lo
    float*    coef     = (float*)w;     w += 8388608;   // [B,N,R]
    ushort_t* ct_hi    = (ushort_t*)w;  w += 4194304;   // [B,R,N]
    ushort_t* ct_lo    = (ushort_t*)w;  w += 4194304;
    float*    ctc_part = (float*)w;     w += 8388608;   // [64][B][4096]
    float*    xc_part  = (float*)w;     w += 8388608;   // [8][B][512][64]
    float*    btb_part = (float*)w;     w += 1048576;   // [8][B][4096]
    float*    bases    = (float*)w;     w += 1048576;   // [B,C,R]
    float*    WcB      = (float*)w;     w += 1048576;   // [B,C,R]
    ushort_t* bt_hi    = (ushort_t*)w;  w += 524288;    // [B,R,C]
    ushort_t* bt_lo    = (ushort_t*)w;  w += 524288;
    ushort_t* wl_hi    = (ushort_t*)w;  w += 524288;
    ushort_t* wl_lo    = (ushort_t*)w;  w += 524288;
    ushort_t* w_up     = (ushort_t*)w;  w += 524288;

    // X_lo plane [B,N,C]: keep d_out WRITE-ONCE (final dispatch only) by
    // placing the scratch plane in the workspace when it fits. Branch is on
    // ws_size only — identical every call, graph-capture-safe.
    ushort_t* X_nd_lo;
    {
        const size_t used = (size_t)(w - (char*)d_ws);
        if (ws_size >= used + 33554432UL) {
            X_nd_lo = (ushort_t*)w;  w += 33554432;
        } else {
            X_nd_lo = (ushort_t*)d_out;  // dead before final out write
        }
    }

    ushort_t* X_dn_hi  = xt_hi;
    ushort_t* X_dn_lo  = xt_lo;
    ushort_t* cheese_t = X_nd_hi;           // X_nd dead after final coef_step

    const dim3 blk(256);

    // init
    l2norm_kernel<<<dim3(B), dim3(1024), 0, stream>>>(bases0, bases);
    bases_step<0><<<dim3(C / 64, B), blk, 0, stream>>>(
        nullptr, nullptr, bases, bt_hi, bt_lo, btb_part, B);
    cast_w_split<<<dim3(1024), blk, 0, stream>>>(w_lower, wl_hi, wl_lo, C * C);
    cast_w_plain<<<dim3(1024), blk, 0, stream>>>(w_upper, w_up, C * C);
    cast_x_t<<<dim3(N / 64, C / 64, B), blk, 0, stream>>>(x_in, xt_hi, xt_lo);

    // X = relu(w_lower @ x + b_lower) -> bf16 hi/lo [n][c]
    mfma_gemm<1, 2><<<dim3(N / 128, C / 128, B), blk, 0, stream>>>(
        wl_hi, wl_lo, xt_hi, xt_lo, nullptr, X_nd_hi, X_nd_lo,
        C, N, C, sNC, sNC, b_lower, nullptr, 0L, nullptr, nullptr);
    nd2dn<<<dim3(N / 64, C / 64, B), blk, 0, stream>>>(X_nd_hi, X_nd_lo, X_dn_hi, X_dn_lo);

    // coef init (softmax)
    coef_step<0><<<dim3(N / 64, B), blk, 0, stream>>>(
        X_nd_hi, X_nd_lo, bt_hi, bt_lo, btb_part, coef, ct_hi, ct_lo, ctc_part, B);

    for (int step = 0; step < 6; ++step) {
        coef_step<1><<<dim3(N / 64, B), blk, 0, stream>>>(
            X_nd_hi, X_nd_lo, bt_hi, bt_lo, btb_part, coef, ct_hi, ct_lo, ctc_part, B);
        xc_partial<<<dim3(8, C / 64, B), blk, 0, stream>>>(
            X_dn_hi, X_dn_lo, ct_hi, ct_lo, xc_part, B);
        bases_step<1><<<dim3(C / 64, B), blk, 0, stream>>>(
            xc_part, ctc_part, bases, bt_hi, bt_lo, btb_part, B);
    }

    // final differentiable coef refinement (no ct/ctc tail)
    coef_step<2><<<dim3(N / 64, B), blk, 0, stream>>>(
        X_nd_hi, X_nd_lo, bt_hi, bt_lo, btb_part, coef, ct_hi, ct_lo, ctc_part, B);

    // cheese via associativity
    gemm_kernel<0, 0, 0><<<dim3(1, C / BM, B), blk, 0, stream>>>(
        w_cheese, bases, WcB, C, 1, C, R, R, 0L, sCR, sCR, nullptr);
    gemm_kernel<0, 1, 4><<<dim3(N / BN, C / BM, B), blk, 0, stream>>>(
        WcB, coef, (float*)cheese_t, R, 1, R, R, C, sCR, sNR, sNC, b_cheese);

    // out = relu(ham * (w_upper @ cheese) + sc * x)
    mfma_gemm<0, 3><<<dim3(N / 128, C / 128, B), blk, 0, stream>>>(
        w_up, nullptr, cheese_t, nullptr, out, nullptr, nullptr,
        C, N, C, sNC, sCN, nullptr, x_in, sCN, cham, csc);
}

// Round 3
// 768.280 us; speedup vs baseline: 1.6714x; 1.6714x over previous
//
#include <hip/hip_runtime.h>

#define NMF_EPS 1e-6f

typedef unsigned short ushort_t;
typedef __attribute__((ext_vector_type(8))) short bf16x8;
typedef __attribute__((ext_vector_type(4))) float f32x4;

__device__ __forceinline__ ushort_t f2bf(float f) {
    unsigned int u = __float_as_uint(f);
    return (ushort_t)((u + 0x7FFFu + ((u >> 16) & 1u)) >> 16);
}
__device__ __forceinline__ float bf2f(ushort_t h) {
    return __uint_as_float(((unsigned int)h) << 16);
}

__device__ __forceinline__ void gl_lds16(const ushort_t* g, ushort_t* l) {
    __builtin_amdgcn_global_load_lds(
        (const __attribute__((address_space(1))) unsigned int*)g,
        (__attribute__((address_space(3))) unsigned int*)l,
        16, 0, 0);
}

// =====================================================================
// Big MFMA GEMM (lower / upper). C[m,n] = op(sum_k A[m,k]*B[n,k])
// Double-buffered LDS, single barrier per K-step (stage t+1 before
// compute t; __syncthreads' implicit vmcnt(0) drain is the fence).
// EPI 2: relu(acc+bias[m]) -> bf16 hi/lo TRANSPOSED [n][M] (LDS transpose)
// EPI 3: relu(ham*acc + sc*res[m,n]) -> fp32 [M,N]
// =====================================================================
template<int SPLIT, int EPI>
__global__ __launch_bounds__(256) void mfma_gemm(
    const ushort_t* __restrict__ Ah, const ushort_t* __restrict__ Al,
    const ushort_t* __restrict__ Bh, const ushort_t* __restrict__ Bl,
    float* __restrict__ C, ushort_t* __restrict__ Chi, ushort_t* __restrict__ Clo,
    int M, int N, int K,
    long sB, long sC,
    const float* __restrict__ bias,
    const float* __restrict__ res, long sRes,
    const float* __restrict__ hamp, const float* __restrict__ scp)
{
    constexpr int SB = SPLIT ? 32768 : 16384;   // bytes per dbuf slot
    __shared__ char smem[2 * SB];

    const int tid  = threadIdx.x;
    const int wave = tid >> 6, lane = tid & 63;
    const int quad = lane >> 4, lr = lane & 15;
    const int batch = blockIdx.z;
    const int m0 = blockIdx.y * 128, n0 = blockIdx.x * 128;

    const ushort_t* Bhb = Bh + (long)batch * sB;
    const ushort_t* Blb = SPLIT ? (Bl + (long)batch * sB) : nullptr;

    f32x4 acc[4][4];
    #pragma unroll
    for (int i = 0; i < 4; ++i)
        #pragma unroll
        for (int j = 0; j < 4; ++j)
            acc[i][j] = (f32x4){0.f, 0.f, 0.f, 0.f};

    const int q   = wave * 2;
    const int ra0 = (q + 0) * 16 + (lane >> 2);
    const int ra1 = (q + 1) * 16 + (lane >> 2);
    const int ko  = (lane & 3) * 8;
    const int wm = (wave & 1) * 64, wn = (wave >> 1) * 64;

    auto STAGE = [&](int buf, int k0) {
        char* base = smem + buf * SB;
        ushort_t* dAh = (ushort_t*)base;
        ushort_t* dBh = (ushort_t*)(base + 8192);
        gl_lds16(&Ah [(long)(m0 + ra0) * K + k0 + ko], &dAh[(q + 0) * 512]);
        gl_lds16(&Ah [(long)(m0 + ra1) * K + k0 + ko], &dAh[(q + 1) * 512]);
        gl_lds16(&Bhb[(long)(n0 + ra0) * K + k0 + ko], &dBh[(q + 0) * 512]);
        gl_lds16(&Bhb[(long)(n0 + ra1) * K + k0 + ko], &dBh[(q + 1) * 512]);
        if constexpr (SPLIT) {
            ushort_t* dAl = (ushort_t*)(base + 16384);
            ushort_t* dBl = (ushort_t*)(base + 24576);
            gl_lds16(&Al [(long)(m0 + ra0) * K + k0 + ko], &dAl[(q + 0) * 512]);
            gl_lds16(&Al [(long)(m0 + ra1) * K + k0 + ko], &dAl[(q + 1) * 512]);
            gl_lds16(&Blb[(long)(n0 + ra0) * K + k0 + ko], &dBl[(q + 0) * 512]);
            gl_lds16(&Blb[(long)(n0 + ra1) * K + k0 + ko], &dBl[(q + 1) * 512]);
        }
    };

    STAGE(0, 0);
    __syncthreads();
    int cur = 0;

    for (int k0 = 0; k0 < K; k0 += 32) {
        if (k0 + 32 < K) STAGE(cur ^ 1, k0 + 32);

        char* base = smem + cur * SB;
        ushort_t* sAh = (ushort_t*)base;
        ushort_t* sBh = (ushort_t*)(base + 8192);

        bf16x8 af[4], bfr[4], afl[4], bfl[4];
        #pragma unroll
        for (int i = 0; i < 4; ++i)
            af[i] = *(const bf16x8*)&sAh[(wm + i * 16 + lr) * 32 + quad * 8];
        #pragma unroll
        for (int j = 0; j < 4; ++j)
            bfr[j] = *(const bf16x8*)&sBh[(wn + j * 16 + lr) * 32 + quad * 8];
        if constexpr (SPLIT) {
            ushort_t* sAl = (ushort_t*)(base + 16384);
            ushort_t* sBl = (ushort_t*)(base + 24576);
            #pragma unroll
            for (int i = 0; i < 4; ++i)
                afl[i] = *(const bf16x8*)&sAl[(wm + i * 16 + lr) * 32 + quad * 8];
            #pragma unroll
            for (int j = 0; j < 4; ++j)
                bfl[j] = *(const bf16x8*)&sBl[(wn + j * 16 + lr) * 32 + quad * 8];
        }

        #pragma unroll
        for (int i = 0; i < 4; ++i)
            #pragma unroll
            for (int j = 0; j < 4; ++j) {
                acc[i][j] = __builtin_amdgcn_mfma_f32_16x16x32_bf16(af[i], bfr[j], acc[i][j], 0, 0, 0);
                if constexpr (SPLIT) {
                    acc[i][j] = __builtin_amdgcn_mfma_f32_16x16x32_bf16(af[i], bfl[j], acc[i][j], 0, 0, 0);
                    acc[i][j] = __builtin_amdgcn_mfma_f32_16x16x32_bf16(afl[i], bfr[j], acc[i][j], 0, 0, 0);
                }
            }
        __syncthreads();
        cur ^= 1;
    }

    if (EPI == 2) {
        ushort_t* Hh = Chi + (long)batch * sC;
        ushort_t* Hl = Clo + (long)batch * sC;
        unsigned int* slab = (unsigned int*)smem;  // [128 n][64 m] u32
        #pragma unroll
        for (int p = 0; p < 2; ++p) {
            __syncthreads();
            if ((wave & 1) == p) {
                #pragma unroll
                for (int i = 0; i < 4; ++i) {
                    const int mb = m0 + p * 64 + i * 16 + quad * 4;
                    #pragma unroll
                    for (int j = 0; j < 4; ++j) {
                        const int nl = wn + j * 16 + lr;
                        #pragma unroll
                        for (int r = 0; r < 4; ++r) {
                            float v = fmaxf(acc[i][j][r] + bias[mb + r], 0.f);
                            ushort_t h = f2bf(v);
                            ushort_t l = f2bf(v - bf2f(h));
                            slab[nl * 64 + (i * 16 + quad * 4 + r)] =
                                (unsigned)h | ((unsigned)l << 16);
                        }
                    }
                }
            }
            __syncthreads();
            for (int idx = tid; idx < 8192; idx += 256) {
                const int nl = idx >> 6, ml = idx & 63;
                unsigned u = slab[idx];
                const long off = (long)(n0 + nl) * M + m0 + p * 64 + ml;
                Hh[off] = (ushort_t)(u & 0xffffu);
                Hl[off] = (ushort_t)(u >> 16);
            }
        }
    } else {
        const float hm = *hamp, sc = *scp;
        float* Cb = C + (long)batch * sC;
        #pragma unroll
        for (int i = 0; i < 4; ++i) {
            #pragma unroll
            for (int j = 0; j < 4; ++j) {
                const int mbase = m0 + wm + i * 16 + quad * 4;
                const int n     = n0 + wn + j * 16 + lr;
                #pragma unroll
                for (int r = 0; r < 4; ++r) {
                    float rv = res[(long)batch * sRes + (long)(mbase + r) * N + n];
                    Cb[(long)(mbase + r) * N + n] = fmaxf(fmaf(hm, acc[i][j][r], sc * rv), 0.f);
                }
            }
        }
    }
}

// =====================================================================
// Fused coef step. grid (N/64, B), 256 thr.
// All four streams (X hi/lo, bt hi/lo) staged to LDS as in R1, but in
// BK=32 ping-pong chunks: stage chunk t+1 into the other half-buffer
// before computing chunk t; one barrier per chunk. Same LDS as R1 (50KB).
// MODE 0 (INIT): coef = softmax_r(X^T bases)
// MODE 1 (MU):   coef = coef*xtb/(coef@btb+eps); writes ct hi/lo + ctc partials
// MODE 2 (MU, final): as MODE 1 but skips the dead ct/ctc tail
// =====================================================================
template<int MODE>
__global__ __launch_bounds__(256) void coef_step(
    const ushort_t* __restrict__ Xh, const ushort_t* __restrict__ Xl,   // [B][N][512]
    const ushort_t* __restrict__ bth, const ushort_t* __restrict__ btl, // [B][64][512]
    const float* __restrict__ btb_part,   // [8][B][4096]
    float* __restrict__ coef,             // [B][N][64]
    ushort_t* __restrict__ cth, ushort_t* __restrict__ ctl, // [B][64][N]
    float* __restrict__ ctc_part,         // [64][B][4096]
    int Bcnt)
{
    constexpr bool MU = (MODE >= 1);
    __shared__ char smem[32768 + 18432];
    ushort_t* stg = (ushort_t*)smem;             // [2 buf][4 stream][2048]
    ushort_t* gLh = (ushort_t*)(smem + 32768);   // [64][72] btb hi (later ct hi)
    ushort_t* gLl = gLh + 64 * 72;               // btb lo (later ct lo)

    const int tid = threadIdx.x, wave = tid >> 6, lane = tid & 63;
    const int quad = lane >> 4, lr = lane & 15;
    const int b = blockIdx.y, n0 = blockIdx.x * 64;

    const ushort_t* Xhb  = Xh  + (long)b * 2097152 + (long)n0 * 512;
    const ushort_t* Xlb  = Xl  + (long)b * 2097152 + (long)n0 * 512;
    const ushort_t* bthb = bth + (long)b * 32768;
    const ushort_t* btlb = btl + (long)b * 32768;
    float* coefB = coef + (long)b * 262144 + (long)n0 * 64;

    if (MU) {
        // reduce btb partials -> LDS (hi/lo)
        for (int i = tid; i < 4096; i += 256) {
            const int r = i >> 6, s = i & 63;
            float v = 0.f;
            #pragma unroll
            for (int c = 0; c < 8; ++c)
                v += btb_part[((long)c * Bcnt + b) * 4096 + i];
            ushort_t h = f2bf(v);
            gLh[r * 72 + s] = h;
            gLl[r * 72 + s] = f2bf(v - bf2f(h));
        }
    }

    // ---- xtb via MFMA, BK=32 ping-pong ----
    const int srow = wave * 16 + (lane >> 2);
    const int koff = (lane & 3) * 8;
    f32x4 accx[4];
    #pragma unroll
    for (int j = 0; j < 4; ++j) accx[j] = (f32x4){0.f, 0.f, 0.f, 0.f};

    auto STAGEX = [&](int buf, int kc) {
        const int kg = kc * 32 + koff;
        gl_lds16(&Xhb [(long)srow * 512 + kg], &stg[buf * 8192 + 0 * 2048 + wave * 512]);
        gl_lds16(&Xlb [(long)srow * 512 + kg], &stg[buf * 8192 + 1 * 2048 + wave * 512]);
        gl_lds16(&bthb[(long)srow * 512 + kg], &stg[buf * 8192 + 2 * 2048 + wave * 512]);
        gl_lds16(&btlb[(long)srow * 512 + kg], &stg[buf * 8192 + 3 * 2048 + wave * 512]);
    };

    STAGEX(0, 0);
    __syncthreads();
    int cur = 0;

    for (int kc = 0; kc < 16; ++kc) {
        if (kc + 1 < 16) STAGEX(cur ^ 1, kc + 1);
        bf16x8 ah = *(const bf16x8*)&stg[cur * 8192 + 0 * 2048 + (wave * 16 + lr) * 32 + quad * 8];
        bf16x8 al = *(const bf16x8*)&stg[cur * 8192 + 1 * 2048 + (wave * 16 + lr) * 32 + quad * 8];
        #pragma unroll
        for (int j = 0; j < 4; ++j) {
            bf16x8 bh = *(const bf16x8*)&stg[cur * 8192 + 2 * 2048 + (j * 16 + lr) * 32 + quad * 8];
            bf16x8 bl = *(const bf16x8*)&stg[cur * 8192 + 3 * 2048 + (j * 16 + lr) * 32 + quad * 8];
            accx[j] = __builtin_amdgcn_mfma_f32_16x16x32_bf16(ah, bh, accx[j], 0, 0, 0);
            accx[j] = __builtin_amdgcn_mfma_f32_16x16x32_bf16(ah, bl, accx[j], 0, 0, 0);
            accx[j] = __builtin_amdgcn_mfma_f32_16x16x32_bf16(al, bh, accx[j], 0, 0, 0);
        }
        __syncthreads();
        cur ^= 1;
    }

    float cnew[4][4]; // [j][reg]
    if (MU) {
        // denom = coef @ btb (split MFMA; coef A-frags direct from global fp32)
        f32x4 accd[4];
        #pragma unroll
        for (int j = 0; j < 4; ++j) accd[j] = (f32x4){0.f, 0.f, 0.f, 0.f};
        #pragma unroll
        for (int kk = 0; kk < 2; ++kk) {
            const float* cp = &coefB[(wave * 16 + lr) * 64 + kk * 32 + quad * 8];
            float4 cA = *(const float4*)cp;
            float4 cB = *(const float4*)(cp + 4);
            float cv[8] = {cA.x, cA.y, cA.z, cA.w, cB.x, cB.y, cB.z, cB.w};
            bf16x8 ah, al;
            #pragma unroll
            for (int e = 0; e < 8; ++e) {
                ushort_t h = f2bf(cv[e]);
                ((short*)&ah)[e] = (short)h;
                ((short*)&al)[e] = (short)f2bf(cv[e] - bf2f(h));
            }
            #pragma unroll
            for (int j = 0; j < 4; ++j) {
                bf16x8 bh = *(const bf16x8*)&gLh[(j * 16 + lr) * 72 + kk * 32 + quad * 8];
                bf16x8 bl = *(const bf16x8*)&gLl[(j * 16 + lr) * 72 + kk * 32 + quad * 8];
                accd[j] = __builtin_amdgcn_mfma_f32_16x16x32_bf16(ah, bh, accd[j], 0, 0, 0);
                accd[j] = __builtin_amdgcn_mfma_f32_16x16x32_bf16(ah, bl, accd[j], 0, 0, 0);
                accd[j] = __builtin_amdgcn_mfma_f32_16x16x32_bf16(al, bh, accd[j], 0, 0, 0);
            }
        }
        #pragma unroll
        for (int j = 0; j < 4; ++j)
            #pragma unroll
            for (int r = 0; r < 4; ++r) {
                float cold = coefB[(wave * 16 + quad * 4 + r) * 64 + j * 16 + lr];
                cnew[j][r] = cold * accx[j][r] / (accd[j][r] + NMF_EPS);
            }
    } else {
        #pragma unroll
        for (int r = 0; r < 4; ++r) {
            float m = fmaxf(fmaxf(accx[0][r], accx[1][r]), fmaxf(accx[2][r], accx[3][r]));
            #pragma unroll
            for (int off = 1; off < 16; off <<= 1) m = fmaxf(m, __shfl_xor(m, off, 64));
            float e[4], s = 0.f;
            #pragma unroll
            for (int j = 0; j < 4; ++j) { e[j] = __expf(accx[j][r] - m); s += e[j]; }
            #pragma unroll
            for (int off = 1; off < 16; off <<= 1) s += __shfl_xor(s, off, 64);
            float inv = 1.f / s;
            #pragma unroll
            for (int j = 0; j < 4; ++j) cnew[j][r] = e[j] * inv;
        }
    }

    #pragma unroll
    for (int j = 0; j < 4; ++j)
        #pragma unroll
        for (int r = 0; r < 4; ++r)
            coefB[(wave * 16 + quad * 4 + r) * 64 + j * 16 + lr] = cnew[j][r];

    if (MODE != 1) return;

    __syncthreads();  // btb dead; overlay ct on gL
    #pragma unroll
    for (int j = 0; j < 4; ++j)
        #pragma unroll
        for (int r = 0; r < 4; ++r) {
            const int nl = wave * 16 + quad * 4 + r;
            const int rr = j * 16 + lr;
            float v = cnew[j][r];
            ushort_t h = f2bf(v);
            gLh[rr * 72 + nl] = h;
            gLl[rr * 72 + nl] = f2bf(v - bf2f(h));
        }
    __syncthreads();
    for (int i = tid; i < 4096; i += 256) {
        const int r = i >> 6, nn = i & 63;
        cth[(long)b * 262144 + (long)r * 4096 + n0 + nn] = gLh[r * 72 + nn];
        ctl[(long)b * 262144 + (long)r * 4096 + n0 + nn] = gLl[r * 72 + nn];
    }
    // ctc Gram partials via MFMA
    f32x4 accc[4];
    #pragma unroll
    for (int j = 0; j < 4; ++j) accc[j] = (f32x4){0.f, 0.f, 0.f, 0.f};
    #pragma unroll
    for (int kk = 0; kk < 64; kk += 32) {
        bf16x8 ah = *(const bf16x8*)&gLh[(wave * 16 + lr) * 72 + kk + quad * 8];
        bf16x8 al = *(const bf16x8*)&gLl[(wave * 16 + lr) * 72 + kk + quad * 8];
        #pragma unroll
        for (int j = 0; j < 4; ++j) {
            bf16x8 bh = *(const bf16x8*)&gLh[(j * 16 + lr) * 72 + kk + quad * 8];
            bf16x8 bl = *(const bf16x8*)&gLl[(j * 16 + lr) * 72 + kk + quad * 8];
            accc[j] = __builtin_amdgcn_mfma_f32_16x16x32_bf16(ah, bh, accc[j], 0, 0, 0);
            accc[j] = __builtin_amdgcn_mfma_f32_16x16x32_bf16(ah, bl, accc[j], 0, 0, 0);
            accc[j] = __builtin_amdgcn_mfma_f32_16x16x32_bf16(al, bh, accc[j], 0, 0, 0);
        }
    }
    float* cp = ctc_part + ((long)blockIdx.x * Bcnt + b) * 4096;
    #pragma unroll
    for (int j = 0; j < 4; ++j)
        #pragma unroll
        for (int r = 0; r < 4; ++r)
            cp[(wave * 16 + quad * 4 + r) * 64 + j * 16 + lr] = accc[j][r];
}

// reduce ctc partials
__global__ __launch_bounds__(256) void ctc_reduce(const float* __restrict__ part,
                                                  float* __restrict__ ctc, int Bcnt)
{
    const int b = blockIdx.x >> 4;
    const int i = (blockIdx.x & 15) * 256 + threadIdx.x;
    float v = 0.f;
    #pragma unroll 8
    for (int c = 0; c < 64; ++c)
        v += part[((long)c * Bcnt + b) * 4096 + i];
    ctc[(long)b * 4096 + i] = v;
}

// xc split-K partials, BK=32 ping-pong: part[kc][b][c][r] = sum X[c,k]*ct[r,k]
// grid (8, C/64, B). All four streams LDS-staged (R1 addresses), dbuf chunks.
__global__ __launch_bounds__(256) void xc_partial(
    const ushort_t* __restrict__ Ah, const ushort_t* __restrict__ Al, // X_dn [B][512][4096]
    const ushort_t* __restrict__ Bh, const ushort_t* __restrict__ Bl, // ct  [B][64][4096]
    float* __restrict__ part, int Bcnt)
{
    __shared__ ushort_t stg[2 * 8192];   // [2 buf][4 stream][2048]
    const int tid = threadIdx.x, wave = tid >> 6, lane = tid & 63;
    const int quad = lane >> 4, lr = lane & 15;
    const int batch = blockIdx.z;
    const int m0 = blockIdx.y * 64;
    const int k0 = blockIdx.x * 512;

    const ushort_t* Ab  = Ah + (long)batch * 2097152;
    const ushort_t* Alb = Al + (long)batch * 2097152;
    const ushort_t* Bb  = Bh + (long)batch * 262144;
    const ushort_t* Blb = Bl + (long)batch * 262144;

    const int srow = wave * 16 + (lane >> 2);
    const int koff = (lane & 3) * 8;

    f32x4 acc[4];
    #pragma unroll
    for (int j = 0; j < 4; ++j) acc[j] = (f32x4){0.f, 0.f, 0.f, 0.f};

    auto STAGEX = [&](int buf, int kc) {
        const int kg = k0 + kc * 32 + koff;
        gl_lds16(&Ab [(long)(m0 + srow) * 4096 + kg], &stg[buf * 8192 + 0 * 2048 + wave * 512]);
        gl_lds16(&Alb[(long)(m0 + srow) * 4096 + kg], &stg[buf * 8192 + 1 * 2048 + wave * 512]);
        gl_lds16(&Bb [(long)srow * 4096 + kg], &stg[buf * 8192 + 2 * 2048 + wave * 512]);
        gl_lds16(&Blb[(long)srow * 4096 + kg], &stg[buf * 8192 + 3 * 2048 + wave * 512]);
    };

    STAGEX(0, 0);
    __syncthreads();
    int cur = 0;

    for (int kc = 0; kc < 16; ++kc) {
        if (kc + 1 < 16) STAGEX(cur ^ 1, kc + 1);
        bf16x8 ah = *(const bf16x8*)&stg[cur * 8192 + 0 * 2048 + (wave * 16 + lr) * 32 + quad * 8];
        bf16x8 al = *(const bf16x8*)&stg[cur * 8192 + 1 * 2048 + (wave * 16 + lr) * 32 + quad * 8];
        #pragma unroll
        for (int j = 0; j < 4; ++j) {
            bf16x8 bh = *(const bf16x8*)&stg[cur * 8192 + 2 * 2048 + (j * 16 + lr) * 32 + quad * 8];
            bf16x8 bl = *(const bf16x8*)&stg[cur * 8192 + 3 * 2048 + (j * 16 + lr) * 32 + quad * 8];
            acc[j] = __builtin_amdgcn_mfma_f32_16x16x32_bf16(ah, bh, acc[j], 0, 0, 0);
            acc[j] = __builtin_amdgcn_mfma_f32_16x16x32_bf16(ah, bl, acc[j], 0, 0, 0);
            acc[j] = __builtin_amdgcn_mfma_f32_16x16x32_bf16(al, bh, acc[j], 0, 0, 0);
        }
        __syncthreads();
        cur ^= 1;
    }

    float* Cb = part + ((long)blockIdx.x * Bcnt + batch) * 32768;
    #pragma unroll
    for (int j = 0; j < 4; ++j) {
        const int col = j * 16 + lr;
        #pragma unroll
        for (int r = 0; r < 4; ++r)
            Cb[(long)(m0 + wave * 16 + quad * 4 + r) * 64 + col] = acc[j][r];
    }
}

// =====================================================================
// Fused bases step. grid (C/64, B).
// MODE 0 (prep): bases -> bt hi/lo + btb Gram partials
// MODE 1 (full): reduce xc partials, mu-update bases, then bt + btb partials
// =====================================================================
template<int MODE>
__global__ __launch_bounds__(256) void bases_step(
    const float* __restrict__ xc_part,   // [8][B][512][64]
    const float* __restrict__ ctc,       // [B][64][64]
    float* __restrict__ bases,           // [B][512][64]
    ushort_t* __restrict__ bth, ushort_t* __restrict__ btl, // [B][64][512]
    float* __restrict__ btb_part,        // [8][B][4096]
    int Bcnt)
{
    __shared__ char smem[16640 * 2 + 18432];
    float* bnL  = (float*)smem;                  // [64][65]
    float* ctcL = (float*)(smem + 16640);        // [64][65]
    ushort_t* btLh = (ushort_t*)(smem + 33280);  // [64][72]
    ushort_t* btLl = btLh + 64 * 72;
    float* basesL = (float*)(smem + 33280);      // overlays btL (phase 1 only)

    const int b = blockIdx.y, c0 = blockIdx.x * 64;
    const int tid = threadIdx.x;
    float* basesB = bases + (long)b * 32768 + (long)c0 * 64;

    if (MODE == 1) {
        for (int i = tid; i < 4096; i += 256) {
            const int c = i >> 6, r = i & 63;
            basesL[c * 65 + r] = basesB[i];
            ctcL[c * 65 + r]   = ctc[(long)b * 4096 + i];
            float v = 0.f;
            #pragma unroll
            for (int s0 = 0; s0 < 8; ++s0)
                v += xc_part[((long)s0 * Bcnt + b) * 32768 + (long)(c0 + c) * 64 + r];
            bnL[c * 65 + r] = v;
        }
        __syncthreads();
        for (int i = tid; i < 4096; i += 256) {
            const int c = i >> 6, r = i & 63;
            float denom = 0.f;
            #pragma unroll 8
            for (int s = 0; s < 64; ++s)
                denom = fmaf(basesL[c * 65 + s], ctcL[s * 65 + r], denom);
            float bnew = basesL[c * 65 + r] * bnL[c * 65 + r] / (denom + NMF_EPS);
            bnL[c * 65 + r] = bnew;
            basesB[i] = bnew;
        }
        __syncthreads();
    } else {
        for (int i = tid; i < 4096; i += 256)
            bnL[(i >> 6) * 65 + (i & 63)] = basesB[i];
        __syncthreads();
    }

    for (int i = tid; i < 4096; i += 256) {
        const int r = i >> 6, cc = i & 63;
        float v = bnL[cc * 65 + r];
        ushort_t h = f2bf(v);
        ushort_t l = f2bf(v - bf2f(h));
        btLh[r * 72 + cc] = h;
        btLl[r * 72 + cc] = l;
        bth[(long)b * 32768 + (long)r * 512 + c0 + cc] = h;
        btl[(long)b * 32768 + (long)r * 512 + c0 + cc] = l;
    }
    __syncthreads();

    const int wave = tid >> 6, lane = tid & 63;
    const int quad = lane >> 4, lr = lane & 15;
    f32x4 acg[4];
    #pragma unroll
    for (int j = 0; j < 4; ++j) acg[j] = (f32x4){0.f, 0.f, 0.f, 0.f};
    #pragma unroll
    for (int kk = 0; kk < 64; kk += 32) {
        bf16x8 ah = *(const bf16x8*)&btLh[(wave * 16 + lr) * 72 + kk + quad * 8];
        bf16x8 al = *(const bf16x8*)&btLl[(wave * 16 + lr) * 72 + kk + quad * 8];
        #pragma unroll
        for (int j = 0; j < 4; ++j) {
            bf16x8 bh = *(const bf16x8*)&btLh[(j * 16 + lr) * 72 + kk + quad * 8];
            bf16x8 bl = *(const bf16x8*)&btLl[(j * 16 + lr) * 72 + kk + quad * 8];
            acg[j] = __builtin_amdgcn_mfma_f32_16x16x32_bf16(ah, bh, acg[j], 0, 0, 0);
            acg[j] = __builtin_amdgcn_mfma_f32_16x16x32_bf16(ah, bl, acg[j], 0, 0, 0);
            acg[j] = __builtin_amdgcn_mfma_f32_16x16x32_bf16(al, bh, acg[j], 0, 0, 0);
        }
    }
    float* gp = btb_part + ((long)blockIdx.x * Bcnt + b) * 4096;
    #pragma unroll
    for (int j = 0; j < 4; ++j)
        #pragma unroll
        for (int r = 0; r < 4; ++r)
            gp[(wave * 16 + quad * 4 + r) * 64 + j * 16 + lr] = acg[j][r];
}

// =====================================================================
// fp32 tiled GEMM (cheese ops only): EPI 0 plain; 4 relu(+bias)->bf16 [n][m]
// =====================================================================
constexpr int BM = 64, BN = 64, BK = 16;

template<int ALAY, int BLAY, int EPI>
__global__ __launch_bounds__(256) void gemm_kernel(
    const float* __restrict__ A, const float* __restrict__ B, float* __restrict__ C,
    int Kchunk, int kchunks,
    int lda, int ldb, int ldc,
    long sA, long sB, long sC,
    const float* __restrict__ bias)
{
    __shared__ float As[BK][BM + 4];
    __shared__ float Bs[BK][BN + 4];

    const int batch = blockIdx.z;
    const float* Ab = A + (long)batch * sA;
    const float* Bb = B + (long)batch * sB;

    const int m0  = blockIdx.y * BM;
    const int n0  = blockIdx.x * BN;
    const int tid = threadIdx.x;
    const int ty  = tid >> 4, tx = tid & 15;

    float acc[4][4] = {};

    for (int kt = 0; kt < Kchunk; kt += BK) {
        if (ALAY == 0) {
            const int m = tid >> 2, k4 = (tid & 3) << 2;
            float4 v = *(const float4*)&Ab[(long)(m0 + m) * lda + (kt + k4)];
            As[k4 + 0][m] = v.x; As[k4 + 1][m] = v.y;
            As[k4 + 2][m] = v.z; As[k4 + 3][m] = v.w;
        } else {
            const int k = tid >> 4, m4 = (tid & 15) << 2;
            float4 v = *(const float4*)&Ab[(long)(kt + k) * lda + (m0 + m4)];
            *(float4*)&As[k][m4] = v;
        }
        if (BLAY == 0) {
            const int k = tid >> 4, n4 = (tid & 15) << 2;
            float4 v = *(const float4*)&Bb[(long)(kt + k) * ldb + (n0 + n4)];
            *(float4*)&Bs[k][n4] = v;
        } else {
            const int n = tid >> 2, k4 = (tid & 3) << 2;
            float4 v = *(const float4*)&Bb[(long)(n0 + n) * ldb + (kt + k4)];
            Bs[k4 + 0][n] = v.x; Bs[k4 + 1][n] = v.y;
            Bs[k4 + 2][n] = v.z; Bs[k4 + 3][n] = v.w;
        }
        __syncthreads();
        #pragma unroll
        for (int k = 0; k < BK; ++k) {
            float4 a4 = *(const float4*)&As[k][ty << 2];
            float4 b4 = *(const float4*)&Bs[k][tx << 2];
            float av[4] = {a4.x, a4.y, a4.z, a4.w};
            float bv[4] = {b4.x, b4.y, b4.z, b4.w};
            #pragma unroll
            for (int i = 0; i < 4; ++i)
                #pragma unroll
                for (int j = 0; j < 4; ++j)
                    acc[i][j] = fmaf(av[i], bv[j], acc[i][j]);
        }
        __syncthreads();
    }

    const int mb = m0 + (ty << 2), nb = n0 + (tx << 2);
    if (EPI == 4) {
        ushort_t* Cu = (ushort_t*)C + (long)batch * sC;
        #pragma unroll
        for (int j = 0; j < 4; ++j) {
            ushort_t pk[4];
            #pragma unroll
            for (int i = 0; i < 4; ++i)
                pk[i] = f2bf(fmaxf(acc[i][j] + bias[mb + i], 0.f));
            *(ushort4*)&Cu[(long)(nb + j) * ldc + mb] =
                make_ushort4(pk[0], pk[1], pk[2], pk[3]);
        }
    } else {
        float* Cb = C + (long)batch * sC;
        #pragma unroll
        for (int i = 0; i < 4; ++i) {
            float4 o = make_float4(acc[i][0], acc[i][1], acc[i][2], acc[i][3]);
            *(float4*)&Cb[(long)(mb + i) * ldc + nb] = o;
        }
    }
}

// ---------- casts / transposes ----------
__global__ __launch_bounds__(256) void cast_x_t(const float* __restrict__ x,
                                                ushort_t* __restrict__ hi,
                                                ushort_t* __restrict__ lo)
{
    __shared__ float t[64][65];
    const int b = blockIdx.z, c0 = blockIdx.y * 64, n0 = blockIdx.x * 64;
    const int tid = threadIdx.x, tx = tid & 63, ty = tid >> 6;
    const float* xb = x + (long)b * 512 * 4096;
    #pragma unroll 4
    for (int s = ty; s < 64; s += 4)
        t[s][tx] = xb[(long)(c0 + s) * 4096 + n0 + tx];
    __syncthreads();
    #pragma unroll 4
    for (int s = ty; s < 64; s += 4) {
        float v = t[tx][s];
        long idx = (long)b * 2097152 + (long)(n0 + s) * 512 + c0 + tx;
        ushort_t h = f2bf(v);
        hi[idx] = h;
        lo[idx] = f2bf(v - bf2f(h));
    }
}

__global__ __launch_bounds__(256) void nd2dn(const ushort_t* __restrict__ hi,
                                             const ushort_t* __restrict__ lo,
                                             ushort_t* __restrict__ dhi,
                                             ushort_t* __restrict__ dlo)
{
    __shared__ unsigned int t[64][65];
    const int b = blockIdx.z, n0 = blockIdx.x * 64, c0 = blockIdx.y * 64;
    const int tx = threadIdx.x & 63, ty = threadIdx.x >> 6;
    const long base = (long)b * 2097152;
    #pragma unroll 4
    for (int s = ty; s < 64; s += 4) {
        long idx = base + (long)(n0 + s) * 512 + c0 + tx;
        t[s][tx] = (unsigned)hi[idx] | ((unsigned)lo[idx] << 16);
    }
    __syncthreads();
    #pragma unroll 4
    for (int s = ty; s < 64; s += 4) {
        unsigned v = t[tx][s];
        long idx = base + (long)(c0 + s) * 4096 + n0 + tx;
        dhi[idx] = (ushort_t)(v & 0xffffu);
        dlo[idx] = (ushort_t)(v >> 16);
    }
}

__global__ void cast_w_split(const float* __restrict__ w, ushort_t* __restrict__ hi,
                             ushort_t* __restrict__ lo, int n)
{
    int i = blockIdx.x * 256 + threadIdx.x;
    if (i < n) {
        float v = w[i];
        ushort_t h = f2bf(v);
        hi[i] = h;
        lo[i] = f2bf(v - bf2f(h));
    }
}

__global__ void cast_w_plain(const float* __restrict__ w, ushort_t* __restrict__ o, int n)
{
    int i = blockIdx.x * 256 + threadIdx.x;
    if (i < n) o[i] = f2bf(w[i]);
}

__global__ __launch_bounds__(1024) void l2norm_kernel(const float* __restrict__ b0,
                                                      float* __restrict__ bases)
{
    __shared__ float part[16][64];
    const int b = blockIdx.x;
    const int tid = threadIdx.x;
    const int r = tid & 63, slice = tid >> 6;
    const float* src = b0 + (long)b * 512 * 64;
    float* dst = bases + (long)b * 512 * 64;
    float s = 0.f;
    #pragma unroll 4
    for (int d = slice; d < 512; d += 16) {
        float v = src[d * 64 + r];
        s = fmaf(v, v, s);
    }
    part[slice][r] = s;
    __syncthreads();
    if (slice == 0) {
        float t = 0.f;
        #pragma unroll
        for (int i = 0; i < 16; ++i) t += part[i][r];
        part[0][r] = 1.0f / fmaxf(sqrtf(t), 1e-12f);
    }
    __syncthreads();
    const float inv = part[0][r];
    #pragma unroll 4
    for (int d = slice; d < 512; d += 16)
        dst[d * 64 + r] = src[d * 64 + r] * inv;
}

extern "C" void kernel_launch(void* const* d_in, const int* in_sizes, int n_in,
                              void* d_out, int out_size, void* d_ws, size_t ws_size,
                              hipStream_t stream)
{
    const float* x_in     = (const float*)d_in[0];
    const float* bases0   = (const float*)d_in[1];
    const float* w_lower  = (const float*)d_in[2];
    const float* b_lower  = (const float*)d_in[3];
    const float* w_cheese = (const float*)d_in[4];
    const float* b_cheese = (const float*)d_in[5];
    const float* w_upper  = (const float*)d_in[6];
    const float* csc      = (const float*)d_in[7];
    const float* cham     = (const float*)d_in[8];
    float* out = (float*)d_out;

    const int B = 8, C = 512, N = 4096, R = 64;
    const long sCN = (long)C * N;
    const long sNC = (long)N * C;
    const long sNR = (long)N * R, sCR = (long)C * R;

    // ---- workspace layout (bytes) ----
    char* w = (char*)d_ws;
    ushort_t* X_nd_hi  = (ushort_t*)w;  w += 33554432;  // [B,N,C]
    ushort_t* xt_hi    = (ushort_t*)w;  w += 33554432;  // x^T; later X_dn_hi
    ushort_t* xt_lo    = (ushort_t*)w;  w += 33554432;  // x^T; later X_dn_lo
    float*    coef     = (float*)w;     w += 8388608;   // [B,N,R]
    ushort_t* ct_hi    = (ushort_t*)w;  w += 4194304;   // [B,R,N]
    ushort_t* ct_lo    = (ushort_t*)w;  w += 4194304;
    float*    ctc_part = (float*)w;     w += 8388608;   // [64][B][4096]
    float*    xc_part  = (float*)w;     w += 8388608;   // [8][B][512][64]
    float*    btb_part = (float*)w;     w += 1048576;   // [8][B][4096]
    float*    bases    = (float*)w;     w += 1048576;   // [B,C,R]
    float*    WcB      = (float*)w;     w += 1048576;   // [B,C,R]
    float*    ctc      = (float*)w;     w += 131072;    // [B,R,R]
    ushort_t* bt_hi    = (ushort_t*)w;  w += 524288;    // [B,R,C]
    ushort_t* bt_lo    = (ushort_t*)w;  w += 524288;
    ushort_t* wl_hi    = (ushort_t*)w;  w += 524288;
    ushort_t* wl_lo    = (ushort_t*)w;  w += 524288;
    ushort_t* w_up     = (ushort_t*)w;  w += 524288;

    // X_lo plane [B,N,C]: keep d_out WRITE-ONCE (final dispatch only) by
    // placing the scratch plane in the workspace when it fits. Branch is on
    // ws_size only — identical every call, graph-capture-safe.
    ushort_t* X_nd_lo;
    {
        const size_t used = (size_t)(w - (char*)d_ws);
        if (ws_size >= used + 33554432UL) {
            X_nd_lo = (ushort_t*)w;  w += 33554432;
        } else {
            X_nd_lo = (ushort_t*)d_out;  // dead before final out write
        }
    }

    ushort_t* X_dn_hi  = xt_hi;
    ushort_t* X_dn_lo  = xt_lo;
    ushort_t* cheese_t = X_nd_hi;           // X_nd dead after final coef_step

    const dim3 blk(256);

    // init
    l2norm_kernel<<<dim3(B), dim3(1024), 0, stream>>>(bases0, bases);
    bases_step<0><<<dim3(C / 64, B), blk, 0, stream>>>(
        nullptr, nullptr, bases, bt_hi, bt_lo, btb_part, B);
    cast_w_split<<<dim3(1024), blk, 0, stream>>>(w_lower, wl_hi, wl_lo, C * C);
    cast_w_plain<<<dim3(1024), blk, 0, stream>>>(w_upper, w_up, C * C);
    cast_x_t<<<dim3(N / 64, C / 64, B), blk, 0, stream>>>(x_in, xt_hi, xt_lo);

    // X = relu(w_lower @ x + b_lower) -> bf16 hi/lo [n][c]
    mfma_gemm<1, 2><<<dim3(N / 128, C / 128, B), blk, 0, stream>>>(
        wl_hi, wl_lo, xt_hi, xt_lo, nullptr, X_nd_hi, X_nd_lo,
        C, N, C, sNC, sNC, b_lower, nullptr, 0L, nullptr, nullptr);
    nd2dn<<<dim3(N / 64, C / 64, B), blk, 0, stream>>>(X_nd_hi, X_nd_lo, X_dn_hi, X_dn_lo);

    // coef init (softmax)
    coef_step<0><<<dim3(N / 64, B), blk, 0, stream>>>(
        X_nd_hi, X_nd_lo, bt_hi, bt_lo, btb_part, coef, ct_hi, ct_lo, ctc_part, B);

    for (int step = 0; step < 6; ++step) {
        coef_step<1><<<dim3(N / 64, B), blk, 0, stream>>>(
            X_nd_hi, X_nd_lo, bt_hi, bt_lo, btb_part, coef, ct_hi, ct_lo, ctc_part, B);
        ctc_reduce<<<dim3(B * 16), blk, 0, stream>>>(ctc_part, ctc, B);
        xc_partial<<<dim3(8, C / 64, B), blk, 0, stream>>>(
            X_dn_hi, X_dn_lo, ct_hi, ct_lo, xc_part, B);
        bases_step<1><<<dim3(C / 64, B), blk, 0, stream>>>(
            xc_part, ctc, bases, bt_hi, bt_lo, btb_part, B);
    }

    // final differentiable coef refinement (no ct/ctc tail)
    coef_step<2><<<dim3(N / 64, B), blk, 0, stream>>>(
        X_nd_hi, X_nd_lo, bt_hi, bt_lo, btb_part, coef, ct_hi, ct_lo, ctc_part, B);

    // cheese via associativity
    gemm_kernel<0, 0, 0><<<dim3(1, C / BM, B), blk, 0, stream>>>(
        w_cheese, bases, WcB, C, 1, C, R, R, 0L, sCR, sCR, nullptr);
    gemm_kernel<0, 1, 4><<<dim3(N / BN, C / BM, B), blk, 0, stream>>>(
        WcB, coef, (float*)cheese_t, R, 1, R, R, C, sCR, sNR, sNC, b_cheese);

    // out = relu(ham * (w_upper @ cheese) + sc * x)
    mfma_gemm<0, 3><<<dim3(N / 128, C / 128, B), blk, 0, stream>>>(
        w_up, nullptr, cheese_t, nullptr, out, nullptr, nullptr,
        C, N, C, sNC, sCN, nullptr, x_in, sCN, cham, csc);
}

// Round 4
// 757.554 us; speedup vs baseline: 1.6951x; 1.0142x over previous
//
#include <hip/hip_runtime.h>

#define NMF_EPS 1e-6f

typedef unsigned short ushort_t;
typedef __attribute__((ext_vector_type(8))) short bf16x8;
typedef __attribute__((ext_vector_type(4))) float f32x4;

__device__ __forceinline__ ushort_t f2bf(float f) {
    unsigned int u = __float_as_uint(f);
    return (ushort_t)((u + 0x7FFFu + ((u >> 16) & 1u)) >> 16);
}
__device__ __forceinline__ float bf2f(ushort_t h) {
    return __uint_as_float(((unsigned int)h) << 16);
}

__device__ __forceinline__ void gl_lds16(const ushort_t* g, ushort_t* l) {
    __builtin_amdgcn_global_load_lds(
        (const __attribute__((address_space(1))) unsigned int*)g,
        (__attribute__((address_space(3))) unsigned int*)l,
        16, 0, 0);
}

#define WAIT_VMCNT(N) asm volatile("s_waitcnt vmcnt(" #N ")" ::: "memory")
#define SCHED_FENCE() __builtin_amdgcn_sched_barrier(0)
#define RAW_BAR()     __builtin_amdgcn_s_barrier()

// =====================================================================
// Big MFMA GEMM (lower / upper). C[m,n] = op(sum_k A[m,k]*B[n,k])
// 2-buffer pipeline with COUNTED vmcnt + raw barriers:
//   [stage t+1][vmcnt(loads/tile)][bar][compute t][bar]
// so each tile's wait targets loads issued a full iteration earlier.
// EPI 2: relu(acc+bias[m]) -> bf16 hi/lo TRANSPOSED [n][M] (LDS transpose)
// EPI 3: relu(ham*acc + sc*res[m,n]) -> fp32 [M,N]
// =====================================================================
template<int SPLIT, int EPI>
__global__ __launch_bounds__(256) void mfma_gemm(
    const ushort_t* __restrict__ Ah, const ushort_t* __restrict__ Al,
    const ushort_t* __restrict__ Bh, const ushort_t* __restrict__ Bl,
    float* __restrict__ C, ushort_t* __restrict__ Chi, ushort_t* __restrict__ Clo,
    int M, int N, int K,
    long sB, long sC,
    const float* __restrict__ bias,
    const float* __restrict__ res, long sRes,
    const float* __restrict__ hamp, const float* __restrict__ scp)
{
    constexpr int SB = SPLIT ? 32768 : 16384;   // bytes per dbuf slot
    __shared__ char smem[2 * SB];

    const int tid  = threadIdx.x;
    const int wave = tid >> 6, lane = tid & 63;
    const int quad = lane >> 4, lr = lane & 15;
    const int batch = blockIdx.z;
    const int m0 = blockIdx.y * 128, n0 = blockIdx.x * 128;

    const ushort_t* Bhb = Bh + (long)batch * sB;
    const ushort_t* Blb = SPLIT ? (Bl + (long)batch * sB) : nullptr;

    f32x4 acc[4][4];
    #pragma unroll
    for (int i = 0; i < 4; ++i)
        #pragma unroll
        for (int j = 0; j < 4; ++j)
            acc[i][j] = (f32x4){0.f, 0.f, 0.f, 0.f};

    const int q   = wave * 2;
    const int ra0 = (q + 0) * 16 + (lane >> 2);
    const int ra1 = (q + 1) * 16 + (lane >> 2);
    const int ko  = (lane & 3) * 8;
    const int wm = (wave & 1) * 64, wn = (wave >> 1) * 64;

    auto STAGE = [&](int buf, int k0) {
        char* base = smem + buf * SB;
        ushort_t* dAh = (ushort_t*)base;
        ushort_t* dBh = (ushort_t*)(base + 8192);
        gl_lds16(&Ah [(long)(m0 + ra0) * K + k0 + ko], &dAh[(q + 0) * 512]);
        gl_lds16(&Ah [(long)(m0 + ra1) * K + k0 + ko], &dAh[(q + 1) * 512]);
        gl_lds16(&Bhb[(long)(n0 + ra0) * K + k0 + ko], &dBh[(q + 0) * 512]);
        gl_lds16(&Bhb[(long)(n0 + ra1) * K + k0 + ko], &dBh[(q + 1) * 512]);
        if constexpr (SPLIT) {
            ushort_t* dAl = (ushort_t*)(base + 16384);
            ushort_t* dBl = (ushort_t*)(base + 24576);
            gl_lds16(&Al [(long)(m0 + ra0) * K + k0 + ko], &dAl[(q + 0) * 512]);
            gl_lds16(&Al [(long)(m0 + ra1) * K + k0 + ko], &dAl[(q + 1) * 512]);
            gl_lds16(&Blb[(long)(n0 + ra0) * K + k0 + ko], &dBl[(q + 0) * 512]);
            gl_lds16(&Blb[(long)(n0 + ra1) * K + k0 + ko], &dBl[(q + 1) * 512]);
        }
    };

    STAGE(0, 0);
    __syncthreads();        // full drain: tile 0 resident
    int cur = 0;
    const int NT = K >> 5;

    for (int t = 0; t < NT; ++t) {
        if (t + 1 < NT) {
            STAGE(cur ^ 1, (t + 1) << 5);
            if constexpr (SPLIT) { WAIT_VMCNT(8); } else { WAIT_VMCNT(4); }
        } else {
            WAIT_VMCNT(0);
        }
        SCHED_FENCE();
        RAW_BAR();          // all waves' tile-t loads complete
        SCHED_FENCE();

        char* base = smem + cur * SB;
        ushort_t* sAh = (ushort_t*)base;
        ushort_t* sBh = (ushort_t*)(base + 8192);

        bf16x8 af[4], bfr[4], afl[4], bfl[4];
        #pragma unroll
        for (int i = 0; i < 4; ++i)
            af[i] = *(const bf16x8*)&sAh[(wm + i * 16 + lr) * 32 + quad * 8];
        #pragma unroll
        for (int j = 0; j < 4; ++j)
            bfr[j] = *(const bf16x8*)&sBh[(wn + j * 16 + lr) * 32 + quad * 8];
        if constexpr (SPLIT) {
            ushort_t* sAl = (ushort_t*)(base + 16384);
            ushort_t* sBl = (ushort_t*)(base + 24576);
            #pragma unroll
            for (int i = 0; i < 4; ++i)
                afl[i] = *(const bf16x8*)&sAl[(wm + i * 16 + lr) * 32 + quad * 8];
            #pragma unroll
            for (int j = 0; j < 4; ++j)
                bfl[j] = *(const bf16x8*)&sBl[(wn + j * 16 + lr) * 32 + quad * 8];
        }

        #pragma unroll
        for (int i = 0; i < 4; ++i)
            #pragma unroll
            for (int j = 0; j < 4; ++j) {
                acc[i][j] = __builtin_amdgcn_mfma_f32_16x16x32_bf16(af[i], bfr[j], acc[i][j], 0, 0, 0);
                if constexpr (SPLIT) {
                    acc[i][j] = __builtin_amdgcn_mfma_f32_16x16x32_bf16(af[i], bfl[j], acc[i][j], 0, 0, 0);
                    acc[i][j] = __builtin_amdgcn_mfma_f32_16x16x32_bf16(afl[i], bfr[j], acc[i][j], 0, 0, 0);
                }
            }
        RAW_BAR();          // all waves done reading buf cur (safe to restage)
        SCHED_FENCE();
        cur ^= 1;
    }

    if (EPI == 2) {
        ushort_t* Hh = Chi + (long)batch * sC;
        ushort_t* Hl = Clo + (long)batch * sC;
        unsigned int* slab = (unsigned int*)smem;  // [128 n][64 m] u32
        #pragma unroll
        for (int p = 0; p < 2; ++p) {
            __syncthreads();
            if ((wave & 1) == p) {
                #pragma unroll
                for (int i = 0; i < 4; ++i) {
                    const int mb = m0 + p * 64 + i * 16 + quad * 4;
                    #pragma unroll
                    for (int j = 0; j < 4; ++j) {
                        const int nl = wn + j * 16 + lr;
                        #pragma unroll
                        for (int r = 0; r < 4; ++r) {
                            float v = fmaxf(acc[i][j][r] + bias[mb + r], 0.f);
                            ushort_t h = f2bf(v);
                            ushort_t l = f2bf(v - bf2f(h));
                            slab[nl * 64 + (i * 16 + quad * 4 + r)] =
                                (unsigned)h | ((unsigned)l << 16);
                        }
                    }
                }
            }
            __syncthreads();
            for (int idx = tid; idx < 8192; idx += 256) {
                const int nl = idx >> 6, ml = idx & 63;
                unsigned u = slab[idx];
                const long off = (long)(n0 + nl) * M + m0 + p * 64 + ml;
                Hh[off] = (ushort_t)(u & 0xffffu);
                Hl[off] = (ushort_t)(u >> 16);
            }
        }
    } else {
        const float hm = *hamp, sc = *scp;
        float* Cb = C + (long)batch * sC;
        #pragma unroll
        for (int i = 0; i < 4; ++i) {
            #pragma unroll
            for (int j = 0; j < 4; ++j) {
                const int mbase = m0 + wm + i * 16 + quad * 4;
                const int n     = n0 + wn + j * 16 + lr;
                #pragma unroll
                for (int r = 0; r < 4; ++r) {
                    float rv = res[(long)batch * sRes + (long)(mbase + r) * N + n];
                    Cb[(long)(mbase + r) * N + n] = fmaxf(fmaf(hm, acc[i][j][r], sc * rv), 0.f);
                }
            }
        }
    }
}

// =====================================================================
// Fused coef step. grid (N/64, B), 256 thr.
// 3-buffer depth-2 pipeline, counted vmcnt, raw barriers. 16 tiles of 32-K,
// 4 gl_lds16/thread/tile. LDS: 3x16KB stage + 18KB gL = 66 KB.
// MODE 0 (INIT): coef = softmax_r(X^T bases)
// MODE 1 (MU):   coef = coef*xtb/(coef@btb+eps); writes ct hi/lo + ctc partials
// MODE 2 (MU, final): as MODE 1 but skips the dead ct/ctc tail
// =====================================================================
template<int MODE>
__global__ __launch_bounds__(256) void coef_step(
    const ushort_t* __restrict__ Xh, const ushort_t* __restrict__ Xl,   // [B][N][512]
    const ushort_t* __restrict__ bth, const ushort_t* __restrict__ btl, // [B][64][512]
    const float* __restrict__ btb_part,   // [8][B][4096]
    float* __restrict__ coef,             // [B][N][64]
    ushort_t* __restrict__ cth, ushort_t* __restrict__ ctl, // [B][64][N]
    float* __restrict__ ctc_part,         // [64][B][4096]
    int Bcnt)
{
    constexpr bool MU = (MODE >= 1);
    __shared__ char smem[49152 + 18432];
    ushort_t* stg = (ushort_t*)smem;             // [3 buf][4 stream][2048]
    ushort_t* gLh = (ushort_t*)(smem + 49152);   // [64][72] btb hi (later ct hi)
    ushort_t* gLl = gLh + 64 * 72;               // btb lo (later ct lo)

    const int tid = threadIdx.x, wave = tid >> 6, lane = tid & 63;
    const int quad = lane >> 4, lr = lane & 15;
    const int b = blockIdx.y, n0 = blockIdx.x * 64;

    const ushort_t* Xhb  = Xh  + (long)b * 2097152 + (long)n0 * 512;
    const ushort_t* Xlb  = Xl  + (long)b * 2097152 + (long)n0 * 512;
    const ushort_t* bthb = bth + (long)b * 32768;
    const ushort_t* btlb = btl + (long)b * 32768;
    float* coefB = coef + (long)b * 262144 + (long)n0 * 64;

    if (MU) {
        // reduce btb partials -> LDS (hi/lo)
        for (int i = tid; i < 4096; i += 256) {
            const int r = i >> 6, s = i & 63;
            float v = 0.f;
            #pragma unroll
            for (int c = 0; c < 8; ++c)
                v += btb_part[((long)c * Bcnt + b) * 4096 + i];
            ushort_t h = f2bf(v);
            gLh[r * 72 + s] = h;
            gLl[r * 72 + s] = f2bf(v - bf2f(h));
        }
    }

    // ---- xtb via MFMA, 16 tiles of 32-K, 3-buffer depth-2 ----
    const int srow = wave * 16 + (lane >> 2);
    const int koff = (lane & 3) * 8;
    f32x4 accx[4];
    #pragma unroll
    for (int j = 0; j < 4; ++j) accx[j] = (f32x4){0.f, 0.f, 0.f, 0.f};

    auto STAGEX = [&](int buf, int kc) {
        const int kg = kc * 32 + koff;
        gl_lds16(&Xhb [(long)srow * 512 + kg], &stg[buf * 8192 + 0 * 2048 + wave * 512]);
        gl_lds16(&Xlb [(long)srow * 512 + kg], &stg[buf * 8192 + 1 * 2048 + wave * 512]);
        gl_lds16(&bthb[(long)srow * 512 + kg], &stg[buf * 8192 + 2 * 2048 + wave * 512]);
        gl_lds16(&btlb[(long)srow * 512 + kg], &stg[buf * 8192 + 3 * 2048 + wave * 512]);
    };

    STAGEX(0, 0);
    STAGEX(1, 1);
    __syncthreads();        // tiles 0,1 resident (+ gL writes visible)

    int b0 = 0, b1 = 1, b2 = 2;
    for (int t = 0; t < 16; ++t) {
        if (t < 14) {
            STAGEX(b2, t + 2);
            WAIT_VMCNT(8);          // tiles t+1, t+2 may fly; tile t done
        } else if (t == 14) {
            WAIT_VMCNT(4);          // only tile 15 may fly
        } else {
            WAIT_VMCNT(0);
        }
        SCHED_FENCE();
        RAW_BAR();
        SCHED_FENCE();

        bf16x8 ah = *(const bf16x8*)&stg[b0 * 8192 + 0 * 2048 + (wave * 16 + lr) * 32 + quad * 8];
        bf16x8 al = *(const bf16x8*)&stg[b0 * 8192 + 1 * 2048 + (wave * 16 + lr) * 32 + quad * 8];
        #pragma unroll
        for (int j = 0; j < 4; ++j) {
            bf16x8 bh = *(const bf16x8*)&stg[b0 * 8192 + 2 * 2048 + (j * 16 + lr) * 32 + quad * 8];
            bf16x8 bl = *(const bf16x8*)&stg[b0 * 8192 + 3 * 2048 + (j * 16 + lr) * 32 + quad * 8];
            accx[j] = __builtin_amdgcn_mfma_f32_16x16x32_bf16(ah, bh, accx[j], 0, 0, 0);
            accx[j] = __builtin_amdgcn_mfma_f32_16x16x32_bf16(ah, bl, accx[j], 0, 0, 0);
            accx[j] = __builtin_amdgcn_mfma_f32_16x16x32_bf16(al, bh, accx[j], 0, 0, 0);
        }
        RAW_BAR();
        SCHED_FENCE();
        int tmp = b0; b0 = b1; b1 = b2; b2 = tmp;
    }

    float cnew[4][4]; // [j][reg]
    if (MU) {
        // denom = coef @ btb (split MFMA; coef A-frags direct from global fp32)
        f32x4 accd[4];
        #pragma unroll
        for (int j = 0; j < 4; ++j) accd[j] = (f32x4){0.f, 0.f, 0.f, 0.f};
        #pragma unroll
        for (int kk = 0; kk < 2; ++kk) {
            const float* cp = &coefB[(wave * 16 + lr) * 64 + kk * 32 + quad * 8];
            float4 cA = *(const float4*)cp;
            float4 cB = *(const float4*)(cp + 4);
            float cv[8] = {cA.x, cA.y, cA.z, cA.w, cB.x, cB.y, cB.z, cB.w};
            bf16x8 ah, al;
            #pragma unroll
            for (int e = 0; e < 8; ++e) {
                ushort_t h = f2bf(cv[e]);
                ((short*)&ah)[e] = (short)h;
                ((short*)&al)[e] = (short)f2bf(cv[e] - bf2f(h));
            }
            #pragma unroll
            for (int j = 0; j < 4; ++j) {
                bf16x8 bh = *(const bf16x8*)&gLh[(j * 16 + lr) * 72 + kk * 32 + quad * 8];
                bf16x8 bl = *(const bf16x8*)&gLl[(j * 16 + lr) * 72 + kk * 32 + quad * 8];
                accd[j] = __builtin_amdgcn_mfma_f32_16x16x32_bf16(ah, bh, accd[j], 0, 0, 0);
                accd[j] = __builtin_amdgcn_mfma_f32_16x16x32_bf16(ah, bl, accd[j], 0, 0, 0);
                accd[j] = __builtin_amdgcn_mfma_f32_16x16x32_bf16(al, bh, accd[j], 0, 0, 0);
            }
        }
        #pragma unroll
        for (int j = 0; j < 4; ++j)
            #pragma unroll
            for (int r = 0; r < 4; ++r) {
                float cold = coefB[(wave * 16 + quad * 4 + r) * 64 + j * 16 + lr];
                cnew[j][r] = cold * accx[j][r] / (accd[j][r] + NMF_EPS);
            }
    } else {
        #pragma unroll
        for (int r = 0; r < 4; ++r) {
            float m = fmaxf(fmaxf(accx[0][r], accx[1][r]), fmaxf(accx[2][r], accx[3][r]));
            #pragma unroll
            for (int off = 1; off < 16; off <<= 1) m = fmaxf(m, __shfl_xor(m, off, 64));
            float e[4], s = 0.f;
            #pragma unroll
            for (int j = 0; j < 4; ++j) { e[j] = __expf(accx[j][r] - m); s += e[j]; }
            #pragma unroll
            for (int off = 1; off < 16; off <<= 1) s += __shfl_xor(s, off, 64);
            float inv = 1.f / s;
            #pragma unroll
            for (int j = 0; j < 4; ++j) cnew[j][r] = e[j] * inv;
        }
    }

    #pragma unroll
    for (int j = 0; j < 4; ++j)
        #pragma unroll
        for (int r = 0; r < 4; ++r)
            coefB[(wave * 16 + quad * 4 + r) * 64 + j * 16 + lr] = cnew[j][r];

    if (MODE != 1) return;

    __syncthreads();  // btb dead; overlay ct on gL
    #pragma unroll
    for (int j = 0; j < 4; ++j)
        #pragma unroll
        for (int r = 0; r < 4; ++r) {
            const int nl = wave * 16 + quad * 4 + r;
            const int rr = j * 16 + lr;
            float v = cnew[j][r];
            ushort_t h = f2bf(v);
            gLh[rr * 72 + nl] = h;
            gLl[rr * 72 + nl] = f2bf(v - bf2f(h));
        }
    __syncthreads();
    for (int i = tid; i < 4096; i += 256) {
        const int r = i >> 6, nn = i & 63;
        cth[(long)b * 262144 + (long)r * 4096 + n0 + nn] = gLh[r * 72 + nn];
        ctl[(long)b * 262144 + (long)r * 4096 + n0 + nn] = gLl[r * 72 + nn];
    }
    // ctc Gram partials via MFMA
    f32x4 accc[4];
    #pragma unroll
    for (int j = 0; j < 4; ++j) accc[j] = (f32x4){0.f, 0.f, 0.f, 0.f};
    #pragma unroll
    for (int kk = 0; kk < 64; kk += 32) {
        bf16x8 ah = *(const bf16x8*)&gLh[(wave * 16 + lr) * 72 + kk + quad * 8];
        bf16x8 al = *(const bf16x8*)&gLl[(wave * 16 + lr) * 72 + kk + quad * 8];
        #pragma unroll
        for (int j = 0; j < 4; ++j) {
            bf16x8 bh = *(const bf16x8*)&gLh[(j * 16 + lr) * 72 + kk + quad * 8];
            bf16x8 bl = *(const bf16x8*)&gLl[(j * 16 + lr) * 72 + kk + quad * 8];
            accc[j] = __builtin_amdgcn_mfma_f32_16x16x32_bf16(ah, bh, accc[j], 0, 0, 0);
            accc[j] = __builtin_amdgcn_mfma_f32_16x16x32_bf16(ah, bl, accc[j], 0, 0, 0);
            accc[j] = __builtin_amdgcn_mfma_f32_16x16x32_bf16(al, bh, accc[j], 0, 0, 0);
        }
    }
    float* cp = ctc_part + ((long)blockIdx.x * Bcnt + b) * 4096;
    #pragma unroll
    for (int j = 0; j < 4; ++j)
        #pragma unroll
        for (int r = 0; r < 4; ++r)
            cp[(wave * 16 + quad * 4 + r) * 64 + j * 16 + lr] = accc[j][r];
}

// reduce ctc partials
__global__ __launch_bounds__(256) void ctc_reduce(const float* __restrict__ part,
                                                  float* __restrict__ ctc, int Bcnt)
{
    const int b = blockIdx.x >> 4;
    const int i = (blockIdx.x & 15) * 256 + threadIdx.x;
    float v = 0.f;
    #pragma unroll 8
    for (int c = 0; c < 64; ++c)
        v += part[((long)c * Bcnt + b) * 4096 + i];
    ctc[(long)b * 4096 + i] = v;
}

// xc split-K partials: part[kc][b][c][r] = sum_{k chunk} X[c,k]*ct[r,k]
// grid (8, C/64, B). 3-buffer depth-2 pipeline, 16 tiles of 32-K.
__global__ __launch_bounds__(256) void xc_partial(
    const ushort_t* __restrict__ Ah, const ushort_t* __restrict__ Al, // X_dn [B][512][4096]
    const ushort_t* __restrict__ Bh, const ushort_t* __restrict__ Bl, // ct  [B][64][4096]
    float* __restrict__ part, int Bcnt)
{
    __shared__ ushort_t stg[3 * 8192];   // [3 buf][4 stream][2048]
    const int tid = threadIdx.x, wave = tid >> 6, lane = tid & 63;
    const int quad = lane >> 4, lr = lane & 15;
    const int batch = blockIdx.z;
    const int m0 = blockIdx.y * 64;
    const int k0 = blockIdx.x * 512;

    const ushort_t* Ab  = Ah + (long)batch * 2097152;
    const ushort_t* Alb = Al + (long)batch * 2097152;
    const ushort_t* Bb  = Bh + (long)batch * 262144;
    const ushort_t* Blb = Bl + (long)batch * 262144;

    const int srow = wave * 16 + (lane >> 2);
    const int koff = (lane & 3) * 8;

    f32x4 acc[4];
    #pragma unroll
    for (int j = 0; j < 4; ++j) acc[j] = (f32x4){0.f, 0.f, 0.f, 0.f};

    auto STAGEX = [&](int buf, int kc) {
        const int kg = k0 + kc * 32 + koff;
        gl_lds16(&Ab [(long)(m0 + srow) * 4096 + kg], &stg[buf * 8192 + 0 * 2048 + wave * 512]);
        gl_lds16(&Alb[(long)(m0 + srow) * 4096 + kg], &stg[buf * 8192 + 1 * 2048 + wave * 512]);
        gl_lds16(&Bb [(long)srow * 4096 + kg], &stg[buf * 8192 + 2 * 2048 + wave * 512]);
        gl_lds16(&Blb[(long)srow * 4096 + kg], &stg[buf * 8192 + 3 * 2048 + wave * 512]);
    };

    STAGEX(0, 0);
    STAGEX(1, 1);
    __syncthreads();        // tiles 0,1 resident

    int b0 = 0, b1 = 1, b2 = 2;
    for (int t = 0; t < 16; ++t) {
        if (t < 14) {
            STAGEX(b2, t + 2);
            WAIT_VMCNT(8);
        } else if (t == 14) {
            WAIT_VMCNT(4);
        } else {
            WAIT_VMCNT(0);
        }
        SCHED_FENCE();
        RAW_BAR();
        SCHED_FENCE();

        bf16x8 ah = *(const bf16x8*)&stg[b0 * 8192 + 0 * 2048 + (wave * 16 + lr) * 32 + quad * 8];
        bf16x8 al = *(const bf16x8*)&stg[b0 * 8192 + 1 * 2048 + (wave * 16 + lr) * 32 + quad * 8];
        #pragma unroll
        for (int j = 0; j < 4; ++j) {
            bf16x8 bh = *(const bf16x8*)&stg[b0 * 8192 + 2 * 2048 + (j * 16 + lr) * 32 + quad * 8];
            bf16x8 bl = *(const bf16x8*)&stg[b0 * 8192 + 3 * 2048 + (j * 16 + lr) * 32 + quad * 8];
            acc[j] = __builtin_amdgcn_mfma_f32_16x16x32_bf16(ah, bh, acc[j], 0, 0, 0);
            acc[j] = __builtin_amdgcn_mfma_f32_16x16x32_bf16(ah, bl, acc[j], 0, 0, 0);
            acc[j] = __builtin_amdgcn_mfma_f32_16x16x32_bf16(al, bh, acc[j], 0, 0, 0);
        }
        RAW_BAR();
        SCHED_FENCE();
        int tmp = b0; b0 = b1; b1 = b2; b2 = tmp;
    }

    float* Cb = part + ((long)blockIdx.x * Bcnt + batch) * 32768;
    #pragma unroll
    for (int j = 0; j < 4; ++j) {
        const int col = j * 16 + lr;
        #pragma unroll
        for (int r = 0; r < 4; ++r)
            Cb[(long)(m0 + wave * 16 + quad * 4 + r) * 64 + col] = acc[j][r];
    }
}

// =====================================================================
// Fused bases step. grid (C/64, B).
// MODE 0 (prep): bases -> bt hi/lo + btb Gram partials
// MODE 1 (full): reduce xc partials, mu-update bases, then bt + btb partials
// =====================================================================
template<int MODE>
__global__ __launch_bounds__(256) void bases_step(
    const float* __restrict__ xc_part,   // [8][B][512][64]
    const float* __restrict__ ctc,       // [B][64][64]
    float* __restrict__ bases,           // [B][512][64]
    ushort_t* __restrict__ bth, ushort_t* __restrict__ btl, // [B][64][512]
    float* __restrict__ btb_part,        // [8][B][4096]
    int Bcnt)
{
    __shared__ char smem[16640 * 2 + 18432];
    float* bnL  = (float*)smem;                  // [64][65]
    float* ctcL = (float*)(smem + 16640);        // [64][65]
    ushort_t* btLh = (ushort_t*)(smem + 33280);  // [64][72]
    ushort_t* btLl = btLh + 64 * 72;
    float* basesL = (float*)(smem + 33280);      // overlays btL (phase 1 only)

    const int b = blockIdx.y, c0 = blockIdx.x * 64;
    const int tid = threadIdx.x;
    float* basesB = bases + (long)b * 32768 + (long)c0 * 64;

    if (MODE == 1) {
        for (int i = tid; i < 4096; i += 256) {
            const int c = i >> 6, r = i & 63;
            basesL[c * 65 + r] = basesB[i];
            ctcL[c * 65 + r]   = ctc[(long)b * 4096 + i];
            float v = 0.f;
            #pragma unroll
            for (int s0 = 0; s0 < 8; ++s0)
                v += xc_part[((long)s0 * Bcnt + b) * 32768 + (long)(c0 + c) * 64 + r];
            bnL[c * 65 + r] = v;
        }
        __syncthreads();
        for (int i = tid; i < 4096; i += 256) {
            const int c = i >> 6, r = i & 63;
            float denom = 0.f;
            #pragma unroll 8
            for (int s = 0; s < 64; ++s)
                denom = fmaf(basesL[c * 65 + s], ctcL[s * 65 + r], denom);
            float bnew = basesL[c * 65 + r] * bnL[c * 65 + r] / (denom + NMF_EPS);
            bnL[c * 65 + r] = bnew;
            basesB[i] = bnew;
        }
        __syncthreads();
    } else {
        for (int i = tid; i < 4096; i += 256)
            bnL[(i >> 6) * 65 + (i & 63)] = basesB[i];
        __syncthreads();
    }

    for (int i = tid; i < 4096; i += 256) {
        const int r = i >> 6, cc = i & 63;
        float v = bnL[cc * 65 + r];
        ushort_t h = f2bf(v);
        ushort_t l = f2bf(v - bf2f(h));
        btLh[r * 72 + cc] = h;
        btLl[r * 72 + cc] = l;
        bth[(long)b * 32768 + (long)r * 512 + c0 + cc] = h;
        btl[(long)b * 32768 + (long)r * 512 + c0 + cc] = l;
    }
    __syncthreads();

    const int wave = tid >> 6, lane = tid & 63;
    const int quad = lane >> 4, lr = lane & 15;
    f32x4 acg[4];
    #pragma unroll
    for (int j = 0; j < 4; ++j) acg[j] = (f32x4){0.f, 0.f, 0.f, 0.f};
    #pragma unroll
    for (int kk = 0; kk < 64; kk += 32) {
        bf16x8 ah = *(const bf16x8*)&btLh[(wave * 16 + lr) * 72 + kk + quad * 8];
        bf16x8 al = *(const bf16x8*)&btLl[(wave * 16 + lr) * 72 + kk + quad * 8];
        #pragma unroll
        for (int j = 0; j < 4; ++j) {
            bf16x8 bh = *(const bf16x8*)&btLh[(j * 16 + lr) * 72 + kk + quad * 8];
            bf16x8 bl = *(const bf16x8*)&btLl[(j * 16 + lr) * 72 + kk + quad * 8];
            acg[j] = __builtin_amdgcn_mfma_f32_16x16x32_bf16(ah, bh, acg[j], 0, 0, 0);
            acg[j] = __builtin_amdgcn_mfma_f32_16x16x32_bf16(ah, bl, acg[j], 0, 0, 0);
            acg[j] = __builtin_amdgcn_mfma_f32_16x16x32_bf16(al, bh, acg[j], 0, 0, 0);
        }
    }
    float* gp = btb_part + ((long)blockIdx.x * Bcnt + b) * 4096;
    #pragma unroll
    for (int j = 0; j < 4; ++j)
        #pragma unroll
        for (int r = 0; r < 4; ++r)
            gp[(wave * 16 + quad * 4 + r) * 64 + j * 16 + lr] = acg[j][r];
}

// =====================================================================
// fp32 tiled GEMM (cheese ops only): EPI 0 plain; 4 relu(+bias)->bf16 [n][m]
// =====================================================================
constexpr int BM = 64, BN = 64, BK = 16;

template<int ALAY, int BLAY, int EPI>
__global__ __launch_bounds__(256) void gemm_kernel(
    const float* __restrict__ A, const float* __restrict__ B, float* __restrict__ C,
    int Kchunk, int kchunks,
    int lda, int ldb, int ldc,
    long sA, long sB, long sC,
    const float* __restrict__ bias)
{
    __shared__ float As[BK][BM + 4];
    __shared__ float Bs[BK][BN + 4];

    const int batch = blockIdx.z;
    const float* Ab = A + (long)batch * sA;
    const float* Bb = B + (long)batch * sB;

    const int m0  = blockIdx.y * BM;
    const int n0  = blockIdx.x * BN;
    const int tid = threadIdx.x;
    const int ty  = tid >> 4, tx = tid & 15;

    float acc[4][4] = {};

    for (int kt = 0; kt < Kchunk; kt += BK) {
        if (ALAY == 0) {
            const int m = tid >> 2, k4 = (tid & 3) << 2;
            float4 v = *(const float4*)&Ab[(long)(m0 + m) * lda + (kt + k4)];
            As[k4 + 0][m] = v.x; As[k4 + 1][m] = v.y;
            As[k4 + 2][m] = v.z; As[k4 + 3][m] = v.w;
        } else {
            const int k = tid >> 4, m4 = (tid & 15) << 2;
            float4 v = *(const float4*)&Ab[(long)(kt + k) * lda + (m0 + m4)];
            *(float4*)&As[k][m4] = v;
        }
        if (BLAY == 0) {
            const int k = tid >> 4, n4 = (tid & 15) << 2;
            float4 v = *(const float4*)&Bb[(long)(kt + k) * ldb + (n0 + n4)];
            *(float4*)&Bs[k][n4] = v;
        } else {
            const int n = tid >> 2, k4 = (tid & 3) << 2;
            float4 v = *(const float4*)&Bb[(long)(n0 + n) * ldb + (kt + k4)];
            Bs[k4 + 0][n] = v.x; Bs[k4 + 1][n] = v.y;
            Bs[k4 + 2][n] = v.z; Bs[k4 + 3][n] = v.w;
        }
        __syncthreads();
        #pragma unroll
        for (int k = 0; k < BK; ++k) {
            float4 a4 = *(const float4*)&As[k][ty << 2];
            float4 b4 = *(const float4*)&Bs[k][tx << 2];
            float av[4] = {a4.x, a4.y, a4.z, a4.w};
            float bv[4] = {b4.x, b4.y, b4.z, b4.w};
            #pragma unroll
            for (int i = 0; i < 4; ++i)
                #pragma unroll
                for (int j = 0; j < 4; ++j)
                    acc[i][j] = fmaf(av[i], bv[j], acc[i][j]);
        }
        __syncthreads();
    }

    const int mb = m0 + (ty << 2), nb = n0 + (tx << 2);
    if (EPI == 4) {
        ushort_t* Cu = (ushort_t*)C + (long)batch * sC;
        #pragma unroll
        for (int j = 0; j < 4; ++j) {
            ushort_t pk[4];
            #pragma unroll
            for (int i = 0; i < 4; ++i)
                pk[i] = f2bf(fmaxf(acc[i][j] + bias[mb + i], 0.f));
            *(ushort4*)&Cu[(long)(nb + j) * ldc + mb] =
                make_ushort4(pk[0], pk[1], pk[2], pk[3]);
        }
    } else {
        float* Cb = C + (long)batch * sC;
        #pragma unroll
        for (int i = 0; i < 4; ++i) {
            float4 o = make_float4(acc[i][0], acc[i][1], acc[i][2], acc[i][3]);
            *(float4*)&Cb[(long)(mb + i) * ldc + nb] = o;
        }
    }
}

// ---------- casts / transposes ----------
__global__ __launch_bounds__(256) void cast_x_t(const float* __restrict__ x,
                                                ushort_t* __restrict__ hi,
                                                ushort_t* __restrict__ lo)
{
    __shared__ float t[64][65];
    const int b = blockIdx.z, c0 = blockIdx.y * 64, n0 = blockIdx.x * 64;
    const int tid = threadIdx.x, tx = tid & 63, ty = tid >> 6;
    const float* xb = x + (long)b * 512 * 4096;
    #pragma unroll 4
    for (int s = ty; s < 64; s += 4)
        t[s][tx] = xb[(long)(c0 + s) * 4096 + n0 + tx];
    __syncthreads();
    #pragma unroll 4
    for (int s = ty; s < 64; s += 4) {
        float v = t[tx][s];
        long idx = (long)b * 2097152 + (long)(n0 + s) * 512 + c0 + tx;
        ushort_t h = f2bf(v);
        hi[idx] = h;
        lo[idx] = f2bf(v - bf2f(h));
    }
}

__global__ __launch_bounds__(256) void nd2dn(const ushort_t* __restrict__ hi,
                                             const ushort_t* __restrict__ lo,
                                             ushort_t* __restrict__ dhi,
                                             ushort_t* __restrict__ dlo)
{
    __shared__ unsigned int t[64][65];
    const int b = blockIdx.z, n0 = blockIdx.x * 64, c0 = blockIdx.y * 64;
    const int tx = threadIdx.x & 63, ty = threadIdx.x >> 6;
    const long base = (long)b * 2097152;
    #pragma unroll 4
    for (int s = ty; s < 64; s += 4) {
        long idx = base + (long)(n0 + s) * 512 + c0 + tx;
        t[s][tx] = (unsigned)hi[idx] | ((unsigned)lo[idx] << 16);
    }
    __syncthreads();
    #pragma unroll 4
    for (int s = ty; s < 64; s += 4) {
        unsigned v = t[tx][s];
        long idx = base + (long)(c0 + s) * 4096 + n0 + tx;
        dhi[idx] = (ushort_t)(v & 0xffffu);
        dlo[idx] = (ushort_t)(v >> 16);
    }
}

__global__ void cast_w_split(const float* __restrict__ w, ushort_t* __restrict__ hi,
                             ushort_t* __restrict__ lo, int n)
{
    int i = blockIdx.x * 256 + threadIdx.x;
    if (i < n) {
        float v = w[i];
        ushort_t h = f2bf(v);
        hi[i] = h;
        lo[i] = f2bf(v - bf2f(h));
    }
}

__global__ void cast_w_plain(const float* __restrict__ w, ushort_t* __restrict__ o, int n)
{
    int i = blockIdx.x * 256 + threadIdx.x;
    if (i < n) o[i] = f2bf(w[i]);
}

__global__ __launch_bounds__(1024) void l2norm_kernel(const float* __restrict__ b0,
                                                      float* __restrict__ bases)
{
    __shared__ float part[16][64];
    const int b = blockIdx.x;
    const int tid = threadIdx.x;
    const int r = tid & 63, slice = tid >> 6;
    const float* src = b0 + (long)b * 512 * 64;
    float* dst = bases + (long)b * 512 * 64;
    float s = 0.f;
    #pragma unroll 4
    for (int d = slice; d < 512; d += 16) {
        float v = src[d * 64 + r];
        s = fmaf(v, v, s);
    }
    part[slice][r] = s;
    __syncthreads();
    if (slice == 0) {
        float t = 0.f;
        #pragma unroll
        for (int i = 0; i < 16; ++i) t += part[i][r];
        part[0][r] = 1.0f / fmaxf(sqrtf(t), 1e-12f);
    }
    __syncthreads();
    const float inv = part[0][r];
    #pragma unroll 4
    for (int d = slice; d < 512; d += 16)
        dst[d * 64 + r] = src[d * 64 + r] * inv;
}

extern "C" void kernel_launch(void* const* d_in, const int* in_sizes, int n_in,
                              void* d_out, int out_size, void* d_ws, size_t ws_size,
                              hipStream_t stream)
{
    const float* x_in     = (const float*)d_in[0];
    const float* bases0   = (const float*)d_in[1];
    const float* w_lower  = (const float*)d_in[2];
    const float* b_lower  = (const float*)d_in[3];
    const float* w_cheese = (const float*)d_in[4];
    const float* b_cheese = (const float*)d_in[5];
    const float* w_upper  = (const float*)d_in[6];
    const float* csc      = (const float*)d_in[7];
    const float* cham     = (const float*)d_in[8];
    float* out = (float*)d_out;

    const int B = 8, C = 512, N = 4096, R = 64;
    const long sCN = (long)C * N;
    const long sNC = (long)N * C;
    const long sNR = (long)N * R, sCR = (long)C * R;

    // ---- workspace layout (bytes) ----
    char* w = (char*)d_ws;
    ushort_t* X_nd_hi  = (ushort_t*)w;  w += 33554432;  // [B,N,C]
    ushort_t* xt_hi    = (ushort_t*)w;  w += 33554432;  // x^T; later X_dn_hi
    ushort_t* xt_lo    = (ushort_t*)w;  w += 33554432;  // x^T; later X_dn_lo
    float*    coef     = (float*)w;     w += 8388608;   // [B,N,R]
    ushort_t* ct_hi    = (ushort_t*)w;  w += 4194304;   // [B,R,N]
    ushort_t* ct_lo    = (ushort_t*)w;  w += 4194304;
    float*    ctc_part = (float*)w;     w += 8388608;   // [64][B][4096]
    float*    xc_part  = (float*)w;     w += 8388608;   // [8][B][512][64]
    float*    btb_part = (float*)w;     w += 1048576;   // [8][B][4096]
    float*    bases    = (float*)w;     w += 1048576;   // [B,C,R]
    float*    WcB      = (float*)w;     w += 1048576;   // [B,C,R]
    float*    ctc      = (float*)w;     w += 131072;    // [B,R,R]
    ushort_t* bt_hi    = (ushort_t*)w;  w += 524288;    // [B,R,C]
    ushort_t* bt_lo    = (ushort_t*)w;  w += 524288;
    ushort_t* wl_hi    = (ushort_t*)w;  w += 524288;
    ushort_t* wl_lo    = (ushort_t*)w;  w += 524288;
    ushort_t* w_up     = (ushort_t*)w;  w += 524288;

    // X_lo plane [B,N,C]: keep d_out WRITE-ONCE (final dispatch only) by
    // placing the scratch plane in the workspace when it fits. Branch is on
    // ws_size only — identical every call, graph-capture-safe.
    ushort_t* X_nd_lo;
    {
        const size_t used = (size_t)(w - (char*)d_ws);
        if (ws_size >= used + 33554432UL) {
            X_nd_lo = (ushort_t*)w;  w += 33554432;
        } else {
            X_nd_lo = (ushort_t*)d_out;  // dead before final out write
        }
    }

    ushort_t* X_dn_hi  = xt_hi;
    ushort_t* X_dn_lo  = xt_lo;
    ushort_t* cheese_t = X_nd_hi;           // X_nd dead after final coef_step

    const dim3 blk(256);

    // init
    l2norm_kernel<<<dim3(B), dim3(1024), 0, stream>>>(bases0, bases);
    bases_step<0><<<dim3(C / 64, B), blk, 0, stream>>>(
        nullptr, nullptr, bases, bt_hi, bt_lo, btb_part, B);
    cast_w_split<<<dim3(1024), blk, 0, stream>>>(w_lower, wl_hi, wl_lo, C * C);
    cast_w_plain<<<dim3(1024), blk, 0, stream>>>(w_upper, w_up, C * C);
    cast_x_t<<<dim3(N / 64, C / 64, B), blk, 0, stream>>>(x_in, xt_hi, xt_lo);

    // X = relu(w_lower @ x + b_lower) -> bf16 hi/lo [n][c]
    mfma_gemm<1, 2><<<dim3(N / 128, C / 128, B), blk, 0, stream>>>(
        wl_hi, wl_lo, xt_hi, xt_lo, nullptr, X_nd_hi, X_nd_lo,
        C, N, C, sNC, sNC, b_lower, nullptr, 0L, nullptr, nullptr);
    nd2dn<<<dim3(N / 64, C / 64, B), blk, 0, stream>>>(X_nd_hi, X_nd_lo, X_dn_hi, X_dn_lo);

    // coef init (softmax)
    coef_step<0><<<dim3(N / 64, B), blk, 0, stream>>>(
        X_nd_hi, X_nd_lo, bt_hi, bt_lo, btb_part, coef, ct_hi, ct_lo, ctc_part, B);

    for (int step = 0; step < 6; ++step) {
        coef_step<1><<<dim3(N / 64, B), blk, 0, stream>>>(
            X_nd_hi, X_nd_lo, bt_hi, bt_lo, btb_part, coef, ct_hi, ct_lo, ctc_part, B);
        ctc_reduce<<<dim3(B * 16), blk, 0, stream>>>(ctc_part, ctc, B);
        xc_partial<<<dim3(8, C / 64, B), blk, 0, stream>>>(
            X_dn_hi, X_dn_lo, ct_hi, ct_lo, xc_part, B);
        bases_step<1><<<dim3(C / 64, B), blk, 0, stream>>>(
            xc_part, ctc, bases, bt_hi, bt_lo, btb_part, B);
    }

    // final differentiable coef refinement (no ct/ctc tail)
    coef_step<2><<<dim3(N / 64, B), blk, 0, stream>>>(
        X_nd_hi, X_nd_lo, bt_hi, bt_lo, btb_part, coef, ct_hi, ct_lo, ctc_part, B);

    // cheese via associativity
    gemm_kernel<0, 0, 0><<<dim3(1, C / BM, B), blk, 0, stream>>>(
        w_cheese, bases, WcB, C, 1, C, R, R, 0L, sCR, sCR, nullptr);
    gemm_kernel<0, 1, 4><<<dim3(N / BN, C / BM, B), blk, 0, stream>>>(
        WcB, coef, (float*)cheese_t, R, 1, R, R, C, sCR, sNR, sNC, b_cheese);

    // out = relu(ham * (w_upper @ cheese) + sc * x)
    mfma_gemm<0, 3><<<dim3(N / 128, C / 128, B), blk, 0, stream>>>(
        w_up, nullptr, cheese_t, nullptr, out, nullptr, nullptr,
        C, N, C, sNC, sCN, nullptr, x_in, sCN, cham, csc);
}

// Round 5
// 748.870 us; speedup vs baseline: 1.7148x; 1.0116x over previous
//
#include <hip/hip_runtime.h>

#define NMF_EPS 1e-6f

typedef unsigned short ushort_t;
typedef __attribute__((ext_vector_type(8))) short bf16x8;
typedef __attribute__((ext_vector_type(4))) float f32x4;

__device__ __forceinline__ ushort_t f2bf(float f) {
    unsigned int u = __float_as_uint(f);
    return (ushort_t)((u + 0x7FFFu + ((u >> 16) & 1u)) >> 16);
}
__device__ __forceinline__ float bf2f(ushort_t h) {
    return __uint_as_float(((unsigned int)h) << 16);
}

__device__ __forceinline__ void gl_lds16(const ushort_t* g, ushort_t* l) {
    __builtin_amdgcn_global_load_lds(
        (const __attribute__((address_space(1))) unsigned int*)g,
        (__attribute__((address_space(3))) unsigned int*)l,
        16, 0, 0);
}

// =====================================================================
// Big MFMA GEMM (lower / upper). C[m,n] = op(sum_k A[m,k]*B[n,k])
// Double-buffered LDS, single barrier per K-step (verified best: R2 form).
// EPI 2: relu(acc+bias[m]) -> bf16 hi/lo TRANSPOSED [n][M] (LDS transpose)
// EPI 3: relu(ham*acc + sc*res[m,n]) -> fp32 [M,N]
// =====================================================================
template<int SPLIT, int EPI>
__global__ __launch_bounds__(256) void mfma_gemm(
    const ushort_t* __restrict__ Ah, const ushort_t* __restrict__ Al,
    const ushort_t* __restrict__ Bh, const ushort_t* __restrict__ Bl,
    float* __restrict__ C, ushort_t* __restrict__ Chi, ushort_t* __restrict__ Clo,
    int M, int N, int K,
    long sB, long sC,
    const float* __restrict__ bias,
    const float* __restrict__ res, long sRes,
    const float* __restrict__ hamp, const float* __restrict__ scp)
{
    constexpr int SB = SPLIT ? 32768 : 16384;   // bytes per dbuf slot
    __shared__ char smem[2 * SB];

    const int tid  = threadIdx.x;
    const int wave = tid >> 6, lane = tid & 63;
    const int quad = lane >> 4, lr = lane & 15;
    const int batch = blockIdx.z;
    const int m0 = blockIdx.y * 128, n0 = blockIdx.x * 128;

    const ushort_t* Bhb = Bh + (long)batch * sB;
    const ushort_t* Blb = SPLIT ? (Bl + (long)batch * sB) : nullptr;

    f32x4 acc[4][4];
    #pragma unroll
    for (int i = 0; i < 4; ++i)
        #pragma unroll
        for (int j = 0; j < 4; ++j)
            acc[i][j] = (f32x4){0.f, 0.f, 0.f, 0.f};

    const int q   = wave * 2;
    const int ra0 = (q + 0) * 16 + (lane >> 2);
    const int ra1 = (q + 1) * 16 + (lane >> 2);
    const int ko  = (lane & 3) * 8;
    const int wm = (wave & 1) * 64, wn = (wave >> 1) * 64;

    auto STAGE = [&](int buf, int k0) {
        char* base = smem + buf * SB;
        ushort_t* dAh = (ushort_t*)base;
        ushort_t* dBh = (ushort_t*)(base + 8192);
        gl_lds16(&Ah [(long)(m0 + ra0) * K + k0 + ko], &dAh[(q + 0) * 512]);
        gl_lds16(&Ah [(long)(m0 + ra1) * K + k0 + ko], &dAh[(q + 1) * 512]);
        gl_lds16(&Bhb[(long)(n0 + ra0) * K + k0 + ko], &dBh[(q + 0) * 512]);
        gl_lds16(&Bhb[(long)(n0 + ra1) * K + k0 + ko], &dBh[(q + 1) * 512]);
        if constexpr (SPLIT) {
            ushort_t* dAl = (ushort_t*)(base + 16384);
            ushort_t* dBl = (ushort_t*)(base + 24576);
            gl_lds16(&Al [(long)(m0 + ra0) * K + k0 + ko], &dAl[(q + 0) * 512]);
            gl_lds16(&Al [(long)(m0 + ra1) * K + k0 + ko], &dAl[(q + 1) * 512]);
            gl_lds16(&Blb[(long)(n0 + ra0) * K + k0 + ko], &dBl[(q + 0) * 512]);
            gl_lds16(&Blb[(long)(n0 + ra1) * K + k0 + ko], &dBl[(q + 1) * 512]);
        }
    };

    STAGE(0, 0);
    __syncthreads();
    int cur = 0;

    for (int k0 = 0; k0 < K; k0 += 32) {
        if (k0 + 32 < K) STAGE(cur ^ 1, k0 + 32);

        char* base = smem + cur * SB;
        ushort_t* sAh = (ushort_t*)base;
        ushort_t* sBh = (ushort_t*)(base + 8192);

        bf16x8 af[4], bfr[4], afl[4], bfl[4];
        #pragma unroll
        for (int i = 0; i < 4; ++i)
            af[i] = *(const bf16x8*)&sAh[(wm + i * 16 + lr) * 32 + quad * 8];
        #pragma unroll
        for (int j = 0; j < 4; ++j)
            bfr[j] = *(const bf16x8*)&sBh[(wn + j * 16 + lr) * 32 + quad * 8];
        if constexpr (SPLIT) {
            ushort_t* sAl = (ushort_t*)(base + 16384);
            ushort_t* sBl = (ushort_t*)(base + 24576);
            #pragma unroll
            for (int i = 0; i < 4; ++i)
                afl[i] = *(const bf16x8*)&sAl[(wm + i * 16 + lr) * 32 + quad * 8];
            #pragma unroll
            for (int j = 0; j < 4; ++j)
                bfl[j] = *(const bf16x8*)&sBl[(wn + j * 16 + lr) * 32 + quad * 8];
        }

        #pragma unroll
        for (int i = 0; i < 4; ++i)
            #pragma unroll
            for (int j = 0; j < 4; ++j) {
                acc[i][j] = __builtin_amdgcn_mfma_f32_16x16x32_bf16(af[i], bfr[j], acc[i][j], 0, 0, 0);
                if constexpr (SPLIT) {
                    acc[i][j] = __builtin_amdgcn_mfma_f32_16x16x32_bf16(af[i], bfl[j], acc[i][j], 0, 0, 0);
                    acc[i][j] = __builtin_amdgcn_mfma_f32_16x16x32_bf16(afl[i], bfr[j], acc[i][j], 0, 0, 0);
                }
            }
        __syncthreads();
        cur ^= 1;
    }

    if (EPI == 2) {
        ushort_t* Hh = Chi + (long)batch * sC;
        ushort_t* Hl = Clo + (long)batch * sC;
        unsigned int* slab = (unsigned int*)smem;  // [128 n][64 m] u32
        #pragma unroll
        for (int p = 0; p < 2; ++p) {
            __syncthreads();
            if ((wave & 1) == p) {
                #pragma unroll
                for (int i = 0; i < 4; ++i) {
                    const int mb = m0 + p * 64 + i * 16 + quad * 4;
                    #pragma unroll
                    for (int j = 0; j < 4; ++j) {
                        const int nl = wn + j * 16 + lr;
                        #pragma unroll
                        for (int r = 0; r < 4; ++r) {
                            float v = fmaxf(acc[i][j][r] + bias[mb + r], 0.f);
                            ushort_t h = f2bf(v);
                            ushort_t l = f2bf(v - bf2f(h));
                            slab[nl * 64 + (i * 16 + quad * 4 + r)] =
                                (unsigned)h | ((unsigned)l << 16);
                        }
                    }
                }
            }
            __syncthreads();
            for (int idx = tid; idx < 8192; idx += 256) {
                const int nl = idx >> 6, ml = idx & 63;
                unsigned u = slab[idx];
                const long off = (long)(n0 + nl) * M + m0 + p * 64 + ml;
                Hh[off] = (ushort_t)(u & 0xffffu);
                Hl[off] = (ushort_t)(u >> 16);
            }
        }
    } else {
        const float hm = *hamp, sc = *scp;
        float* Cb = C + (long)batch * sC;
        #pragma unroll
        for (int i = 0; i < 4; ++i) {
            #pragma unroll
            for (int j = 0; j < 4; ++j) {
                const int mbase = m0 + wm + i * 16 + quad * 4;
                const int n     = n0 + wn + j * 16 + lr;
                #pragma unroll
                for (int r = 0; r < 4; ++r) {
                    float rv = res[(long)batch * sRes + (long)(mbase + r) * N + n];
                    Cb[(long)(mbase + r) * N + n] = fmaxf(fmaf(hm, acc[i][j][r], sc * rv), 0.f);
                }
            }
        }
    }
}

// =====================================================================
// Fused coef step. grid (N/64, B), 256 thr. BK=32 ping-pong (R3 form).
// MODE 0 (INIT): coef = softmax_r(X^T bases)
// MODE 1 (MU):   coef = coef*xtb/(coef@btb+eps); writes ct hi/lo + ctc partials
// MODE 2 (MU, final): as MODE 1 but skips the dead ct/ctc tail
// =====================================================================
template<int MODE>
__global__ __launch_bounds__(256) void coef_step(
    const ushort_t* __restrict__ Xh, const ushort_t* __restrict__ Xl,   // [B][N][512]
    const ushort_t* __restrict__ bth, const ushort_t* __restrict__ btl, // [B][64][512]
    const float* __restrict__ btb_part,   // [8][B][4096]
    float* __restrict__ coef,             // [B][N][64]
    ushort_t* __restrict__ cth, ushort_t* __restrict__ ctl, // [B][64][N]
    float* __restrict__ ctc_part,         // [64][B][4096]
    int Bcnt)
{
    constexpr bool MU = (MODE >= 1);
    __shared__ char smem[32768 + 18432];
    ushort_t* stg = (ushort_t*)smem;             // [2 buf][4 stream][2048]
    ushort_t* gLh = (ushort_t*)(smem + 32768);   // [64][72] btb hi (later ct hi)
    ushort_t* gLl = gLh + 64 * 72;               // btb lo (later ct lo)

    const int tid = threadIdx.x, wave = tid >> 6, lane = tid & 63;
    const int quad = lane >> 4, lr = lane & 15;
    const int b = blockIdx.y, n0 = blockIdx.x * 64;

    const ushort_t* Xhb  = Xh  + (long)b * 2097152 + (long)n0 * 512;
    const ushort_t* Xlb  = Xl  + (long)b * 2097152 + (long)n0 * 512;
    const ushort_t* bthb = bth + (long)b * 32768;
    const ushort_t* btlb = btl + (long)b * 32768;
    float* coefB = coef + (long)b * 262144 + (long)n0 * 64;

    if (MU) {
        // reduce btb partials -> LDS (hi/lo)
        for (int i = tid; i < 4096; i += 256) {
            const int r = i >> 6, s = i & 63;
            float v = 0.f;
            #pragma unroll
            for (int c = 0; c < 8; ++c)
                v += btb_part[((long)c * Bcnt + b) * 4096 + i];
            ushort_t h = f2bf(v);
            gLh[r * 72 + s] = h;
            gLl[r * 72 + s] = f2bf(v - bf2f(h));
        }
    }

    // ---- xtb via MFMA, BK=32 ping-pong ----
    const int srow = wave * 16 + (lane >> 2);
    const int koff = (lane & 3) * 8;
    f32x4 accx[4];
    #pragma unroll
    for (int j = 0; j < 4; ++j) accx[j] = (f32x4){0.f, 0.f, 0.f, 0.f};

    auto STAGEX = [&](int buf, int kc) {
        const int kg = kc * 32 + koff;
        gl_lds16(&Xhb [(long)srow * 512 + kg], &stg[buf * 8192 + 0 * 2048 + wave * 512]);
        gl_lds16(&Xlb [(long)srow * 512 + kg], &stg[buf * 8192 + 1 * 2048 + wave * 512]);
        gl_lds16(&bthb[(long)srow * 512 + kg], &stg[buf * 8192 + 2 * 2048 + wave * 512]);
        gl_lds16(&btlb[(long)srow * 512 + kg], &stg[buf * 8192 + 3 * 2048 + wave * 512]);
    };

    STAGEX(0, 0);
    __syncthreads();
    int cur = 0;

    for (int kc = 0; kc < 16; ++kc) {
        if (kc + 1 < 16) STAGEX(cur ^ 1, kc + 1);
        bf16x8 ah = *(const bf16x8*)&stg[cur * 8192 + 0 * 2048 + (wave * 16 + lr) * 32 + quad * 8];
        bf16x8 al = *(const bf16x8*)&stg[cur * 8192 + 1 * 2048 + (wave * 16 + lr) * 32 + quad * 8];
        #pragma unroll
        for (int j = 0; j < 4; ++j) {
            bf16x8 bh = *(const bf16x8*)&stg[cur * 8192 + 2 * 2048 + (j * 16 + lr) * 32 + quad * 8];
            bf16x8 bl = *(const bf16x8*)&stg[cur * 8192 + 3 * 2048 + (j * 16 + lr) * 32 + quad * 8];
            accx[j] = __builtin_amdgcn_mfma_f32_16x16x32_bf16(ah, bh, accx[j], 0, 0, 0);
            accx[j] = __builtin_amdgcn_mfma_f32_16x16x32_bf16(ah, bl, accx[j], 0, 0, 0);
            accx[j] = __builtin_amdgcn_mfma_f32_16x16x32_bf16(al, bh, accx[j], 0, 0, 0);
        }
        __syncthreads();
        cur ^= 1;
    }

    float cnew[4][4]; // [j][reg]
    if (MU) {
        // denom = coef @ btb (split MFMA; coef A-frags direct from global fp32)
        f32x4 accd[4];
        #pragma unroll
        for (int j = 0; j < 4; ++j) accd[j] = (f32x4){0.f, 0.f, 0.f, 0.f};
        #pragma unroll
        for (int kk = 0; kk < 2; ++kk) {
            const float* cp = &coefB[(wave * 16 + lr) * 64 + kk * 32 + quad * 8];
            float4 cA = *(const float4*)cp;
            float4 cB = *(const float4*)(cp + 4);
            float cv[8] = {cA.x, cA.y, cA.z, cA.w, cB.x, cB.y, cB.z, cB.w};
            bf16x8 ah, al;
            #pragma unroll
            for (int e = 0; e < 8; ++e) {
                ushort_t h = f2bf(cv[e]);
                ((short*)&ah)[e] = (short)h;
                ((short*)&al)[e] = (short)f2bf(cv[e] - bf2f(h));
            }
            #pragma unroll
            for (int j = 0; j < 4; ++j) {
                bf16x8 bh = *(const bf16x8*)&gLh[(j * 16 + lr) * 72 + kk * 32 + quad * 8];
                bf16x8 bl = *(const bf16x8*)&gLl[(j * 16 + lr) * 72 + kk * 32 + quad * 8];
                accd[j] = __builtin_amdgcn_mfma_f32_16x16x32_bf16(ah, bh, accd[j], 0, 0, 0);
                accd[j] = __builtin_amdgcn_mfma_f32_16x16x32_bf16(ah, bl, accd[j], 0, 0, 0);
                accd[j] = __builtin_amdgcn_mfma_f32_16x16x32_bf16(al, bh, accd[j], 0, 0, 0);
            }
        }
        #pragma unroll
        for (int j = 0; j < 4; ++j)
            #pragma unroll
            for (int r = 0; r < 4; ++r) {
                float cold = coefB[(wave * 16 + quad * 4 + r) * 64 + j * 16 + lr];
                cnew[j][r] = cold * accx[j][r] / (accd[j][r] + NMF_EPS);
            }
    } else {
        #pragma unroll
        for (int r = 0; r < 4; ++r) {
            float m = fmaxf(fmaxf(accx[0][r], accx[1][r]), fmaxf(accx[2][r], accx[3][r]));
            #pragma unroll
            for (int off = 1; off < 16; off <<= 1) m = fmaxf(m, __shfl_xor(m, off, 64));
            float e[4], s = 0.f;
            #pragma unroll
            for (int j = 0; j < 4; ++j) { e[j] = __expf(accx[j][r] - m); s += e[j]; }
            #pragma unroll
            for (int off = 1; off < 16; off <<= 1) s += __shfl_xor(s, off, 64);
            float inv = 1.f / s;
            #pragma unroll
            for (int j = 0; j < 4; ++j) cnew[j][r] = e[j] * inv;
        }
    }

    #pragma unroll
    for (int j = 0; j < 4; ++j)
        #pragma unroll
        for (int r = 0; r < 4; ++r)
            coefB[(wave * 16 + quad * 4 + r) * 64 + j * 16 + lr] = cnew[j][r];

    if (MODE != 1) return;

    __syncthreads();  // btb dead; overlay ct on gL
    #pragma unroll
    for (int j = 0; j < 4; ++j)
        #pragma unroll
        for (int r = 0; r < 4; ++r) {
            const int nl = wave * 16 + quad * 4 + r;
            const int rr = j * 16 + lr;
            float v = cnew[j][r];
            ushort_t h = f2bf(v);
            gLh[rr * 72 + nl] = h;
            gLl[rr * 72 + nl] = f2bf(v - bf2f(h));
        }
    __syncthreads();
    for (int i = tid; i < 4096; i += 256) {
        const int r = i >> 6, nn = i & 63;
        cth[(long)b * 262144 + (long)r * 4096 + n0 + nn] = gLh[r * 72 + nn];
        ctl[(long)b * 262144 + (long)r * 4096 + n0 + nn] = gLl[r * 72 + nn];
    }
    // ctc Gram partials via MFMA
    f32x4 accc[4];
    #pragma unroll
    for (int j = 0; j < 4; ++j) accc[j] = (f32x4){0.f, 0.f, 0.f, 0.f};
    #pragma unroll
    for (int kk = 0; kk < 64; kk += 32) {
        bf16x8 ah = *(const bf16x8*)&gLh[(wave * 16 + lr) * 72 + kk + quad * 8];
        bf16x8 al = *(const bf16x8*)&gLl[(wave * 16 + lr) * 72 + kk + quad * 8];
        #pragma unroll
        for (int j = 0; j < 4; ++j) {
            bf16x8 bh = *(const bf16x8*)&gLh[(j * 16 + lr) * 72 + kk + quad * 8];
            bf16x8 bl = *(const bf16x8*)&gLl[(j * 16 + lr) * 72 + kk + quad * 8];
            accc[j] = __builtin_amdgcn_mfma_f32_16x16x32_bf16(ah, bh, accc[j], 0, 0, 0);
            accc[j] = __builtin_amdgcn_mfma_f32_16x16x32_bf16(ah, bl, accc[j], 0, 0, 0);
            accc[j] = __builtin_amdgcn_mfma_f32_16x16x32_bf16(al, bh, accc[j], 0, 0, 0);
        }
    }
    float* cp = ctc_part + ((long)blockIdx.x * Bcnt + b) * 4096;
    #pragma unroll
    for (int j = 0; j < 4; ++j)
        #pragma unroll
        for (int r = 0; r < 4; ++r)
            cp[(wave * 16 + quad * 4 + r) * 64 + j * 16 + lr] = accc[j][r];
}

// xc split-K partials + folded ctc reduce.
// grid (8, 9, B): y<8 -> GEMM partials (m0 = y*64); y==8 -> ctc reduce for
// i-slice [x*512, x*512+512) of batch z (depends only on ctc_part from the
// preceding coef_step dispatch — stream-ordered, race-free).
__global__ __launch_bounds__(256) void xc_partial(
    const ushort_t* __restrict__ Ah, const ushort_t* __restrict__ Al, // X_dn [B][512][4096]
    const ushort_t* __restrict__ Bh, const ushort_t* __restrict__ Bl, // ct  [B][64][4096]
    float* __restrict__ part,
    const float* __restrict__ ctc_part,  // [64][B][4096]
    float* __restrict__ ctc,             // [B][64][64]
    int Bcnt)
{
    __shared__ ushort_t stg[2 * 8192];   // [2 buf][4 stream][2048]
    const int tid = threadIdx.x;
    const int batch = blockIdx.z;

    if (blockIdx.y == 8) {
        const int i0 = blockIdx.x * 512;
        #pragma unroll
        for (int rep = 0; rep < 2; ++rep) {
            const int i = i0 + rep * 256 + tid;
            float v = 0.f;
            #pragma unroll 8
            for (int c = 0; c < 64; ++c)
                v += ctc_part[((long)c * Bcnt + batch) * 4096 + i];
            ctc[(long)batch * 4096 + i] = v;
        }
        return;
    }

    const int wave = tid >> 6, lane = tid & 63;
    const int quad = lane >> 4, lr = lane & 15;
    const int m0 = blockIdx.y * 64;
    const int k0 = blockIdx.x * 512;

    const ushort_t* Ab  = Ah + (long)batch * 2097152;
    const ushort_t* Alb = Al + (long)batch * 2097152;
    const ushort_t* Bb  = Bh + (long)batch * 262144;
    const ushort_t* Blb = Bl + (long)batch * 262144;

    const int srow = wave * 16 + (lane >> 2);
    const int koff = (lane & 3) * 8;

    f32x4 acc[4];
    #pragma unroll
    for (int j = 0; j < 4; ++j) acc[j] = (f32x4){0.f, 0.f, 0.f, 0.f};

    auto STAGEX = [&](int buf, int kc) {
        const int kg = k0 + kc * 32 + koff;
        gl_lds16(&Ab [(long)(m0 + srow) * 4096 + kg], &stg[buf * 8192 + 0 * 2048 + wave * 512]);
        gl_lds16(&Alb[(long)(m0 + srow) * 4096 + kg], &stg[buf * 8192 + 1 * 2048 + wave * 512]);
        gl_lds16(&Bb [(long)srow * 4096 + kg], &stg[buf * 8192 + 2 * 2048 + wave * 512]);
        gl_lds16(&Blb[(long)srow * 4096 + kg], &stg[buf * 8192 + 3 * 2048 + wave * 512]);
    };

    STAGEX(0, 0);
    __syncthreads();
    int cur = 0;

    for (int kc = 0; kc < 16; ++kc) {
        if (kc + 1 < 16) STAGEX(cur ^ 1, kc + 1);
        bf16x8 ah = *(const bf16x8*)&stg[cur * 8192 + 0 * 2048 + (wave * 16 + lr) * 32 + quad * 8];
        bf16x8 al = *(const bf16x8*)&stg[cur * 8192 + 1 * 2048 + (wave * 16 + lr) * 32 + quad * 8];
        #pragma unroll
        for (int j = 0; j < 4; ++j) {
            bf16x8 bh = *(const bf16x8*)&stg[cur * 8192 + 2 * 2048 + (j * 16 + lr) * 32 + quad * 8];
            bf16x8 bl = *(const bf16x8*)&stg[cur * 8192 + 3 * 2048 + (j * 16 + lr) * 32 + quad * 8];
            acc[j] = __builtin_amdgcn_mfma_f32_16x16x32_bf16(ah, bh, acc[j], 0, 0, 0);
            acc[j] = __builtin_amdgcn_mfma_f32_16x16x32_bf16(ah, bl, acc[j], 0, 0, 0);
            acc[j] = __builtin_amdgcn_mfma_f32_16x16x32_bf16(al, bh, acc[j], 0, 0, 0);
        }
        __syncthreads();
        cur ^= 1;
    }

    float* Cb = part + ((long)blockIdx.x * Bcnt + batch) * 32768;
    #pragma unroll
    for (int j = 0; j < 4; ++j) {
        const int col = j * 16 + lr;
        #pragma unroll
        for (int r = 0; r < 4; ++r)
            Cb[(long)(m0 + wave * 16 + quad * 4 + r) * 64 + col] = acc[j][r];
    }
}

// =====================================================================
// Fused bases step. grid (C/64, B).
// MODE 0 (prep): bases -> bt hi/lo + btb Gram partials
// MODE 1 (full): reduce xc partials, mu-update bases, then bt + btb partials
// =====================================================================
template<int MODE>
__global__ __launch_bounds__(256) void bases_step(
    const float* __restrict__ xc_part,   // [8][B][512][64]
    const float* __restrict__ ctc,       // [B][64][64]
    float* __restrict__ bases,           // [B][512][64]
    ushort_t* __restrict__ bth, ushort_t* __restrict__ btl, // [B][64][512]
    float* __restrict__ btb_part,        // [8][B][4096]
    int Bcnt)
{
    __shared__ char smem[16640 * 2 + 18432];
    float* bnL  = (float*)smem;                  // [64][65]
    float* ctcL = (float*)(smem + 16640);        // [64][65]
    ushort_t* btLh = (ushort_t*)(smem + 33280);  // [64][72]
    ushort_t* btLl = btLh + 64 * 72;
    float* basesL = (float*)(smem + 33280);      // overlays btL (phase 1 only)

    const int b = blockIdx.y, c0 = blockIdx.x * 64;
    const int tid = threadIdx.x;
    float* basesB = bases + (long)b * 32768 + (long)c0 * 64;

    if (MODE == 1) {
        for (int i = tid; i < 4096; i += 256) {
            const int c = i >> 6, r = i & 63;
            basesL[c * 65 + r] = basesB[i];
            ctcL[c * 65 + r]   = ctc[(long)b * 4096 + i];
            float v = 0.f;
            #pragma unroll
            for (int s0 = 0; s0 < 8; ++s0)
                v += xc_part[((long)s0 * Bcnt + b) * 32768 + (long)(c0 + c) * 64 + r];
            bnL[c * 65 + r] = v;
        }
        __syncthreads();
        for (int i = tid; i < 4096; i += 256) {
            const int c = i >> 6, r = i & 63;
            float denom = 0.f;
            #pragma unroll 8
            for (int s = 0; s < 64; ++s)
                denom = fmaf(basesL[c * 65 + s], ctcL[s * 65 + r], denom);
            float bnew = basesL[c * 65 + r] * bnL[c * 65 + r] / (denom + NMF_EPS);
            bnL[c * 65 + r] = bnew;
            basesB[i] = bnew;
        }
        __syncthreads();
    } else {
        for (int i = tid; i < 4096; i += 256)
            bnL[(i >> 6) * 65 + (i & 63)] = basesB[i];
        __syncthreads();
    }

    for (int i = tid; i < 4096; i += 256) {
        const int r = i >> 6, cc = i & 63;
        float v = bnL[cc * 65 + r];
        ushort_t h = f2bf(v);
        ushort_t l = f2bf(v - bf2f(h));
        btLh[r * 72 + cc] = h;
        btLl[r * 72 + cc] = l;
        bth[(long)b * 32768 + (long)r * 512 + c0 + cc] = h;
        btl[(long)b * 32768 + (long)r * 512 + c0 + cc] = l;
    }
    __syncthreads();

    const int wave = tid >> 6, lane = tid & 63;
    const int quad = lane >> 4, lr = lane & 15;
    f32x4 acg[4];
    #pragma unroll
    for (int j = 0; j < 4; ++j) acg[j] = (f32x4){0.f, 0.f, 0.f, 0.f};
    #pragma unroll
    for (int kk = 0; kk < 64; kk += 32) {
        bf16x8 ah = *(const bf16x8*)&btLh[(wave * 16 + lr) * 72 + kk + quad * 8];
        bf16x8 al = *(const bf16x8*)&btLl[(wave * 16 + lr) * 72 + kk + quad * 8];
        #pragma unroll
        for (int j = 0; j < 4; ++j) {
            bf16x8 bh = *(const bf16x8*)&btLh[(j * 16 + lr) * 72 + kk + quad * 8];
            bf16x8 bl = *(const bf16x8*)&btLl[(j * 16 + lr) * 72 + kk + quad * 8];
            acg[j] = __builtin_amdgcn_mfma_f32_16x16x32_bf16(ah, bh, acg[j], 0, 0, 0);
            acg[j] = __builtin_amdgcn_mfma_f32_16x16x32_bf16(ah, bl, acg[j], 0, 0, 0);
            acg[j] = __builtin_amdgcn_mfma_f32_16x16x32_bf16(al, bh, acg[j], 0, 0, 0);
        }
    }
    float* gp = btb_part + ((long)blockIdx.x * Bcnt + b) * 4096;
    #pragma unroll
    for (int j = 0; j < 4; ++j)
        #pragma unroll
        for (int r = 0; r < 4; ++r)
            gp[(wave * 16 + quad * 4 + r) * 64 + j * 16 + lr] = acg[j][r];
}

// =====================================================================
// fp32 tiled GEMM (cheese ops only): EPI 0 plain; 4 relu(+bias)->bf16 [n][m]
// =====================================================================
constexpr int BM = 64, BN = 64, BK = 16;

template<int ALAY, int BLAY, int EPI>
__global__ __launch_bounds__(256) void gemm_kernel(
    const float* __restrict__ A, const float* __restrict__ B, float* __restrict__ C,
    int Kchunk, int kchunks,
    int lda, int ldb, int ldc,
    long sA, long sB, long sC,
    const float* __restrict__ bias)
{
    __shared__ float As[BK][BM + 4];
    __shared__ float Bs[BK][BN + 4];

    const int batch = blockIdx.z;
    const float* Ab = A + (long)batch * sA;
    const float* Bb = B + (long)batch * sB;

    const int m0  = blockIdx.y * BM;
    const int n0  = blockIdx.x * BN;
    const int tid = threadIdx.x;
    const int ty  = tid >> 4, tx = tid & 15;

    float acc[4][4] = {};

    for (int kt = 0; kt < Kchunk; kt += BK) {
        if (ALAY == 0) {
            const int m = tid >> 2, k4 = (tid & 3) << 2;
            float4 v = *(const float4*)&Ab[(long)(m0 + m) * lda + (kt + k4)];
            As[k4 + 0][m] = v.x; As[k4 + 1][m] = v.y;
            As[k4 + 2][m] = v.z; As[k4 + 3][m] = v.w;
        } else {
            const int k = tid >> 4, m4 = (tid & 15) << 2;
            float4 v = *(const float4*)&Ab[(long)(kt + k) * lda + (m0 + m4)];
            *(float4*)&As[k][m4] = v;
        }
        if (BLAY == 0) {
            const int k = tid >> 4, n4 = (tid & 15) << 2;
            float4 v = *(const float4*)&Bb[(long)(kt + k) * ldb + (n0 + n4)];
            *(float4*)&Bs[k][n4] = v;
        } else {
            const int n = tid >> 2, k4 = (tid & 3) << 2;
            float4 v = *(const float4*)&Bb[(long)(n0 + n) * ldb + (kt + k4)];
            Bs[k4 + 0][n] = v.x; Bs[k4 + 1][n] = v.y;
            Bs[k4 + 2][n] = v.z; Bs[k4 + 3][n] = v.w;
        }
        __syncthreads();
        #pragma unroll
        for (int k = 0; k < BK; ++k) {
            float4 a4 = *(const float4*)&As[k][ty << 2];
            float4 b4 = *(const float4*)&Bs[k][tx << 2];
            float av[4] = {a4.x, a4.y, a4.z, a4.w};
            float bv[4] = {b4.x, b4.y, b4.z, b4.w};
            #pragma unroll
            for (int i = 0; i < 4; ++i)
                #pragma unroll
                for (int j = 0; j < 4; ++j)
                    acc[i][j] = fmaf(av[i], bv[j], acc[i][j]);
        }
        __syncthreads();
    }

    const int mb = m0 + (ty << 2), nb = n0 + (tx << 2);
    if (EPI == 4) {
        ushort_t* Cu = (ushort_t*)C + (long)batch * sC;
        #pragma unroll
        for (int j = 0; j < 4; ++j) {
            ushort_t pk[4];
            #pragma unroll
            for (int i = 0; i < 4; ++i)
                pk[i] = f2bf(fmaxf(acc[i][j] + bias[mb + i], 0.f));
            *(ushort4*)&Cu[(long)(nb + j) * ldc + mb] =
                make_ushort4(pk[0], pk[1], pk[2], pk[3]);
        }
    } else {
        float* Cb = C + (long)batch * sC;
        #pragma unroll
        for (int i = 0; i < 4; ++i) {
            float4 o = make_float4(acc[i][0], acc[i][1], acc[i][2], acc[i][3]);
            *(float4*)&Cb[(long)(mb + i) * ldc + nb] = o;
        }
    }
}

// ---------- casts / transposes ----------
__global__ __launch_bounds__(256) void cast_x_t(const float* __restrict__ x,
                                                ushort_t* __restrict__ hi,
                                                ushort_t* __restrict__ lo)
{
    __shared__ float t[64][65];
    const int b = blockIdx.z, c0 = blockIdx.y * 64, n0 = blockIdx.x * 64;
    const int tid = threadIdx.x, tx = tid & 63, ty = tid >> 6;
    const float* xb = x + (long)b * 512 * 4096;
    #pragma unroll 4
    for (int s = ty; s < 64; s += 4)
        t[s][tx] = xb[(long)(c0 + s) * 4096 + n0 + tx];
    __syncthreads();
    #pragma unroll 4
    for (int s = ty; s < 64; s += 4) {
        float v = t[tx][s];
        long idx = (long)b * 2097152 + (long)(n0 + s) * 512 + c0 + tx;
        ushort_t h = f2bf(v);
        hi[idx] = h;
        lo[idx] = f2bf(v - bf2f(h));
    }
}

__global__ __launch_bounds__(256) void nd2dn(const ushort_t* __restrict__ hi,
                                             const ushort_t* __restrict__ lo,
                                             ushort_t* __restrict__ dhi,
                                             ushort_t* __restrict__ dlo)
{
    __shared__ unsigned int t[64][65];
    const int b = blockIdx.z, n0 = blockIdx.x * 64, c0 = blockIdx.y * 64;
    const int tx = threadIdx.x & 63, ty = threadIdx.x >> 6;
    const long base = (long)b * 2097152;
    #pragma unroll 4
    for (int s = ty; s < 64; s += 4) {
        long idx = base + (long)(n0 + s) * 512 + c0 + tx;
        t[s][tx] = (unsigned)hi[idx] | ((unsigned)lo[idx] << 16);
    }
    __syncthreads();
    #pragma unroll 4
    for (int s = ty; s < 64; s += 4) {
        unsigned v = t[tx][s];
        long idx = base + (long)(c0 + s) * 4096 + n0 + tx;
        dhi[idx] = (ushort_t)(v & 0xffffu);
        dlo[idx] = (ushort_t)(v >> 16);
    }
}

// prep256: one dispatch for {w_lower split cast, w_upper plain cast, l2norm}.
// grid: [0,1024) wl cast; [1024,2048) w_up cast; [2048,2056) l2norm batch.
__global__ __launch_bounds__(256) void prep256(
    const float* __restrict__ w_lower, ushort_t* __restrict__ wl_hi, ushort_t* __restrict__ wl_lo,
    const float* __restrict__ w_upper, ushort_t* __restrict__ w_up,
    const float* __restrict__ b0, float* __restrict__ bases)
{
    const int bx = blockIdx.x, tid = threadIdx.x;
    if (bx < 1024) {
        int i = bx * 256 + tid;
        float v = w_lower[i];
        ushort_t h = f2bf(v);
        wl_hi[i] = h;
        wl_lo[i] = f2bf(v - bf2f(h));
        return;
    }
    if (bx < 2048) {
        int i = (bx - 1024) * 256 + tid;
        w_up[i] = f2bf(w_upper[i]);
        return;
    }
    // l2norm over D=512 per column r of bases0[b] (256 threads: 4 slices)
    __shared__ float part[4][64];
    const int b = bx - 2048;
    const int r = tid & 63, slice = tid >> 6;
    const float* src = b0 + (long)b * 512 * 64;
    float* dst = bases + (long)b * 512 * 64;
    float s = 0.f;
    #pragma unroll 8
    for (int d = slice; d < 512; d += 4) {
        float v = src[d * 64 + r];
        s = fmaf(v, v, s);
    }
    part[slice][r] = s;
    __syncthreads();
    if (slice == 0) {
        float t = part[0][r] + part[1][r] + part[2][r] + part[3][r];
        part[0][r] = 1.0f / fmaxf(sqrtf(t), 1e-12f);
    }
    __syncthreads();
    const float inv = part[0][r];
    #pragma unroll 8
    for (int d = slice; d < 512; d += 4)
        dst[d * 64 + r] = src[d * 64 + r] * inv;
}

extern "C" void kernel_launch(void* const* d_in, const int* in_sizes, int n_in,
                              void* d_out, int out_size, void* d_ws, size_t ws_size,
                              hipStream_t stream)
{
    const float* x_in     = (const float*)d_in[0];
    const float* bases0   = (const float*)d_in[1];
    const float* w_lower  = (const float*)d_in[2];
    const float* b_lower  = (const float*)d_in[3];
    const float* w_cheese = (const float*)d_in[4];
    const float* b_cheese = (const float*)d_in[5];
    const float* w_upper  = (const float*)d_in[6];
    const float* csc      = (const float*)d_in[7];
    const float* cham     = (const float*)d_in[8];
    float* out = (float*)d_out;

    const int B = 8, C = 512, N = 4096, R = 64;
    const long sCN = (long)C * N;
    const long sNC = (long)N * C;
    const long sNR = (long)N * R, sCR = (long)C * R;

    // ---- workspace layout (bytes) ----
    char* w = (char*)d_ws;
    ushort_t* X_nd_hi  = (ushort_t*)w;  w += 33554432;  // [B,N,C]
    ushort_t* xt_hi    = (ushort_t*)w;  w += 33554432;  // x^T; later X_dn_hi
    ushort_t* xt_lo    = (ushort_t*)w;  w += 33554432;  // x^T; later X_dn_lo
    float*    coef     = (float*)w;     w += 8388608;   // [B,N,R]
    ushort_t* ct_hi    = (ushort_t*)w;  w += 4194304;   // [B,R,N]
    ushort_t* ct_lo    = (ushort_t*)w;  w += 4194304;
    float*    ctc_part = (float*)w;     w += 8388608;   // [64][B][4096]
    float*    xc_part  = (float*)w;     w += 8388608;   // [8][B][512][64]
    float*    btb_part = (float*)w;     w += 1048576;   // [8][B][4096]
    float*    bases    = (float*)w;     w += 1048576;   // [B,C,R]
    float*    WcB      = (float*)w;     w += 1048576;   // [B,C,R]
    float*    ctc      = (float*)w;     w += 131072;    // [B,R,R]
    ushort_t* bt_hi    = (ushort_t*)w;  w += 524288;    // [B,R,C]
    ushort_t* bt_lo    = (ushort_t*)w;  w += 524288;
    ushort_t* wl_hi    = (ushort_t*)w;  w += 524288;
    ushort_t* wl_lo    = (ushort_t*)w;  w += 524288;
    ushort_t* w_up     = (ushort_t*)w;  w += 524288;

    // X_lo plane [B,N,C]: keep d_out WRITE-ONCE (final dispatch only) by
    // placing the scratch plane in the workspace when it fits. Branch is on
    // ws_size only — identical every call, graph-capture-safe.
    ushort_t* X_nd_lo;
    {
        const size_t used = (size_t)(w - (char*)d_ws);
        if (ws_size >= used + 33554432UL) {
            X_nd_lo = (ushort_t*)w;  w += 33554432;
        } else {
            X_nd_lo = (ushort_t*)d_out;  // dead before final out write
        }
    }

    ushort_t* X_dn_hi  = xt_hi;
    ushort_t* X_dn_lo  = xt_lo;
    ushort_t* cheese_t = X_nd_hi;           // X_nd dead after final coef_step

    const dim3 blk(256);

    // init: casts + l2norm in one dispatch, then bt/btb prep
    prep256<<<dim3(2056), blk, 0, stream>>>(w_lower, wl_hi, wl_lo, w_upper, w_up,
                                            bases0, bases);
    bases_step<0><<<dim3(C / 64, B), blk, 0, stream>>>(
        nullptr, nullptr, bases, bt_hi, bt_lo, btb_part, B);
    cast_x_t<<<dim3(N / 64, C / 64, B), blk, 0, stream>>>(x_in, xt_hi, xt_lo);

    // X = relu(w_lower @ x + b_lower) -> bf16 hi/lo [n][c]
    mfma_gemm<1, 2><<<dim3(N / 128, C / 128, B), blk, 0, stream>>>(
        wl_hi, wl_lo, xt_hi, xt_lo, nullptr, X_nd_hi, X_nd_lo,
        C, N, C, sNC, sNC, b_lower, nullptr, 0L, nullptr, nullptr);
    nd2dn<<<dim3(N / 64, C / 64, B), blk, 0, stream>>>(X_nd_hi, X_nd_lo, X_dn_hi, X_dn_lo);

    // coef init (softmax)
    coef_step<0><<<dim3(N / 64, B), blk, 0, stream>>>(
        X_nd_hi, X_nd_lo, bt_hi, bt_lo, btb_part, coef, ct_hi, ct_lo, ctc_part, B);

    for (int step = 0; step < 6; ++step) {
        coef_step<1><<<dim3(N / 64, B), blk, 0, stream>>>(
            X_nd_hi, X_nd_lo, bt_hi, bt_lo, btb_part, coef, ct_hi, ct_lo, ctc_part, B);
        xc_partial<<<dim3(8, 9, B), blk, 0, stream>>>(
            X_dn_hi, X_dn_lo, ct_hi, ct_lo, xc_part, ctc_part, ctc, B);
        bases_step<1><<<dim3(C / 64, B), blk, 0, stream>>>(
            xc_part, ctc, bases, bt_hi, bt_lo, btb_part, B);
    }

    // final differentiable coef refinement (no ct/ctc tail)
    coef_step<2><<<dim3(N / 64, B), blk, 0, stream>>>(
        X_nd_hi, X_nd_lo, bt_hi, bt_lo, btb_part, coef, ct_hi, ct_lo, ctc_part, B);

    // cheese via associativity
    gemm_kernel<0, 0, 0><<<dim3(1, C / BM, B), blk, 0, stream>>>(
        w_cheese, bases, WcB, C, 1, C, R, R, 0L, sCR, sCR, nullptr);
    gemm_kernel<0, 1, 4><<<dim3(N / BN, C / BM, B), blk, 0, stream>>>(
        WcB, coef, (float*)cheese_t, R, 1, R, R, C, sCR, sNR, sNC, b_cheese);

    // out = relu(ham * (w_upper @ cheese) + sc * x)
    mfma_gemm<0, 3><<<dim3(N / 128, C / 128, B), blk, 0, stream>>>(
        w_up, nullptr, cheese_t, nullptr, out, nullptr, nullptr,
        C, N, C, sNC, sCN, nullptr, x_in, sCN, cham, csc);
}

// Round 6
// 705.154 us; speedup vs baseline: 1.8211x; 1.0620x over previous
//
#include <hip/hip_runtime.h>

#define NMF_EPS 1e-6f

typedef unsigned short ushort_t;
typedef __attribute__((ext_vector_type(8))) short bf16x8;
typedef __attribute__((ext_vector_type(4))) float f32x4;

__device__ __forceinline__ ushort_t f2bf(float f) {
    unsigned int u = __float_as_uint(f);
    return (ushort_t)((u + 0x7FFFu + ((u >> 16) & 1u)) >> 16);
}
__device__ __forceinline__ float bf2f(ushort_t h) {
    return __uint_as_float(((unsigned int)h) << 16);
}

__device__ __forceinline__ void gl_lds16(const ushort_t* g, ushort_t* l) {
    __builtin_amdgcn_global_load_lds(
        (const __attribute__((address_space(1))) unsigned int*)g,
        (__attribute__((address_space(3))) unsigned int*)l,
        16, 0, 0);
}

// =====================================================================
// Big MFMA GEMM (lower / upper). C[m,n] = op(sum_k A[m,k]*B[n,k])
// Double-buffered LDS, single barrier per K-step (verified best form).
// EPI 2: relu(acc+bias[m]) -> bf16 hi/lo TRANSPOSED [n][M] (LDS transpose)
// EPI 3: relu(ham*acc + sc*res[m,n]) -> fp32 [M,N]
// =====================================================================
template<int SPLIT, int EPI>
__global__ __launch_bounds__(256) void mfma_gemm(
    const ushort_t* __restrict__ Ah, const ushort_t* __restrict__ Al,
    const ushort_t* __restrict__ Bh, const ushort_t* __restrict__ Bl,
    float* __restrict__ C, ushort_t* __restrict__ Chi, ushort_t* __restrict__ Clo,
    int M, int N, int K,
    long sB, long sC,
    const float* __restrict__ bias,
    const float* __restrict__ res, long sRes,
    const float* __restrict__ hamp, const float* __restrict__ scp)
{
    constexpr int SB = SPLIT ? 32768 : 16384;   // bytes per dbuf slot
    __shared__ char smem[2 * SB];

    const int tid  = threadIdx.x;
    const int wave = tid >> 6, lane = tid & 63;
    const int quad = lane >> 4, lr = lane & 15;
    const int batch = blockIdx.z;
    const int m0 = blockIdx.y * 128, n0 = blockIdx.x * 128;

    const ushort_t* Bhb = Bh + (long)batch * sB;
    const ushort_t* Blb = SPLIT ? (Bl + (long)batch * sB) : nullptr;

    f32x4 acc[4][4];
    #pragma unroll
    for (int i = 0; i < 4; ++i)
        #pragma unroll
        for (int j = 0; j < 4; ++j)
            acc[i][j] = (f32x4){0.f, 0.f, 0.f, 0.f};

    const int q   = wave * 2;
    const int ra0 = (q + 0) * 16 + (lane >> 2);
    const int ra1 = (q + 1) * 16 + (lane >> 2);
    const int ko  = (lane & 3) * 8;
    const int wm = (wave & 1) * 64, wn = (wave >> 1) * 64;

    auto STAGE = [&](int buf, int k0) {
        char* base = smem + buf * SB;
        ushort_t* dAh = (ushort_t*)base;
        ushort_t* dBh = (ushort_t*)(base + 8192);
        gl_lds16(&Ah [(long)(m0 + ra0) * K + k0 + ko], &dAh[(q + 0) * 512]);
        gl_lds16(&Ah [(long)(m0 + ra1) * K + k0 + ko], &dAh[(q + 1) * 512]);
        gl_lds16(&Bhb[(long)(n0 + ra0) * K + k0 + ko], &dBh[(q + 0) * 512]);
        gl_lds16(&Bhb[(long)(n0 + ra1) * K + k0 + ko], &dBh[(q + 1) * 512]);
        if constexpr (SPLIT) {
            ushort_t* dAl = (ushort_t*)(base + 16384);
            ushort_t* dBl = (ushort_t*)(base + 24576);
            gl_lds16(&Al [(long)(m0 + ra0) * K + k0 + ko], &dAl[(q + 0) * 512]);
            gl_lds16(&Al [(long)(m0 + ra1) * K + k0 + ko], &dAl[(q + 1) * 512]);
            gl_lds16(&Blb[(long)(n0 + ra0) * K + k0 + ko], &dBl[(q + 0) * 512]);
            gl_lds16(&Blb[(long)(n0 + ra1) * K + k0 + ko], &dBl[(q + 1) * 512]);
        }
    };

    STAGE(0, 0);
    __syncthreads();
    int cur = 0;

    for (int k0 = 0; k0 < K; k0 += 32) {
        if (k0 + 32 < K) STAGE(cur ^ 1, k0 + 32);

        char* base = smem + cur * SB;
        ushort_t* sAh = (ushort_t*)base;
        ushort_t* sBh = (ushort_t*)(base + 8192);

        bf16x8 af[4], bfr[4], afl[4], bfl[4];
        #pragma unroll
        for (int i = 0; i < 4; ++i)
            af[i] = *(const bf16x8*)&sAh[(wm + i * 16 + lr) * 32 + quad * 8];
        #pragma unroll
        for (int j = 0; j < 4; ++j)
            bfr[j] = *(const bf16x8*)&sBh[(wn + j * 16 + lr) * 32 + quad * 8];
        if constexpr (SPLIT) {
            ushort_t* sAl = (ushort_t*)(base + 16384);
            ushort_t* sBl = (ushort_t*)(base + 24576);
            #pragma unroll
            for (int i = 0; i < 4; ++i)
                afl[i] = *(const bf16x8*)&sAl[(wm + i * 16 + lr) * 32 + quad * 8];
            #pragma unroll
            for (int j = 0; j < 4; ++j)
                bfl[j] = *(const bf16x8*)&sBl[(wn + j * 16 + lr) * 32 + quad * 8];
        }

        #pragma unroll
        for (int i = 0; i < 4; ++i)
            #pragma unroll
            for (int j = 0; j < 4; ++j) {
                acc[i][j] = __builtin_amdgcn_mfma_f32_16x16x32_bf16(af[i], bfr[j], acc[i][j], 0, 0, 0);
                if constexpr (SPLIT) {
                    acc[i][j] = __builtin_amdgcn_mfma_f32_16x16x32_bf16(af[i], bfl[j], acc[i][j], 0, 0, 0);
                    acc[i][j] = __builtin_amdgcn_mfma_f32_16x16x32_bf16(afl[i], bfr[j], acc[i][j], 0, 0, 0);
                }
            }
        __syncthreads();
        cur ^= 1;
    }

    if (EPI == 2) {
        ushort_t* Hh = Chi + (long)batch * sC;
        ushort_t* Hl = Clo + (long)batch * sC;
        unsigned int* slab = (unsigned int*)smem;  // [128 n][64 m] u32
        #pragma unroll
        for (int p = 0; p < 2; ++p) {
            __syncthreads();
            if ((wave & 1) == p) {
                #pragma unroll
                for (int i = 0; i < 4; ++i) {
                    const int mb = m0 + p * 64 + i * 16 + quad * 4;
                    #pragma unroll
                    for (int j = 0; j < 4; ++j) {
                        const int nl = wn + j * 16 + lr;
                        #pragma unroll
                        for (int r = 0; r < 4; ++r) {
                            float v = fmaxf(acc[i][j][r] + bias[mb + r], 0.f);
                            ushort_t h = f2bf(v);
                            ushort_t l = f2bf(v - bf2f(h));
                            slab[nl * 64 + (i * 16 + quad * 4 + r)] =
                                (unsigned)h | ((unsigned)l << 16);
                        }
                    }
                }
            }
            __syncthreads();
            for (int idx = tid; idx < 8192; idx += 256) {
                const int nl = idx >> 6, ml = idx & 63;
                unsigned u = slab[idx];
                const long off = (long)(n0 + nl) * M + m0 + p * 64 + ml;
                Hh[off] = (ushort_t)(u & 0xffffu);
                Hl[off] = (ushort_t)(u >> 16);
            }
        }
    } else {
        const float hm = *hamp, sc = *scp;
        float* Cb = C + (long)batch * sC;
        #pragma unroll
        for (int i = 0; i < 4; ++i) {
            #pragma unroll
            for (int j = 0; j < 4; ++j) {
                const int mbase = m0 + wm + i * 16 + quad * 4;
                const int n     = n0 + wn + j * 16 + lr;
                #pragma unroll
                for (int r = 0; r < 4; ++r) {
                    float rv = res[(long)batch * sRes + (long)(mbase + r) * N + n];
                    Cb[(long)(mbase + r) * N + n] = fmaxf(fmaf(hm, acc[i][j][r], sc * rv), 0.f);
                }
            }
        }
    }
}

// =====================================================================
// Fused coef step. grid (N/64, B), 256 thr. BK=32 ping-pong.
// MODE 0 (INIT): coef = softmax_r(X^T bases)            [split X]
// MODE 1 (MU):   coef = coef*xtb/(coef@btb+eps) + ct/ctc [hi-only X: no-grad]
// MODE 2 (MU, final): as 1, split X, skips dead ct/ctc tail
// =====================================================================
template<int MODE>
__global__ __launch_bounds__(256) void coef_step(
    const ushort_t* __restrict__ Xh, const ushort_t* __restrict__ Xl,   // [B][N][512]
    const ushort_t* __restrict__ bth, const ushort_t* __restrict__ btl, // [B][64][512]
    const float* __restrict__ btb_part,   // [8][B][4096]
    float* __restrict__ coef,             // [B][N][64]
    ushort_t* __restrict__ cth, ushort_t* __restrict__ ctl, // [B][64][N]
    float* __restrict__ ctc_part,         // [64][B][4096]
    int Bcnt)
{
    constexpr bool MU = (MODE >= 1);
    constexpr bool XS = (MODE != 1);   // split-X precision (init + final only)
    __shared__ char smem[32768 + 18432];
    ushort_t* stg = (ushort_t*)smem;             // [2 buf][4 stream][2048]
    ushort_t* gLh = (ushort_t*)(smem + 32768);   // [64][72] btb hi (later ct hi)
    ushort_t* gLl = gLh + 64 * 72;               // btb lo (later ct lo)

    const int tid = threadIdx.x, wave = tid >> 6, lane = tid & 63;
    const int quad = lane >> 4, lr = lane & 15;
    const int b = blockIdx.y, n0 = blockIdx.x * 64;

    const ushort_t* Xhb  = Xh  + (long)b * 2097152 + (long)n0 * 512;
    const ushort_t* Xlb  = Xl  + (long)b * 2097152 + (long)n0 * 512;
    const ushort_t* bthb = bth + (long)b * 32768;
    const ushort_t* btlb = btl + (long)b * 32768;
    float* coefB = coef + (long)b * 262144 + (long)n0 * 64;

    if (MU) {
        // reduce btb partials -> LDS (hi/lo)
        for (int i = tid; i < 4096; i += 256) {
            const int r = i >> 6, s = i & 63;
            float v = 0.f;
            #pragma unroll
            for (int c = 0; c < 8; ++c)
                v += btb_part[((long)c * Bcnt + b) * 4096 + i];
            ushort_t h = f2bf(v);
            gLh[r * 72 + s] = h;
            gLl[r * 72 + s] = f2bf(v - bf2f(h));
        }
    }

    // ---- xtb via MFMA, BK=32 ping-pong ----
    const int srow = wave * 16 + (lane >> 2);
    const int koff = (lane & 3) * 8;
    f32x4 accx[4];
    #pragma unroll
    for (int j = 0; j < 4; ++j) accx[j] = (f32x4){0.f, 0.f, 0.f, 0.f};

    auto STAGEX = [&](int buf, int kc) {
        const int kg = kc * 32 + koff;
        gl_lds16(&Xhb [(long)srow * 512 + kg], &stg[buf * 8192 + 0 * 2048 + wave * 512]);
        if (XS)
            gl_lds16(&Xlb [(long)srow * 512 + kg], &stg[buf * 8192 + 1 * 2048 + wave * 512]);
        gl_lds16(&bthb[(long)srow * 512 + kg], &stg[buf * 8192 + 2 * 2048 + wave * 512]);
        gl_lds16(&btlb[(long)srow * 512 + kg], &stg[buf * 8192 + 3 * 2048 + wave * 512]);
    };

    STAGEX(0, 0);
    __syncthreads();
    int cur = 0;

    for (int kc = 0; kc < 16; ++kc) {
        if (kc + 1 < 16) STAGEX(cur ^ 1, kc + 1);
        bf16x8 ah = *(const bf16x8*)&stg[cur * 8192 + 0 * 2048 + (wave * 16 + lr) * 32 + quad * 8];
        bf16x8 al;
        if (XS)
            al = *(const bf16x8*)&stg[cur * 8192 + 1 * 2048 + (wave * 16 + lr) * 32 + quad * 8];
        #pragma unroll
        for (int j = 0; j < 4; ++j) {
            bf16x8 bh = *(const bf16x8*)&stg[cur * 8192 + 2 * 2048 + (j * 16 + lr) * 32 + quad * 8];
            bf16x8 bl = *(const bf16x8*)&stg[cur * 8192 + 3 * 2048 + (j * 16 + lr) * 32 + quad * 8];
            accx[j] = __builtin_amdgcn_mfma_f32_16x16x32_bf16(ah, bh, accx[j], 0, 0, 0);
            accx[j] = __builtin_amdgcn_mfma_f32_16x16x32_bf16(ah, bl, accx[j], 0, 0, 0);
            if (XS)
                accx[j] = __builtin_amdgcn_mfma_f32_16x16x32_bf16(al, bh, accx[j], 0, 0, 0);
        }
        __syncthreads();
        cur ^= 1;
    }

    float cnew[4][4]; // [j][reg]
    if (MU) {
        // denom = coef @ btb (split MFMA; coef A-frags direct from global fp32)
        f32x4 accd[4];
        #pragma unroll
        for (int j = 0; j < 4; ++j) accd[j] = (f32x4){0.f, 0.f, 0.f, 0.f};
        #pragma unroll
        for (int kk = 0; kk < 2; ++kk) {
            const float* cp = &coefB[(wave * 16 + lr) * 64 + kk * 32 + quad * 8];
            float4 cA = *(const float4*)cp;
            float4 cB = *(const float4*)(cp + 4);
            float cv[8] = {cA.x, cA.y, cA.z, cA.w, cB.x, cB.y, cB.z, cB.w};
            bf16x8 ah, al;
            #pragma unroll
            for (int e = 0; e < 8; ++e) {
                ushort_t h = f2bf(cv[e]);
                ((short*)&ah)[e] = (short)h;
                ((short*)&al)[e] = (short)f2bf(cv[e] - bf2f(h));
            }
            #pragma unroll
            for (int j = 0; j < 4; ++j) {
                bf16x8 bh = *(const bf16x8*)&gLh[(j * 16 + lr) * 72 + kk * 32 + quad * 8];
                bf16x8 bl = *(const bf16x8*)&gLl[(j * 16 + lr) * 72 + kk * 32 + quad * 8];
                accd[j] = __builtin_amdgcn_mfma_f32_16x16x32_bf16(ah, bh, accd[j], 0, 0, 0);
                accd[j] = __builtin_amdgcn_mfma_f32_16x16x32_bf16(ah, bl, accd[j], 0, 0, 0);
                accd[j] = __builtin_amdgcn_mfma_f32_16x16x32_bf16(al, bh, accd[j], 0, 0, 0);
            }
        }
        #pragma unroll
        for (int j = 0; j < 4; ++j)
            #pragma unroll
            for (int r = 0; r < 4; ++r) {
                float cold = coefB[(wave * 16 + quad * 4 + r) * 64 + j * 16 + lr];
                cnew[j][r] = cold * accx[j][r] / (accd[j][r] + NMF_EPS);
            }
    } else {
        #pragma unroll
        for (int r = 0; r < 4; ++r) {
            float m = fmaxf(fmaxf(accx[0][r], accx[1][r]), fmaxf(accx[2][r], accx[3][r]));
            #pragma unroll
            for (int off = 1; off < 16; off <<= 1) m = fmaxf(m, __shfl_xor(m, off, 64));
            float e[4], s = 0.f;
            #pragma unroll
            for (int j = 0; j < 4; ++j) { e[j] = __expf(accx[j][r] - m); s += e[j]; }
            #pragma unroll
            for (int off = 1; off < 16; off <<= 1) s += __shfl_xor(s, off, 64);
            float inv = 1.f / s;
            #pragma unroll
            for (int j = 0; j < 4; ++j) cnew[j][r] = e[j] * inv;
        }
    }

    #pragma unroll
    for (int j = 0; j < 4; ++j)
        #pragma unroll
        for (int r = 0; r < 4; ++r)
            coefB[(wave * 16 + quad * 4 + r) * 64 + j * 16 + lr] = cnew[j][r];

    if (MODE != 1) return;

    __syncthreads();  // btb dead; overlay ct on gL
    #pragma unroll
    for (int j = 0; j < 4; ++j)
        #pragma unroll
        for (int r = 0; r < 4; ++r) {
            const int nl = wave * 16 + quad * 4 + r;
            const int rr = j * 16 + lr;
            float v = cnew[j][r];
            ushort_t h = f2bf(v);
            gLh[rr * 72 + nl] = h;
            gLl[rr * 72 + nl] = f2bf(v - bf2f(h));
        }
    __syncthreads();
    for (int i = tid; i < 4096; i += 256) {
        const int r = i >> 6, nn = i & 63;
        cth[(long)b * 262144 + (long)r * 4096 + n0 + nn] = gLh[r * 72 + nn];
        ctl[(long)b * 262144 + (long)r * 4096 + n0 + nn] = gLl[r * 72 + nn];
    }
    // ctc Gram partials via MFMA
    f32x4 accc[4];
    #pragma unroll
    for (int j = 0; j < 4; ++j) accc[j] = (f32x4){0.f, 0.f, 0.f, 0.f};
    #pragma unroll
    for (int kk = 0; kk < 64; kk += 32) {
        bf16x8 ah = *(const bf16x8*)&gLh[(wave * 16 + lr) * 72 + kk + quad * 8];
        bf16x8 al = *(const bf16x8*)&gLl[(wave * 16 + lr) * 72 + kk + quad * 8];
        #pragma unroll
        for (int j = 0; j < 4; ++j) {
            bf16x8 bh = *(const bf16x8*)&gLh[(j * 16 + lr) * 72 + kk + quad * 8];
            bf16x8 bl = *(const bf16x8*)&gLl[(j * 16 + lr) * 72 + kk + quad * 8];
            accc[j] = __builtin_amdgcn_mfma_f32_16x16x32_bf16(ah, bh, accc[j], 0, 0, 0);
            accc[j] = __builtin_amdgcn_mfma_f32_16x16x32_bf16(ah, bl, accc[j], 0, 0, 0);
            accc[j] = __builtin_amdgcn_mfma_f32_16x16x32_bf16(al, bh, accc[j], 0, 0, 0);
        }
    }
    float* cp = ctc_part + ((long)blockIdx.x * Bcnt + b) * 4096;
    #pragma unroll
    for (int j = 0; j < 4; ++j)
        #pragma unroll
        for (int r = 0; r < 4; ++r)
            cp[(wave * 16 + quad * 4 + r) * 64 + j * 16 + lr] = accc[j][r];
}

// xc split-K partials + folded ctc reduce. X hi-only (no-grad loop).
// grid (8, 9, B): y<8 -> GEMM partials (m0 = y*64); y==8 -> ctc reduce.
__global__ __launch_bounds__(256) void xc_partial(
    const ushort_t* __restrict__ Ah,                          // X_dn hi [B][512][4096]
    const ushort_t* __restrict__ Bh, const ushort_t* __restrict__ Bl, // ct [B][64][4096]
    float* __restrict__ part,
    const float* __restrict__ ctc_part,  // [64][B][4096]
    float* __restrict__ ctc,             // [B][64][64]
    int Bcnt)
{
    __shared__ ushort_t stg[2 * 8192];   // [2 buf][4 stream][2048] (stream 1 unused)
    const int tid = threadIdx.x;
    const int batch = blockIdx.z;

    if (blockIdx.y == 8) {
        const int i0 = blockIdx.x * 512;
        #pragma unroll
        for (int rep = 0; rep < 2; ++rep) {
            const int i = i0 + rep * 256 + tid;
            float v = 0.f;
            #pragma unroll 8
            for (int c = 0; c < 64; ++c)
                v += ctc_part[((long)c * Bcnt + batch) * 4096 + i];
            ctc[(long)batch * 4096 + i] = v;
        }
        return;
    }

    const int wave = tid >> 6, lane = tid & 63;
    const int quad = lane >> 4, lr = lane & 15;
    const int m0 = blockIdx.y * 64;
    const int k0 = blockIdx.x * 512;

    const ushort_t* Ab  = Ah + (long)batch * 2097152;
    const ushort_t* Bb  = Bh + (long)batch * 262144;
    const ushort_t* Blb = Bl + (long)batch * 262144;

    const int srow = wave * 16 + (lane >> 2);
    const int koff = (lane & 3) * 8;

    f32x4 acc[4];
    #pragma unroll
    for (int j = 0; j < 4; ++j) acc[j] = (f32x4){0.f, 0.f, 0.f, 0.f};

    auto STAGEX = [&](int buf, int kc) {
        const int kg = k0 + kc * 32 + koff;
        gl_lds16(&Ab [(long)(m0 + srow) * 4096 + kg], &stg[buf * 8192 + 0 * 2048 + wave * 512]);
        gl_lds16(&Bb [(long)srow * 4096 + kg], &stg[buf * 8192 + 2 * 2048 + wave * 512]);
        gl_lds16(&Blb[(long)srow * 4096 + kg], &stg[buf * 8192 + 3 * 2048 + wave * 512]);
    };

    STAGEX(0, 0);
    __syncthreads();
    int cur = 0;

    for (int kc = 0; kc < 16; ++kc) {
        if (kc + 1 < 16) STAGEX(cur ^ 1, kc + 1);
        bf16x8 ah = *(const bf16x8*)&stg[cur * 8192 + 0 * 2048 + (wave * 16 + lr) * 32 + quad * 8];
        #pragma unroll
        for (int j = 0; j < 4; ++j) {
            bf16x8 bh = *(const bf16x8*)&stg[cur * 8192 + 2 * 2048 + (j * 16 + lr) * 32 + quad * 8];
            bf16x8 bl = *(const bf16x8*)&stg[cur * 8192 + 3 * 2048 + (j * 16 + lr) * 32 + quad * 8];
            acc[j] = __builtin_amdgcn_mfma_f32_16x16x32_bf16(ah, bh, acc[j], 0, 0, 0);
            acc[j] = __builtin_amdgcn_mfma_f32_16x16x32_bf16(ah, bl, acc[j], 0, 0, 0);
        }
        __syncthreads();
        cur ^= 1;
    }

    float* Cb = part + ((long)blockIdx.x * Bcnt + batch) * 32768;
    #pragma unroll
    for (int j = 0; j < 4; ++j) {
        const int col = j * 16 + lr;
        #pragma unroll
        for (int r = 0; r < 4; ++r)
            Cb[(long)(m0 + wave * 16 + quad * 4 + r) * 64 + col] = acc[j][r];
    }
}

// =====================================================================
// Fused bases step. grid (C/64, B).
// MODE 0 (prep): bases -> bt hi/lo + btb Gram partials
// MODE 1 (full): reduce xc partials, mu-update bases, then bt + btb partials
// =====================================================================
template<int MODE>
__global__ __launch_bounds__(256) void bases_step(
    const float* __restrict__ xc_part,   // [8][B][512][64]
    const float* __restrict__ ctc,       // [B][64][64]
    float* __restrict__ bases,           // [B][512][64]
    ushort_t* __restrict__ bth, ushort_t* __restrict__ btl, // [B][64][512]
    float* __restrict__ btb_part,        // [8][B][4096]
    int Bcnt)
{
    __shared__ char smem[16640 * 2 + 18432];
    float* bnL  = (float*)smem;                  // [64][65]
    float* ctcL = (float*)(smem + 16640);        // [64][65]
    ushort_t* btLh = (ushort_t*)(smem + 33280);  // [64][72]
    ushort_t* btLl = btLh + 64 * 72;
    float* basesL = (float*)(smem + 33280);      // overlays btL (phase 1 only)

    const int b = blockIdx.y, c0 = blockIdx.x * 64;
    const int tid = threadIdx.x;
    float* basesB = bases + (long)b * 32768 + (long)c0 * 64;

    if (MODE == 1) {
        for (int i = tid; i < 4096; i += 256) {
            const int c = i >> 6, r = i & 63;
            basesL[c * 65 + r] = basesB[i];
            ctcL[c * 65 + r]   = ctc[(long)b * 4096 + i];
            float v = 0.f;
            #pragma unroll
            for (int s0 = 0; s0 < 8; ++s0)
                v += xc_part[((long)s0 * Bcnt + b) * 32768 + (long)(c0 + c) * 64 + r];
            bnL[c * 65 + r] = v;
        }
        __syncthreads();
        for (int i = tid; i < 4096; i += 256) {
            const int c = i >> 6, r = i & 63;
            float denom = 0.f;
            #pragma unroll 8
            for (int s = 0; s < 64; ++s)
                denom = fmaf(basesL[c * 65 + s], ctcL[s * 65 + r], denom);
            float bnew = basesL[c * 65 + r] * bnL[c * 65 + r] / (denom + NMF_EPS);
            bnL[c * 65 + r] = bnew;
            basesB[i] = bnew;
        }
        __syncthreads();
    } else {
        for (int i = tid; i < 4096; i += 256)
            bnL[(i >> 6) * 65 + (i & 63)] = basesB[i];
        __syncthreads();
    }

    for (int i = tid; i < 4096; i += 256) {
        const int r = i >> 6, cc = i & 63;
        float v = bnL[cc * 65 + r];
        ushort_t h = f2bf(v);
        ushort_t l = f2bf(v - bf2f(h));
        btLh[r * 72 + cc] = h;
        btLl[r * 72 + cc] = l;
        bth[(long)b * 32768 + (long)r * 512 + c0 + cc] = h;
        btl[(long)b * 32768 + (long)r * 512 + c0 + cc] = l;
    }
    __syncthreads();

    const int wave = tid >> 6, lane = tid & 63;
    const int quad = lane >> 4, lr = lane & 15;
    f32x4 acg[4];
    #pragma unroll
    for (int j = 0; j < 4; ++j) acg[j] = (f32x4){0.f, 0.f, 0.f, 0.f};
    #pragma unroll
    for (int kk = 0; kk < 64; kk += 32) {
        bf16x8 ah = *(const bf16x8*)&btLh[(wave * 16 + lr) * 72 + kk + quad * 8];
        bf16x8 al = *(const bf16x8*)&btLl[(wave * 16 + lr) * 72 + kk + quad * 8];
        #pragma unroll
        for (int j = 0; j < 4; ++j) {
            bf16x8 bh = *(const bf16x8*)&btLh[(j * 16 + lr) * 72 + kk + quad * 8];
            bf16x8 bl = *(const bf16x8*)&btLl[(j * 16 + lr) * 72 + kk + quad * 8];
            acg[j] = __builtin_amdgcn_mfma_f32_16x16x32_bf16(ah, bh, acg[j], 0, 0, 0);
            acg[j] = __builtin_amdgcn_mfma_f32_16x16x32_bf16(ah, bl, acg[j], 0, 0, 0);
            acg[j] = __builtin_amdgcn_mfma_f32_16x16x32_bf16(al, bh, acg[j], 0, 0, 0);
        }
    }
    float* gp = btb_part + ((long)blockIdx.x * Bcnt + b) * 4096;
    #pragma unroll
    for (int j = 0; j < 4; ++j)
        #pragma unroll
        for (int r = 0; r < 4; ++r)
            gp[(wave * 16 + quad * 4 + r) * 64 + j * 16 + lr] = acg[j][r];
}

// =====================================================================
// fp32 tiled GEMM (cheese ops only): EPI 0 plain; 4 relu(+bias)->bf16 [n][m]
// =====================================================================
constexpr int BM = 64, BN = 64, BK = 16;

template<int ALAY, int BLAY, int EPI>
__global__ __launch_bounds__(256) void gemm_kernel(
    const float* __restrict__ A, const float* __restrict__ B, float* __restrict__ C,
    int Kchunk, int kchunks,
    int lda, int ldb, int ldc,
    long sA, long sB, long sC,
    const float* __restrict__ bias)
{
    __shared__ float As[BK][BM + 4];
    __shared__ float Bs[BK][BN + 4];

    const int batch = blockIdx.z;
    const float* Ab = A + (long)batch * sA;
    const float* Bb = B + (long)batch * sB;

    const int m0  = blockIdx.y * BM;
    const int n0  = blockIdx.x * BN;
    const int tid = threadIdx.x;
    const int ty  = tid >> 4, tx = tid & 15;

    float acc[4][4] = {};

    for (int kt = 0; kt < Kchunk; kt += BK) {
        if (ALAY == 0) {
            const int m = tid >> 2, k4 = (tid & 3) << 2;
            float4 v = *(const float4*)&Ab[(long)(m0 + m) * lda + (kt + k4)];
            As[k4 + 0][m] = v.x; As[k4 + 1][m] = v.y;
            As[k4 + 2][m] = v.z; As[k4 + 3][m] = v.w;
        } else {
            const int k = tid >> 4, m4 = (tid & 15) << 2;
            float4 v = *(const float4*)&Ab[(long)(kt + k) * lda + (m0 + m4)];
            *(float4*)&As[k][m4] = v;
        }
        if (BLAY == 0) {
            const int k = tid >> 4, n4 = (tid & 15) << 2;
            float4 v = *(const float4*)&Bb[(long)(kt + k) * ldb + (n0 + n4)];
            *(float4*)&Bs[k][n4] = v;
        } else {
            const int n = tid >> 2, k4 = (tid & 3) << 2;
            float4 v = *(const float4*)&Bb[(long)(n0 + n) * ldb + (kt + k4)];
            Bs[k4 + 0][n] = v.x; Bs[k4 + 1][n] = v.y;
            Bs[k4 + 2][n] = v.z; Bs[k4 + 3][n] = v.w;
        }
        __syncthreads();
        #pragma unroll
        for (int k = 0; k < BK; ++k) {
            float4 a4 = *(const float4*)&As[k][ty << 2];
            float4 b4 = *(const float4*)&Bs[k][tx << 2];
            float av[4] = {a4.x, a4.y, a4.z, a4.w};
            float bv[4] = {b4.x, b4.y, b4.z, b4.w};
            #pragma unroll
            for (int i = 0; i < 4; ++i)
                #pragma unroll
                for (int j = 0; j < 4; ++j)
                    acc[i][j] = fmaf(av[i], bv[j], acc[i][j]);
        }
        __syncthreads();
    }

    const int mb = m0 + (ty << 2), nb = n0 + (tx << 2);
    if (EPI == 4) {
        ushort_t* Cu = (ushort_t*)C + (long)batch * sC;
        #pragma unroll
        for (int j = 0; j < 4; ++j) {
            ushort_t pk[4];
            #pragma unroll
            for (int i = 0; i < 4; ++i)
                pk[i] = f2bf(fmaxf(acc[i][j] + bias[mb + i], 0.f));
            *(ushort4*)&Cu[(long)(nb + j) * ldc + mb] =
                make_ushort4(pk[0], pk[1], pk[2], pk[3]);
        }
    } else {
        float* Cb = C + (long)batch * sC;
        #pragma unroll
        for (int i = 0; i < 4; ++i) {
            float4 o = make_float4(acc[i][0], acc[i][1], acc[i][2], acc[i][3]);
            *(float4*)&Cb[(long)(mb + i) * ldc + nb] = o;
        }
    }
}

// ---------- casts / transposes ----------
__global__ __launch_bounds__(256) void cast_x_t(const float* __restrict__ x,
                                                ushort_t* __restrict__ hi,
                                                ushort_t* __restrict__ lo)
{
    __shared__ float t[64][65];
    const int b = blockIdx.z, c0 = blockIdx.y * 64, n0 = blockIdx.x * 64;
    const int tid = threadIdx.x, tx = tid & 63, ty = tid >> 6;
    const float* xb = x + (long)b * 512 * 4096;
    #pragma unroll 4
    for (int s = ty; s < 64; s += 4)
        t[s][tx] = xb[(long)(c0 + s) * 4096 + n0 + tx];
    __syncthreads();
    #pragma unroll 4
    for (int s = ty; s < 64; s += 4) {
        float v = t[tx][s];
        long idx = (long)b * 2097152 + (long)(n0 + s) * 512 + c0 + tx;
        ushort_t h = f2bf(v);
        hi[idx] = h;
        lo[idx] = f2bf(v - bf2f(h));
    }
}

// nd2dn: hi plane only (X_dn lo is unused — MU loop runs hi-only X)
__global__ __launch_bounds__(256) void nd2dn(const ushort_t* __restrict__ hi,
                                             ushort_t* __restrict__ dhi)
{
    __shared__ ushort_t t[64][66];
    const int b = blockIdx.z, n0 = blockIdx.x * 64, c0 = blockIdx.y * 64;
    const int tx = threadIdx.x & 63, ty = threadIdx.x >> 6;
    const long base = (long)b * 2097152;
    #pragma unroll 4
    for (int s = ty; s < 64; s += 4) {
        long idx = base + (long)(n0 + s) * 512 + c0 + tx;
        t[s][tx] = hi[idx];
    }
    __syncthreads();
    #pragma unroll 4
    for (int s = ty; s < 64; s += 4) {
        long idx = base + (long)(c0 + s) * 4096 + n0 + tx;
        dhi[idx] = t[tx][s];
    }
}

// prep256: one dispatch for {w_lower split cast, w_upper plain cast, l2norm}.
// grid: [0,1024) wl cast; [1024,2048) w_up cast; [2048,2056) l2norm batch.
__global__ __launch_bounds__(256) void prep256(
    const float* __restrict__ w_lower, ushort_t* __restrict__ wl_hi, ushort_t* __restrict__ wl_lo,
    const float* __restrict__ w_upper, ushort_t* __restrict__ w_up,
    const float* __restrict__ b0, float* __restrict__ bases)
{
    const int bx = blockIdx.x, tid = threadIdx.x;
    if (bx < 1024) {
        int i = bx * 256 + tid;
        float v = w_lower[i];
        ushort_t h = f2bf(v);
        wl_hi[i] = h;
        wl_lo[i] = f2bf(v - bf2f(h));
        return;
    }
    if (bx < 2048) {
        int i = (bx - 1024) * 256 + tid;
        w_up[i] = f2bf(w_upper[i]);
        return;
    }
    // l2norm over D=512 per column r of bases0[b] (256 threads: 4 slices)
    __shared__ float part[4][64];
    const int b = bx - 2048;
    const int r = tid & 63, slice = tid >> 6;
    const float* src = b0 + (long)b * 512 * 64;
    float* dst = bases + (long)b * 512 * 64;
    float s = 0.f;
    #pragma unroll 8
    for (int d = slice; d < 512; d += 4) {
        float v = src[d * 64 + r];
        s = fmaf(v, v, s);
    }
    part[slice][r] = s;
    __syncthreads();
    if (slice == 0) {
        float t = part[0][r] + part[1][r] + part[2][r] + part[3][r];
        part[0][r] = 1.0f / fmaxf(sqrtf(t), 1e-12f);
    }
    __syncthreads();
    const float inv = part[0][r];
    #pragma unroll 8
    for (int d = slice; d < 512; d += 4)
        dst[d * 64 + r] = src[d * 64 + r] * inv;
}

extern "C" void kernel_launch(void* const* d_in, const int* in_sizes, int n_in,
                              void* d_out, int out_size, void* d_ws, size_t ws_size,
                              hipStream_t stream)
{
    const float* x_in     = (const float*)d_in[0];
    const float* bases0   = (const float*)d_in[1];
    const float* w_lower  = (const float*)d_in[2];
    const float* b_lower  = (const float*)d_in[3];
    const float* w_cheese = (const float*)d_in[4];
    const float* b_cheese = (const float*)d_in[5];
    const float* w_upper  = (const float*)d_in[6];
    const float* csc      = (const float*)d_in[7];
    const float* cham     = (const float*)d_in[8];
    float* out = (float*)d_out;

    const int B = 8, C = 512, N = 4096, R = 64;
    const long sCN = (long)C * N;
    const long sNC = (long)N * C;
    const long sNR = (long)N * R, sCR = (long)C * R;

    // ---- workspace layout (bytes) ----
    char* w = (char*)d_ws;
    ushort_t* X_nd_hi  = (ushort_t*)w;  w += 33554432;  // [B,N,C]
    ushort_t* xt_hi    = (ushort_t*)w;  w += 33554432;  // x^T; later X_dn_hi
    ushort_t* xt_lo    = (ushort_t*)w;  w += 33554432;  // x^T (input split, lower gemm)
    float*    coef     = (float*)w;     w += 8388608;   // [B,N,R]
    ushort_t* ct_hi    = (ushort_t*)w;  w += 4194304;   // [B,R,N]
    ushort_t* ct_lo    = (ushort_t*)w;  w += 4194304;
    float*    ctc_part = (float*)w;     w += 8388608;   // [64][B][4096]
    float*    xc_part  = (float*)w;     w += 8388608;   // [8][B][512][64]
    float*    btb_part = (float*)w;     w += 1048576;   // [8][B][4096]
    float*    bases    = (float*)w;     w += 1048576;   // [B,C,R]
    float*    WcB      = (float*)w;     w += 1048576;   // [B,C,R]
    float*    ctc      = (float*)w;     w += 131072;    // [B,R,R]
    ushort_t* bt_hi    = (ushort_t*)w;  w += 524288;    // [B,R,C]
    ushort_t* bt_lo    = (ushort_t*)w;  w += 524288;
    ushort_t* wl_hi    = (ushort_t*)w;  w += 524288;
    ushort_t* wl_lo    = (ushort_t*)w;  w += 524288;
    ushort_t* w_up     = (ushort_t*)w;  w += 524288;

    // X_lo plane [B,N,C] (used by coef init + final refinement only):
    // keep d_out WRITE-ONCE by placing it in the workspace when it fits.
    // Branch is on ws_size only — identical every call, graph-capture-safe.
    ushort_t* X_nd_lo;
    {
        const size_t used = (size_t)(w - (char*)d_ws);
        if (ws_size >= used + 33554432UL) {
            X_nd_lo = (ushort_t*)w;  w += 33554432;
        } else {
            X_nd_lo = (ushort_t*)d_out;  // dead before final out write
        }
    }

    ushort_t* X_dn_hi  = xt_hi;             // overlays xt_hi (dead after lower gemm)
    ushort_t* cheese_t = X_nd_hi;           // X_nd dead after final coef_step

    const dim3 blk(256);

    // init: casts + l2norm in one dispatch, then bt/btb prep
    prep256<<<dim3(2056), blk, 0, stream>>>(w_lower, wl_hi, wl_lo, w_upper, w_up,
                                            bases0, bases);
    bases_step<0><<<dim3(C / 64, B), blk, 0, stream>>>(
        nullptr, nullptr, bases, bt_hi, bt_lo, btb_part, B);
    cast_x_t<<<dim3(N / 64, C / 64, B), blk, 0, stream>>>(x_in, xt_hi, xt_lo);

    // X = relu(w_lower @ x + b_lower) -> bf16 hi/lo [n][c]
    mfma_gemm<1, 2><<<dim3(N / 128, C / 128, B), blk, 0, stream>>>(
        wl_hi, wl_lo, xt_hi, xt_lo, nullptr, X_nd_hi, X_nd_lo,
        C, N, C, sNC, sNC, b_lower, nullptr, 0L, nullptr, nullptr);
    nd2dn<<<dim3(N / 64, C / 64, B), blk, 0, stream>>>(X_nd_hi, X_dn_hi);

    // coef init (softmax, split X)
    coef_step<0><<<dim3(N / 64, B), blk, 0, stream>>>(
        X_nd_hi, X_nd_lo, bt_hi, bt_lo, btb_part, coef, ct_hi, ct_lo, ctc_part, B);

    for (int step = 0; step < 6; ++step) {
        coef_step<1><<<dim3(N / 64, B), blk, 0, stream>>>(
            X_nd_hi, X_nd_lo, bt_hi, bt_lo, btb_part, coef, ct_hi, ct_lo, ctc_part, B);
        xc_partial<<<dim3(8, 9, B), blk, 0, stream>>>(
            X_dn_hi, ct_hi, ct_lo, xc_part, ctc_part, ctc, B);
        bases_step<1><<<dim3(C / 64, B), blk, 0, stream>>>(
            xc_part, ctc, bases, bt_hi, bt_lo, btb_part, B);
    }

    // final differentiable coef refinement (split X, no ct/ctc tail)
    coef_step<2><<<dim3(N / 64, B), blk, 0, stream>>>(
        X_nd_hi, X_nd_lo, bt_hi, bt_lo, btb_part, coef, ct_hi, ct_lo, ctc_part, B);

    // cheese via associativity
    gemm_kernel<0, 0, 0><<<dim3(1, C / BM, B), blk, 0, stream>>>(
        w_cheese, bases, WcB, C, 1, C, R, R, 0L, sCR, sCR, nullptr);
    gemm_kernel<0, 1, 4><<<dim3(N / BN, C / BM, B), blk, 0, stream>>>(
        WcB, coef, (float*)cheese_t, R, 1, R, R, C, sCR, sNR, sNC, b_cheese);

    // out = relu(ham * (w_upper @ cheese) + sc * x)
    mfma_gemm<0, 3><<<dim3(N / 128, C / 128, B), blk, 0, stream>>>(
        w_up, nullptr, cheese_t, nullptr, out, nullptr, nullptr,
        C, N, C, sNC, sCN, nullptr, x_in, sCN, cham, csc);
}

// Round 8
// 653.165 us; speedup vs baseline: 1.9660x; 1.0796x over previous
//
#include <hip/hip_runtime.h>

#define NMF_EPS 1e-6f

typedef unsigned short ushort_t;
typedef __attribute__((ext_vector_type(8))) short bf16x8;
typedef __attribute__((ext_vector_type(4))) float f32x4;

__device__ __forceinline__ ushort_t f2bf(float f) {
    unsigned int u = __float_as_uint(f);
    return (ushort_t)((u + 0x7FFFu + ((u >> 16) & 1u)) >> 16);
}
__device__ __forceinline__ float bf2f(ushort_t h) {
    return __uint_as_float(((unsigned int)h) << 16);
}

__device__ __forceinline__ void gl_lds16(const ushort_t* g, ushort_t* l) {
    __builtin_amdgcn_global_load_lds(
        (const __attribute__((address_space(1))) unsigned int*)g,
        (__attribute__((address_space(3))) unsigned int*)l,
        16, 0, 0);
}

// =====================================================================
// Big MFMA GEMM (lower / upper). C[m,n] = op(sum_k A[m,k]*B[n,k])
// Double-buffered LDS, single barrier per K-step (verified best form).
// EPI 2: relu(acc+bias[m]) -> bf16 hi/lo TRANSPOSED [n][M] (LDS transpose)
// EPI 3: relu(ham*acc + sc*res[m,n]) -> fp32 [M,N]
// =====================================================================
template<int SPLIT, int EPI>
__global__ __launch_bounds__(256) void mfma_gemm(
    const ushort_t* __restrict__ Ah, const ushort_t* __restrict__ Al,
    const ushort_t* __restrict__ Bh, const ushort_t* __restrict__ Bl,
    float* __restrict__ C, ushort_t* __restrict__ Chi, ushort_t* __restrict__ Clo,
    int M, int N, int K,
    long sB, long sC,
    const float* __restrict__ bias,
    const float* __restrict__ res, long sRes,
    const float* __restrict__ hamp, const float* __restrict__ scp)
{
    constexpr int SB = SPLIT ? 32768 : 16384;   // bytes per dbuf slot
    __shared__ char smem[2 * SB];

    const int tid  = threadIdx.x;
    const int wave = tid >> 6, lane = tid & 63;
    const int quad = lane >> 4, lr = lane & 15;
    const int batch = blockIdx.z;
    const int m0 = blockIdx.y * 128, n0 = blockIdx.x * 128;

    const ushort_t* Bhb = Bh + (long)batch * sB;
    const ushort_t* Blb = SPLIT ? (Bl + (long)batch * sB) : nullptr;

    f32x4 acc[4][4];
    #pragma unroll
    for (int i = 0; i < 4; ++i)
        #pragma unroll
        for (int j = 0; j < 4; ++j)
            acc[i][j] = (f32x4){0.f, 0.f, 0.f, 0.f};

    const int q   = wave * 2;
    const int ra0 = (q + 0) * 16 + (lane >> 2);
    const int ra1 = (q + 1) * 16 + (lane >> 2);
    const int ko  = (lane & 3) * 8;
    const int wm = (wave & 1) * 64, wn = (wave >> 1) * 64;

    auto STAGE = [&](int buf, int k0) {
        char* base = smem + buf * SB;
        ushort_t* dAh = (ushort_t*)base;
        ushort_t* dBh = (ushort_t*)(base + 8192);
        gl_lds16(&Ah [(long)(m0 + ra0) * K + k0 + ko], &dAh[(q + 0) * 512]);
        gl_lds16(&Ah [(long)(m0 + ra1) * K + k0 + ko], &dAh[(q + 1) * 512]);
        gl_lds16(&Bhb[(long)(n0 + ra0) * K + k0 + ko], &dBh[(q + 0) * 512]);
        gl_lds16(&Bhb[(long)(n0 + ra1) * K + k0 + ko], &dBh[(q + 1) * 512]);
        if constexpr (SPLIT) {
            ushort_t* dAl = (ushort_t*)(base + 16384);
            ushort_t* dBl = (ushort_t*)(base + 24576);
            gl_lds16(&Al [(long)(m0 + ra0) * K + k0 + ko], &dAl[(q + 0) * 512]);
            gl_lds16(&Al [(long)(m0 + ra1) * K + k0 + ko], &dAl[(q + 1) * 512]);
            gl_lds16(&Blb[(long)(n0 + ra0) * K + k0 + ko], &dBl[(q + 0) * 512]);
            gl_lds16(&Blb[(long)(n0 + ra1) * K + k0 + ko], &dBl[(q + 1) * 512]);
        }
    };

    STAGE(0, 0);
    __syncthreads();
    int cur = 0;

    for (int k0 = 0; k0 < K; k0 += 32) {
        if (k0 + 32 < K) STAGE(cur ^ 1, k0 + 32);

        char* base = smem + cur * SB;
        ushort_t* sAh = (ushort_t*)base;
        ushort_t* sBh = (ushort_t*)(base + 8192);

        bf16x8 af[4], bfr[4], afl[4], bfl[4];
        #pragma unroll
        for (int i = 0; i < 4; ++i)
            af[i] = *(const bf16x8*)&sAh[(wm + i * 16 + lr) * 32 + quad * 8];
        #pragma unroll
        for (int j = 0; j < 4; ++j)
            bfr[j] = *(const bf16x8*)&sBh[(wn + j * 16 + lr) * 32 + quad * 8];
        if constexpr (SPLIT) {
            ushort_t* sAl = (ushort_t*)(base + 16384);
            ushort_t* sBl = (ushort_t*)(base + 24576);
            #pragma unroll
            for (int i = 0; i < 4; ++i)
                afl[i] = *(const bf16x8*)&sAl[(wm + i * 16 + lr) * 32 + quad * 8];
            #pragma unroll
            for (int j = 0; j < 4; ++j)
                bfl[j] = *(const bf16x8*)&sBl[(wn + j * 16 + lr) * 32 + quad * 8];
        }

        #pragma unroll
        for (int i = 0; i < 4; ++i)
            #pragma unroll
            for (int j = 0; j < 4; ++j) {
                acc[i][j] = __builtin_amdgcn_mfma_f32_16x16x32_bf16(af[i], bfr[j], acc[i][j], 0, 0, 0);
                if constexpr (SPLIT) {
                    acc[i][j] = __builtin_amdgcn_mfma_f32_16x16x32_bf16(af[i], bfl[j], acc[i][j], 0, 0, 0);
                    acc[i][j] = __builtin_amdgcn_mfma_f32_16x16x32_bf16(afl[i], bfr[j], acc[i][j], 0, 0, 0);
                }
            }
        __syncthreads();
        cur ^= 1;
    }

    if (EPI == 2) {
        ushort_t* Hh = Chi + (long)batch * sC;
        ushort_t* Hl = Clo + (long)batch * sC;
        unsigned int* slab = (unsigned int*)smem;  // [128 n][64 m] u32
        #pragma unroll
        for (int p = 0; p < 2; ++p) {
            __syncthreads();
            if ((wave & 1) == p) {
                #pragma unroll
                for (int i = 0; i < 4; ++i) {
                    const int mb = m0 + p * 64 + i * 16 + quad * 4;
                    #pragma unroll
                    for (int j = 0; j < 4; ++j) {
                        const int nl = wn + j * 16 + lr;
                        #pragma unroll
                        for (int r = 0; r < 4; ++r) {
                            float v = fmaxf(acc[i][j][r] + bias[mb + r], 0.f);
                            ushort_t h = f2bf(v);
                            ushort_t l = f2bf(v - bf2f(h));
                            slab[nl * 64 + (i * 16 + quad * 4 + r)] =
                                (unsigned)h | ((unsigned)l << 16);
                        }
                    }
                }
            }
            __syncthreads();
            for (int idx = tid; idx < 8192; idx += 256) {
                const int nl = idx >> 6, ml = idx & 63;
                unsigned u = slab[idx];
                const long off = (long)(n0 + nl) * M + m0 + p * 64 + ml;
                Hh[off] = (ushort_t)(u & 0xffffu);
                Hl[off] = (ushort_t)(u >> 16);
            }
        }
    } else {
        const float hm = *hamp, sc = *scp;
        float* Cb = C + (long)batch * sC;
        #pragma unroll
        for (int i = 0; i < 4; ++i) {
            #pragma unroll
            for (int j = 0; j < 4; ++j) {
                const int mbase = m0 + wm + i * 16 + quad * 4;
                const int n     = n0 + wn + j * 16 + lr;
                #pragma unroll
                for (int r = 0; r < 4; ++r) {
                    float rv = res[(long)batch * sRes + (long)(mbase + r) * N + n];
                    Cb[(long)(mbase + r) * N + n] = fmaxf(fmaf(hm, acc[i][j][r], sc * rv), 0.f);
                }
            }
        }
    }
}

// =====================================================================
// Fused coef step. grid (N/64, B), 256 thr.
// MODE 0 (INIT): coef = softmax_r(X^T bases)   [split X, split bt; BK=32]
// MODE 1 (MU):   coef = coef*xtb/(coef@btb+eps) + ct hi + ctc partials
//                [hi-only X AND bt: no-grad loop; BK=64, 8 phases]
// MODE 2 (MU, final): split X/bt, skips dead ct/ctc tail
// =====================================================================
template<int MODE>
__global__ __launch_bounds__(256) void coef_step(
    const ushort_t* __restrict__ Xh, const ushort_t* __restrict__ Xl,   // [B][N][512]
    const ushort_t* __restrict__ bth, const ushort_t* __restrict__ btl, // [B][64][512]
    const float* __restrict__ btb_part,   // [8][B][4096]
    float* __restrict__ coef,             // [B][N][64]
    ushort_t* __restrict__ cth,           // [B][64][N]
    float* __restrict__ ctc_part,         // [64][B][4096]
    int Bcnt)
{
    constexpr bool MU = (MODE >= 1);
    __shared__ char smem[32768 + 18432];
    ushort_t* stg = (ushort_t*)smem;             // [2 buf][4 slot][2048]
    ushort_t* gLh = (ushort_t*)(smem + 32768);   // [64][72] btb hi (later ct hi)
    ushort_t* gLl = gLh + 64 * 72;               // btb lo

    const int tid = threadIdx.x, wave = tid >> 6, lane = tid & 63;
    const int quad = lane >> 4, lr = lane & 15;
    const int b = blockIdx.y, n0 = blockIdx.x * 64;

    const ushort_t* Xhb  = Xh  + (long)b * 2097152 + (long)n0 * 512;
    const ushort_t* Xlb  = Xl  + (long)b * 2097152 + (long)n0 * 512;
    const ushort_t* bthb = bth + (long)b * 32768;
    const ushort_t* btlb = btl + (long)b * 32768;
    float* coefB = coef + (long)b * 262144 + (long)n0 * 64;

    if (MU) {
        // reduce btb partials -> LDS (hi/lo)
        for (int i = tid; i < 4096; i += 256) {
            const int r = i >> 6, s = i & 63;
            float v = 0.f;
            #pragma unroll
            for (int c = 0; c < 8; ++c)
                v += btb_part[((long)c * Bcnt + b) * 4096 + i];
            ushort_t h = f2bf(v);
            gLh[r * 72 + s] = h;
            gLl[r * 72 + s] = f2bf(v - bf2f(h));
        }
    }

    const int srow = wave * 16 + (lane >> 2);
    const int koff = (lane & 3) * 8;
    f32x4 accx[4];
    #pragma unroll
    for (int j = 0; j < 4; ++j) accx[j] = (f32x4){0.f, 0.f, 0.f, 0.f};

    if constexpr (MODE == 1) {
        // ---- hi-only xtb: 2 streams, BK=64 per phase (8 phases) ----
        auto STG = [&](int buf, int p) {
            const int kg0 = (2 * p) * 32 + koff;
            const int kg1 = (2 * p + 1) * 32 + koff;
            gl_lds16(&Xhb [(long)srow * 512 + kg0], &stg[buf * 8192 + 0 * 2048 + wave * 512]);
            gl_lds16(&Xhb [(long)srow * 512 + kg1], &stg[buf * 8192 + 1 * 2048 + wave * 512]);
            gl_lds16(&bthb[(long)srow * 512 + kg0], &stg[buf * 8192 + 2 * 2048 + wave * 512]);
            gl_lds16(&bthb[(long)srow * 512 + kg1], &stg[buf * 8192 + 3 * 2048 + wave * 512]);
        };
        STG(0, 0);
        __syncthreads();
        int cur = 0;
        for (int p = 0; p < 8; ++p) {
            if (p + 1 < 8) STG(cur ^ 1, p + 1);
            #pragma unroll
            for (int k2 = 0; k2 < 2; ++k2) {
                bf16x8 ah = *(const bf16x8*)&stg[cur * 8192 + k2 * 2048 + (wave * 16 + lr) * 32 + quad * 8];
                #pragma unroll
                for (int j = 0; j < 4; ++j) {
                    bf16x8 bh = *(const bf16x8*)&stg[cur * 8192 + (2 + k2) * 2048 + (j * 16 + lr) * 32 + quad * 8];
                    accx[j] = __builtin_amdgcn_mfma_f32_16x16x32_bf16(ah, bh, accx[j], 0, 0, 0);
                }
            }
            __syncthreads();
            cur ^= 1;
        }
    } else {
        // ---- split xtb: 4 streams, BK=32 ping-pong (init + final) ----
        auto STG = [&](int buf, int kc) {
            const int kg = kc * 32 + koff;
            gl_lds16(&Xhb [(long)srow * 512 + kg], &stg[buf * 8192 + 0 * 2048 + wave * 512]);
            gl_lds16(&Xlb [(long)srow * 512 + kg], &stg[buf * 8192 + 1 * 2048 + wave * 512]);
            gl_lds16(&bthb[(long)srow * 512 + kg], &stg[buf * 8192 + 2 * 2048 + wave * 512]);
            gl_lds16(&btlb[(long)srow * 512 + kg], &stg[buf * 8192 + 3 * 2048 + wave * 512]);
        };
        STG(0, 0);
        __syncthreads();
        int cur = 0;
        for (int kc = 0; kc < 16; ++kc) {
            if (kc + 1 < 16) STG(cur ^ 1, kc + 1);
            bf16x8 ah = *(const bf16x8*)&stg[cur * 8192 + 0 * 2048 + (wave * 16 + lr) * 32 + quad * 8];
            bf16x8 al = *(const bf16x8*)&stg[cur * 8192 + 1 * 2048 + (wave * 16 + lr) * 32 + quad * 8];
            #pragma unroll
            for (int j = 0; j < 4; ++j) {
                bf16x8 bh = *(const bf16x8*)&stg[cur * 8192 + 2 * 2048 + (j * 16 + lr) * 32 + quad * 8];
                bf16x8 bl = *(const bf16x8*)&stg[cur * 8192 + 3 * 2048 + (j * 16 + lr) * 32 + quad * 8];
                accx[j] = __builtin_amdgcn_mfma_f32_16x16x32_bf16(ah, bh, accx[j], 0, 0, 0);
                accx[j] = __builtin_amdgcn_mfma_f32_16x16x32_bf16(ah, bl, accx[j], 0, 0, 0);
                accx[j] = __builtin_amdgcn_mfma_f32_16x16x32_bf16(al, bh, accx[j], 0, 0, 0);
            }
            __syncthreads();
            cur ^= 1;
        }
    }

    float cnew[4][4]; // [j][reg]
    if (MU) {
        // denom = coef @ btb (split MFMA; coef A-frags direct from global fp32)
        f32x4 accd[4];
        #pragma unroll
        for (int j = 0; j < 4; ++j) accd[j] = (f32x4){0.f, 0.f, 0.f, 0.f};
        #pragma unroll
        for (int kk = 0; kk < 2; ++kk) {
            const float* cp = &coefB[(wave * 16 + lr) * 64 + kk * 32 + quad * 8];
            float4 cA = *(const float4*)cp;
            float4 cB = *(const float4*)(cp + 4);
            float cv[8] = {cA.x, cA.y, cA.z, cA.w, cB.x, cB.y, cB.z, cB.w};
            bf16x8 ah, al;
            #pragma unroll
            for (int e = 0; e < 8; ++e) {
                ushort_t h = f2bf(cv[e]);
                ((short*)&ah)[e] = (short)h;
                ((short*)&al)[e] = (short)f2bf(cv[e] - bf2f(h));
            }
            #pragma unroll
            for (int j = 0; j < 4; ++j) {
                bf16x8 bh = *(const bf16x8*)&gLh[(j * 16 + lr) * 72 + kk * 32 + quad * 8];
                bf16x8 bl = *(const bf16x8*)&gLl[(j * 16 + lr) * 72 + kk * 32 + quad * 8];
                accd[j] = __builtin_amdgcn_mfma_f32_16x16x32_bf16(ah, bh, accd[j], 0, 0, 0);
                accd[j] = __builtin_amdgcn_mfma_f32_16x16x32_bf16(ah, bl, accd[j], 0, 0, 0);
                accd[j] = __builtin_amdgcn_mfma_f32_16x16x32_bf16(al, bh, accd[j], 0, 0, 0);
            }
        }
        #pragma unroll
        for (int j = 0; j < 4; ++j)
            #pragma unroll
            for (int r = 0; r < 4; ++r) {
                float cold = coefB[(wave * 16 + quad * 4 + r) * 64 + j * 16 + lr];
                cnew[j][r] = cold * accx[j][r] / (accd[j][r] + NMF_EPS);
            }
    } else {
        #pragma unroll
        for (int r = 0; r < 4; ++r) {
            float m = fmaxf(fmaxf(accx[0][r], accx[1][r]), fmaxf(accx[2][r], accx[3][r]));
            #pragma unroll
            for (int off = 1; off < 16; off <<= 1) m = fmaxf(m, __shfl_xor(m, off, 64));
            float e[4], s = 0.f;
            #pragma unroll
            for (int j = 0; j < 4; ++j) { e[j] = __expf(accx[j][r] - m); s += e[j]; }
            #pragma unroll
            for (int off = 1; off < 16; off <<= 1) s += __shfl_xor(s, off, 64);
            float inv = 1.f / s;
            #pragma unroll
            for (int j = 0; j < 4; ++j) cnew[j][r] = e[j] * inv;
        }
    }

    #pragma unroll
    for (int j = 0; j < 4; ++j)
        #pragma unroll
        for (int r = 0; r < 4; ++r)
            coefB[(wave * 16 + quad * 4 + r) * 64 + j * 16 + lr] = cnew[j][r];

    if (MODE != 1) return;

    __syncthreads();  // btb hi dead; overlay ct hi on gLh (gLl keeps stale btb lo, unused)
    #pragma unroll
    for (int j = 0; j < 4; ++j)
        #pragma unroll
        for (int r = 0; r < 4; ++r) {
            const int nl = wave * 16 + quad * 4 + r;
            const int rr = j * 16 + lr;
            gLh[rr * 72 + nl] = f2bf(cnew[j][r]);
        }
    __syncthreads();
    for (int i = tid; i < 4096; i += 256) {
        const int r = i >> 6, nn = i & 63;
        cth[(long)b * 262144 + (long)r * 4096 + n0 + nn] = gLh[r * 72 + nn];
    }
    // ctc Gram partials via MFMA (hi-only)
    f32x4 accc[4];
    #pragma unroll
    for (int j = 0; j < 4; ++j) accc[j] = (f32x4){0.f, 0.f, 0.f, 0.f};
    #pragma unroll
    for (int kk = 0; kk < 64; kk += 32) {
        bf16x8 ah = *(const bf16x8*)&gLh[(wave * 16 + lr) * 72 + kk + quad * 8];
        #pragma unroll
        for (int j = 0; j < 4; ++j) {
            bf16x8 bh = *(const bf16x8*)&gLh[(j * 16 + lr) * 72 + kk + quad * 8];
            accc[j] = __builtin_amdgcn_mfma_f32_16x16x32_bf16(ah, bh, accc[j], 0, 0, 0);
        }
    }
    float* cp = ctc_part + ((long)blockIdx.x * Bcnt + b) * 4096;
    #pragma unroll
    for (int j = 0; j < 4; ++j)
        #pragma unroll
        for (int r = 0; r < 4; ++r)
            cp[(wave * 16 + quad * 4 + r) * 64 + j * 16 + lr] = accc[j][r];
}

// xc split-K partials + folded ctc reduce. X and ct hi-only (no-grad loop).
// grid (8, 9, B): y<8 -> GEMM partials (m0 = y*64); y==8 -> ctc reduce.
// BK=64 per phase (8 phases), 2 streams.
__global__ __launch_bounds__(256) void xc_partial(
    const ushort_t* __restrict__ Ah,   // X_dn hi [B][512][4096]
    const ushort_t* __restrict__ Bh,   // ct hi  [B][64][4096]
    float* __restrict__ part,
    const float* __restrict__ ctc_part,  // [64][B][4096]
    float* __restrict__ ctc,             // [B][64][64]
    int Bcnt)
{
    __shared__ ushort_t stg[2 * 8192];   // [2 buf][4 slot][2048]
    const int tid = threadIdx.x;
    const int batch = blockIdx.z;

    if (blockIdx.y == 8) {
        const int i0 = blockIdx.x * 512;
        #pragma unroll
        for (int rep = 0; rep < 2; ++rep) {
            const int i = i0 + rep * 256 + tid;
            float v = 0.f;
            #pragma unroll 8
            for (int c = 0; c < 64; ++c)
                v += ctc_part[((long)c * Bcnt + batch) * 4096 + i];
            ctc[(long)batch * 4096 + i] = v;
        }
        return;
    }

    const int wave = tid >> 6, lane = tid & 63;
    const int quad = lane >> 4, lr = lane & 15;
    const int m0 = blockIdx.y * 64;
    const int k0 = blockIdx.x * 512;

    const ushort_t* Ab = Ah + (long)batch * 2097152;
    const ushort_t* Bb = Bh + (long)batch * 262144;

    const int srow = wave * 16 + (lane >> 2);
    const int koff = (lane & 3) * 8;

    f32x4 acc[4];
    #pragma unroll
    for (int j = 0; j < 4; ++j) acc[j] = (f32x4){0.f, 0.f, 0.f, 0.f};

    auto STG = [&](int buf, int p) {
        const int kg0 = k0 + (2 * p) * 32 + koff;
        const int kg1 = k0 + (2 * p + 1) * 32 + koff;
        gl_lds16(&Ab[(long)(m0 + srow) * 4096 + kg0], &stg[buf * 8192 + 0 * 2048 + wave * 512]);
        gl_lds16(&Ab[(long)(m0 + srow) * 4096 + kg1], &stg[buf * 8192 + 1 * 2048 + wave * 512]);
        gl_lds16(&Bb[(long)srow * 4096 + kg0], &stg[buf * 8192 + 2 * 2048 + wave * 512]);
        gl_lds16(&Bb[(long)srow * 4096 + kg1], &stg[buf * 8192 + 3 * 2048 + wave * 512]);
    };

    STG(0, 0);
    __syncthreads();
    int cur = 0;

    for (int p = 0; p < 8; ++p) {
        if (p + 1 < 8) STG(cur ^ 1, p + 1);
        #pragma unroll
        for (int k2 = 0; k2 < 2; ++k2) {
            bf16x8 ah = *(const bf16x8*)&stg[cur * 8192 + k2 * 2048 + (wave * 16 + lr) * 32 + quad * 8];
            #pragma unroll
            for (int j = 0; j < 4; ++j) {
                bf16x8 bh = *(const bf16x8*)&stg[cur * 8192 + (2 + k2) * 2048 + (j * 16 + lr) * 32 + quad * 8];
                acc[j] = __builtin_amdgcn_mfma_f32_16x16x32_bf16(ah, bh, acc[j], 0, 0, 0);
            }
        }
        __syncthreads();
        cur ^= 1;
    }

    float* Cb = part + ((long)blockIdx.x * Bcnt + batch) * 32768;
    #pragma unroll
    for (int j = 0; j < 4; ++j) {
        const int col = j * 16 + lr;
        #pragma unroll
        for (int r = 0; r < 4; ++r)
            Cb[(long)(m0 + wave * 16 + quad * 4 + r) * 64 + col] = acc[j][r];
    }
}

// =====================================================================
// Fused bases step. grid (C/64, B).
// MODE 0 (prep): bases -> bt hi/lo + btb Gram partials
// MODE 1 (full): reduce xc partials, mu-update bases, then bt + btb partials
// =====================================================================
template<int MODE>
__global__ __launch_bounds__(256) void bases_step(
    const float* __restrict__ xc_part,   // [8][B][512][64]
    const float* __restrict__ ctc,       // [B][64][64]
    float* __restrict__ bases,           // [B][512][64]
    ushort_t* __restrict__ bth, ushort_t* __restrict__ btl, // [B][64][512]
    float* __restrict__ btb_part,        // [8][B][4096]
    int Bcnt)
{
    __shared__ char smem[16640 * 2 + 18432];
    float* bnL  = (float*)smem;                  // [64][65]
    float* ctcL = (float*)(smem + 16640);        // [64][65]
    ushort_t* btLh = (ushort_t*)(smem + 33280);  // [64][72]
    ushort_t* btLl = btLh + 64 * 72;
    float* basesL = (float*)(smem + 33280);      // overlays btL (phase 1 only)

    const int b = blockIdx.y, c0 = blockIdx.x * 64;
    const int tid = threadIdx.x;
    float* basesB = bases + (long)b * 32768 + (long)c0 * 64;

    if (MODE == 1) {
        for (int i = tid; i < 4096; i += 256) {
            const int c = i >> 6, r = i & 63;
            basesL[c * 65 + r] = basesB[i];
            ctcL[c * 65 + r]   = ctc[(long)b * 4096 + i];
            float v = 0.f;
            #pragma unroll
            for (int s0 = 0; s0 < 8; ++s0)
                v += xc_part[((long)s0 * Bcnt + b) * 32768 + (long)(c0 + c) * 64 + r];
            bnL[c * 65 + r] = v;
        }
        __syncthreads();
        for (int i = tid; i < 4096; i += 256) {
            const int c = i >> 6, r = i & 63;
            float denom = 0.f;
            #pragma unroll 8
            for (int s = 0; s < 64; ++s)
                denom = fmaf(basesL[c * 65 + s], ctcL[s * 65 + r], denom);
            float bnew = basesL[c * 65 + r] * bnL[c * 65 + r] / (denom + NMF_EPS);
            bnL[c * 65 + r] = bnew;
            basesB[i] = bnew;
        }
        __syncthreads();
    } else {
        for (int i = tid; i < 4096; i += 256)
            bnL[(i >> 6) * 65 + (i & 63)] = basesB[i];
        __syncthreads();
    }

    for (int i = tid; i < 4096; i += 256) {
        const int r = i >> 6, cc = i & 63;
        float v = bnL[cc * 65 + r];
        ushort_t h = f2bf(v);
        ushort_t l = f2bf(v - bf2f(h));
        btLh[r * 72 + cc] = h;
        btLl[r * 72 + cc] = l;
        bth[(long)b * 32768 + (long)r * 512 + c0 + cc] = h;
        btl[(long)b * 32768 + (long)r * 512 + c0 + cc] = l;
    }
    __syncthreads();

    const int wave = tid >> 6, lane = tid & 63;
    const int quad = lane >> 4, lr = lane & 15;
    f32x4 acg[4];
    #pragma unroll
    for (int j = 0; j < 4; ++j) acg[j] = (f32x4){0.f, 0.f, 0.f, 0.f};
    #pragma unroll
    for (int kk = 0; kk < 64; kk += 32) {
        bf16x8 ah = *(const bf16x8*)&btLh[(wave * 16 + lr) * 72 + kk + quad * 8];
        bf16x8 al = *(const bf16x8*)&btLl[(wave * 16 + lr) * 72 + kk + quad * 8];
        #pragma unroll
        for (int j = 0; j < 4; ++j) {
            bf16x8 bh = *(const bf16x8*)&btLh[(j * 16 + lr) * 72 + kk + quad * 8];
            bf16x8 bl = *(const bf16x8*)&btLl[(j * 16 + lr) * 72 + kk + quad * 8];
            acg[j] = __builtin_amdgcn_mfma_f32_16x16x32_bf16(ah, bh, acg[j], 0, 0, 0);
            acg[j] = __builtin_amdgcn_mfma_f32_16x16x32_bf16(ah, bl, acg[j], 0, 0, 0);
            acg[j] = __builtin_amdgcn_mfma_f32_16x16x32_bf16(al, bh, acg[j], 0, 0, 0);
        }
    }
    float* gp = btb_part + ((long)blockIdx.x * Bcnt + b) * 4096;
    #pragma unroll
    for (int j = 0; j < 4; ++j)
        #pragma unroll
        for (int r = 0; r < 4; ++r)
            gp[(wave * 16 + quad * 4 + r) * 64 + j * 16 + lr] = acg[j][r];
}

// =====================================================================
// fp32 tiled GEMM (cheese ops only): EPI 0 plain; 4 relu(+bias)->bf16 [n][m]
// =====================================================================
constexpr int BM = 64, BN = 64, BK = 16;

template<int ALAY, int BLAY, int EPI>
__global__ __launch_bounds__(256) void gemm_kernel(
    const float* __restrict__ A, const float* __restrict__ B, float* __restrict__ C,
    int Kchunk, int kchunks,
    int lda, int ldb, int ldc,
    long sA, long sB, long sC,
    const float* __restrict__ bias)
{
    __shared__ float As[BK][BM + 4];
    __shared__ float Bs[BK][BN + 4];

    const int batch = blockIdx.z;
    const float* Ab = A + (long)batch * sA;
    const float* Bb = B + (long)batch * sB;

    const int m0  = blockIdx.y * BM;
    const int n0  = blockIdx.x * BN;
    const int tid = threadIdx.x;
    const int ty  = tid >> 4, tx = tid & 15;

    float acc[4][4] = {};

    for (int kt = 0; kt < Kchunk; kt += BK) {
        if (ALAY == 0) {
            const int m = tid >> 2, k4 = (tid & 3) << 2;
            float4 v = *(const float4*)&Ab[(long)(m0 + m) * lda + (kt + k4)];
            As[k4 + 0][m] = v.x; As[k4 + 1][m] = v.y;
            As[k4 + 2][m] = v.z; As[k4 + 3][m] = v.w;
        } else {
            const int k = tid >> 4, m4 = (tid & 15) << 2;
            float4 v = *(const float4*)&Ab[(long)(kt + k) * lda + (m0 + m4)];
            *(float4*)&As[k][m4] = v;
        }
        if (BLAY == 0) {
            const int k = tid >> 4, n4 = (tid & 15) << 2;
            float4 v = *(const float4*)&Bb[(long)(kt + k) * ldb + (n0 + n4)];
            *(float4*)&Bs[k][n4] = v;
        } else {
            const int n = tid >> 2, k4 = (tid & 3) << 2;
            float4 v = *(const float4*)&Bb[(long)(n0 + n) * ldb + (kt + k4)];
            Bs[k4 + 0][n] = v.x; Bs[k4 + 1][n] = v.y;
            Bs[k4 + 2][n] = v.z; Bs[k4 + 3][n] = v.w;
        }
        __syncthreads();
        #pragma unroll
        for (int k = 0; k < BK; ++k) {
            float4 a4 = *(const float4*)&As[k][ty << 2];
            float4 b4 = *(const float4*)&Bs[k][tx << 2];
            float av[4] = {a4.x, a4.y, a4.z, a4.w};
            float bv[4] = {b4.x, b4.y, b4.z, b4.w};
            #pragma unroll
            for (int i = 0; i < 4; ++i)
                #pragma unroll
                for (int j = 0; j < 4; ++j)
                    acc[i][j] = fmaf(av[i], bv[j], acc[i][j]);
        }
        __syncthreads();
    }

    const int mb = m0 + (ty << 2), nb = n0 + (tx << 2);
    if (EPI == 4) {
        ushort_t* Cu = (ushort_t*)C + (long)batch * sC;
        #pragma unroll
        for (int j = 0; j < 4; ++j) {
            ushort_t pk[4];
            #pragma unroll
            for (int i = 0; i < 4; ++i)
                pk[i] = f2bf(fmaxf(acc[i][j] + bias[mb + i], 0.f));
            *(ushort4*)&Cu[(long)(nb + j) * ldc + mb] =
                make_ushort4(pk[0], pk[1], pk[2], pk[3]);
        }
    } else {
        float* Cb = C + (long)batch * sC;
        #pragma unroll
        for (int i = 0; i < 4; ++i) {
            float4 o = make_float4(acc[i][0], acc[i][1], acc[i][2], acc[i][3]);
            *(float4*)&Cb[(long)(mb + i) * ldc + nb] = o;
        }
    }
}

// ---------- casts / transposes ----------
__global__ __launch_bounds__(256) void cast_x_t(const float* __restrict__ x,
                                                ushort_t* __restrict__ hi,
                                                ushort_t* __restrict__ lo)
{
    __shared__ float t[64][65];
    const int b = blockIdx.z, c0 = blockIdx.y * 64, n0 = blockIdx.x * 64;
    const int tid = threadIdx.x, tx = tid & 63, ty = tid >> 6;
    const float* xb = x + (long)b * 512 * 4096;
    #pragma unroll 4
    for (int s = ty; s < 64; s += 4)
        t[s][tx] = xb[(long)(c0 + s) * 4096 + n0 + tx];
    __syncthreads();
    #pragma unroll 4
    for (int s = ty; s < 64; s += 4) {
        float v = t[tx][s];
        long idx = (long)b * 2097152 + (long)(n0 + s) * 512 + c0 + tx;
        ushort_t h = f2bf(v);
        hi[idx] = h;
        lo[idx] = f2bf(v - bf2f(h));
    }
}

// nd2dn: hi plane only (X_dn lo is unused — MU loop runs hi-only X)
__global__ __launch_bounds__(256) void nd2dn(const ushort_t* __restrict__ hi,
                                             ushort_t* __restrict__ dhi)
{
    __shared__ ushort_t t[64][66];
    const int b = blockIdx.z, n0 = blockIdx.x * 64, c0 = blockIdx.y * 64;
    const int tx = threadIdx.x & 63, ty = threadIdx.x >> 6;
    const long base = (long)b * 2097152;
    #pragma unroll 4
    for (int s = ty; s < 64; s += 4) {
        long idx = base + (long)(n0 + s) * 512 + c0 + tx;
        t[s][tx] = hi[idx];
    }
    __syncthreads();
    #pragma unroll 4
    for (int s = ty; s < 64; s += 4) {
        long idx = base + (long)(c0 + s) * 4096 + n0 + tx;
        dhi[idx] = t[tx][s];
    }
}

// prep256: one dispatch for {w_lower split cast, w_upper plain cast, l2norm}.
// grid: [0,1024) wl cast; [1024,2048) w_up cast; [2048,2056) l2norm batch.
__global__ __launch_bounds__(256) void prep256(
    const float* __restrict__ w_lower, ushort_t* __restrict__ wl_hi, ushort_t* __restrict__ wl_lo,
    const float* __restrict__ w_upper, ushort_t* __restrict__ w_up,
    const float* __restrict__ b0, float* __restrict__ bases)
{
    const int bx = blockIdx.x, tid = threadIdx.x;
    if (bx < 1024) {
        int i = bx * 256 + tid;
        float v = w_lower[i];
        ushort_t h = f2bf(v);
        wl_hi[i] = h;
        wl_lo[i] = f2bf(v - bf2f(h));
        return;
    }
    if (bx < 2048) {
        int i = (bx - 1024) * 256 + tid;
        w_up[i] = f2bf(w_upper[i]);
        return;
    }
    // l2norm over D=512 per column r of bases0[b] (256 threads: 4 slices)
    __shared__ float part[4][64];
    const int b = bx - 2048;
    const int r = tid & 63, slice = tid >> 6;
    const float* src = b0 + (long)b * 512 * 64;
    float* dst = bases + (long)b * 512 * 64;
    float s = 0.f;
    #pragma unroll 8
    for (int d = slice; d < 512; d += 4) {
        float v = src[d * 64 + r];
        s = fmaf(v, v, s);
    }
    part[slice][r] = s;
    __syncthreads();
    if (slice == 0) {
        float t = part[0][r] + part[1][r] + part[2][r] + part[3][r];
        part[0][r] = 1.0f / fmaxf(sqrtf(t), 1e-12f);
    }
    __syncthreads();
    const float inv = part[0][r];
    #pragma unroll 8
    for (int d = slice; d < 512; d += 4)
        dst[d * 64 + r] = src[d * 64 + r] * inv;
}

extern "C" void kernel_launch(void* const* d_in, const int* in_sizes, int n_in,
                              void* d_out, int out_size, void* d_ws, size_t ws_size,
                              hipStream_t stream)
{
    const float* x_in     = (const float*)d_in[0];
    const float* bases0   = (const float*)d_in[1];
    const float* w_lower  = (const float*)d_in[2];
    const float* b_lower  = (const float*)d_in[3];
    const float* w_cheese = (const float*)d_in[4];
    const float* b_cheese = (const float*)d_in[5];
    const float* w_upper  = (const float*)d_in[6];
    const float* csc      = (const float*)d_in[7];
    const float* cham     = (const float*)d_in[8];
    float* out = (float*)d_out;

    const int B = 8, C = 512, N = 4096, R = 64;
    const long sCN = (long)C * N;
    const long sNC = (long)N * C;
    const long sNR = (long)N * R, sCR = (long)C * R;

    // ---- workspace layout (bytes) ----
    char* w = (char*)d_ws;
    ushort_t* X_nd_hi  = (ushort_t*)w;  w += 33554432;  // [B,N,C]
    ushort_t* xt_hi    = (ushort_t*)w;  w += 33554432;  // x^T; later X_dn_hi
    ushort_t* xt_lo    = (ushort_t*)w;  w += 33554432;  // x^T (input split, lower gemm)
    float*    coef     = (float*)w;     w += 8388608;   // [B,N,R]
    ushort_t* ct_hi    = (ushort_t*)w;  w += 4194304;   // [B,R,N]
    float*    ctc_part = (float*)w;     w += 8388608;   // [64][B][4096]
    float*    xc_part  = (float*)w;     w += 8388608;   // [8][B][512][64]
    float*    btb_part = (float*)w;     w += 1048576;   // [8][B][4096]
    float*    bases    = (float*)w;     w += 1048576;   // [B,C,R]
    float*    WcB      = (float*)w;     w += 1048576;   // [B,C,R]
    float*    ctc      = (float*)w;     w += 131072;    // [B,R,R]
    ushort_t* bt_hi    = (ushort_t*)w;  w += 524288;    // [B,R,C]
    ushort_t* bt_lo    = (ushort_t*)w;  w += 524288;
    ushort_t* wl_hi    = (ushort_t*)w;  w += 524288;
    ushort_t* wl_lo    = (ushort_t*)w;  w += 524288;
    ushort_t* w_up     = (ushort_t*)w;  w += 524288;

    // X_lo plane [B,N,C] (used by coef init + final refinement only):
    // keep d_out WRITE-ONCE by placing it in the workspace when it fits.
    // Branch is on ws_size only — identical every call, graph-capture-safe.
    ushort_t* X_nd_lo;
    {
        const size_t used = (size_t)(w - (char*)d_ws);
        if (ws_size >= used + 33554432UL) {
            X_nd_lo = (ushort_t*)w;  w += 33554432;
        } else {
            X_nd_lo = (ushort_t*)d_out;  // dead before final out write
        }
    }

    ushort_t* X_dn_hi  = xt_hi;             // overlays xt_hi (dead after lower gemm)
    ushort_t* cheese_t = X_nd_hi;           // X_nd dead after final coef_step

    const dim3 blk(256);

    // init: casts + l2norm in one dispatch, then bt/btb prep
    prep256<<<dim3(2056), blk, 0, stream>>>(w_lower, wl_hi, wl_lo, w_upper, w_up,
                                            bases0, bases);
    bases_step<0><<<dim3(C / 64, B), blk, 0, stream>>>(
        nullptr, nullptr, bases, bt_hi, bt_lo, btb_part, B);
    cast_x_t<<<dim3(N / 64, C / 64, B), blk, 0, stream>>>(x_in, xt_hi, xt_lo);

    // X = relu(w_lower @ x + b_lower) -> bf16 hi/lo [n][c]
    mfma_gemm<1, 2><<<dim3(N / 128, C / 128, B), blk, 0, stream>>>(
        wl_hi, wl_lo, xt_hi, xt_lo, nullptr, X_nd_hi, X_nd_lo,
        C, N, C, sNC, sNC, b_lower, nullptr, 0L, nullptr, nullptr);
    nd2dn<<<dim3(N / 64, C / 64, B), blk, 0, stream>>>(X_nd_hi, X_dn_hi);

    // coef init (softmax, split X)
    coef_step<0><<<dim3(N / 64, B), blk, 0, stream>>>(
        X_nd_hi, X_nd_lo, bt_hi, bt_lo, btb_part, coef, ct_hi, ctc_part, B);

    for (int step = 0; step < 6; ++step) {
        coef_step<1><<<dim3(N / 64, B), blk, 0, stream>>>(
            X_nd_hi, X_nd_lo, bt_hi, bt_lo, btb_part, coef, ct_hi, ctc_part, B);
        xc_partial<<<dim3(8, 9, B), blk, 0, stream>>>(
            X_dn_hi, ct_hi, xc_part, ctc_part, ctc, B);
        bases_step<1><<<dim3(C / 64, B), blk, 0, stream>>>(
            xc_part, ctc, bases, bt_hi, bt_lo, btb_part, B);
    }

    // final differentiable coef refinement (split X/bt, no ct/ctc tail)
    coef_step<2><<<dim3(N / 64, B), blk, 0, stream>>>(
        X_nd_hi, X_nd_lo, bt_hi, bt_lo, btb_part, coef, ct_hi, ctc_part, B);

    // cheese via associativity
    gemm_kernel<0, 0, 0><<<dim3(1, C / BM, B), blk, 0, stream>>>(
        w_cheese, bases, WcB, C, 1, C, R, R, 0L, sCR, sCR, nullptr);
    gemm_kernel<0, 1, 4><<<dim3(N / BN, C / BM, B), blk, 0, stream>>>(
        WcB, coef, (float*)cheese_t, R, 1, R, R, C, sCR, sNR, sNC, b_cheese);

    // out = relu(ham * (w_upper @ cheese) + sc * x)
    mfma_gemm<0, 3><<<dim3(N / 128, C / 128, B), blk, 0, stream>>>(
        w_up, nullptr, cheese_t, nullptr, out, nullptr, nullptr,
        C, N, C, sNC, sCN, nullptr, x_in, sCN, cham, csc);
}